// Round 7
// baseline (1048.641 us; speedup 1.0000x reference)
//
#include <hip/hip_runtime.h>
#include <hip/hip_bf16.h>
#include <math.h>

#define S_    2048
#define HID_  4096
#define HQ_   32
#define HKV_  8
#define D_    128
#define G_    4
#define OBS_  128
#define W_    32
#define NKV_  1024
#define NQ_   4096
#define KLD_  2048
#define SCALE_ 0.08838834764831845f
#define THR_IDX_ 89
#define NC_   16128

typedef __attribute__((ext_vector_type(4))) float f32x4;
typedef __attribute__((ext_vector_type(8))) short s16x8;
typedef __attribute__((ext_vector_type(8))) unsigned short u16x8;
typedef __attribute__((ext_vector_type(4))) unsigned short u16x4;
typedef unsigned short ushort_t;

struct TermPtrs { const ushort_t* a[6]; const ushort_t* b[6]; };
struct KvSh { const ushort_t* S[3]; const ushort_t* U0[3]; const ushort_t* U1[3]; int ash[3]; };

__device__ __forceinline__ unsigned short f2bf(float x) {
  union { float f; unsigned u; } v; v.f = x;
  unsigned r = v.u + 0x7FFFu + ((v.u >> 16) & 1u);
  return (unsigned short)(r >> 16);
}
__device__ __forceinline__ float bf2f(unsigned short b) {
  union { unsigned u; float f; } v; v.u = ((unsigned)b) << 16;
  return v.f;
}
__device__ __forceinline__ void gload_lds16(const void* g, void* l) {
  __builtin_amdgcn_global_load_lds((const __attribute__((address_space(1))) unsigned int*)g,
                                   (__attribute__((address_space(3))) unsigned int*)l, 16, 0, 0);
}
__device__ __forceinline__ void term_sel(const TermPtrs& P, int tt,
                                         const ushort_t*& As, const ushort_t*& Bs) {
  switch (tt) {
    case 0: As = P.a[0]; Bs = P.b[0]; break;
    case 1: As = P.a[1]; Bs = P.b[1]; break;
    case 2: As = P.a[2]; Bs = P.b[2]; break;
    case 3: As = P.a[3]; Bs = P.b[3]; break;
    case 4: As = P.a[4]; Bs = P.b[4]; break;
    default: As = P.a[5]; Bs = P.b[5]; break;
  }
}

// ---------------- split fp32 -> 3 bf16 terms ----------------
__global__ __launch_bounds__(256) void split3_kernel(const float* __restrict__ src,
                                                     ushort_t* __restrict__ d0,
                                                     ushort_t* __restrict__ d1,
                                                     ushort_t* __restrict__ d2, int n4) {
  int idx = blockIdx.x * 256 + threadIdx.x;
  if (idx >= n4) return;
  float4 v = ((const float4*)src)[idx];
  u16x4 o0, o1, o2;
  float xs[4] = {v.x, v.y, v.z, v.w};
#pragma unroll
  for (int e = 0; e < 4; ++e) {
    float x = xs[e];
    unsigned short b0 = f2bf(x);
    float r = x - bf2f(b0);
    unsigned short b1 = f2bf(r);
    o0[e] = b0; o1[e] = b1; o2[e] = f2bf(r - bf2f(b1));
  }
  *(u16x4*)(d0 + (size_t)idx * 4) = o0;
  *(u16x4*)(d1 + (size_t)idx * 4) = o1;
  *(u16x4*)(d2 + (size_t)idx * 4) = o2;
}

// ---------------- split + transpose weights ----------------
__global__ __launch_bounds__(256) void splitT_kernel(const float* __restrict__ src, int N,
                                                     ushort_t* __restrict__ t0,
                                                     ushort_t* __restrict__ t1,
                                                     ushort_t* __restrict__ t2) {
  __shared__ float tile[64][65];
  const int t = threadIdx.x;
  const int n0 = blockIdx.x * 64, k0 = blockIdx.y * 64;
#pragma unroll
  for (int i = 0; i < 16; ++i) {
    int idx = i * 256 + t;
    int r = idx >> 6, c = idx & 63;
    tile[r][c] = src[(size_t)(k0 + r) * N + n0 + c];
  }
  __syncthreads();
#pragma unroll
  for (int i = 0; i < 16; ++i) {
    int idx = i * 256 + t;
    int n = idx >> 6, kk = idx & 63;
    float x = tile[kk][n];
    unsigned short b0 = f2bf(x);
    size_t o = (size_t)(n0 + n) * HID_ + k0 + kk;
    t0[o] = b0;
    if (t1) {
      float r = x - bf2f(b0);
      unsigned short b1 = f2bf(r);
      t1[o] = b1;
      t2[o] = f2bf(r - bf2f(b1));
    }
  }
}

// ---------------- KV GEMM: operand-shared 2-product per z ----------------
// z: S shared operand, U0/U1 the partners. ash=1: S is A-side (rows bm); ash=0: S is B-side.
__global__ __launch_bounds__(256) void gemm_kvsh(KvSh P, float* __restrict__ Cbase,
                                                 int M, int N, int K) {
  __shared__ ushort_t lds[3 * 128 * 64];
  const int t = threadIdx.x;
  const int wave = t >> 6, lane = t & 63;
  const int lc = lane & 15, lg = lane >> 4;
  const int bm = blockIdx.y, bn = blockIdx.x, z = blockIdx.z;
  const int wm = wave >> 1, wn = wave & 1;
  const int srow = t >> 3, schunk = t & 7;
  const int ash = P.ash[z];
  const ushort_t* Sp  = P.S[z];
  const ushort_t* U0p = P.U0[z];
  const ushort_t* U1p = P.U1[z];
  float* C = Cbase + (size_t)z * M * N;
  const int sbase = (ash ? bm : bn) * 128;
  const int ubase = (ash ? bn : bm) * 128;

  f32x4 acc[4][4];
#pragma unroll
  for (int fi = 0; fi < 4; ++fi)
#pragma unroll
    for (int fj = 0; fj < 4; ++fj) acc[fi][fj] = 0.f;

  for (int kb = 0; kb < K / 64; ++kb) {
    __syncthreads();
#pragma unroll
    for (int g = 0; g < 4; ++g) {
      int row = g * 32 + srow;
      int sw = schunk ^ (row & 7);
      size_t co = kb * 64 + sw * 8;
      gload_lds16(Sp  + (size_t)(sbase + row) * K + co, lds + g * 2048 + wave * 512);
      gload_lds16(U0p + (size_t)(ubase + row) * K + co, lds + 8192 + g * 2048 + wave * 512);
      gload_lds16(U1p + (size_t)(ubase + row) * K + co, lds + 16384 + g * 2048 + wave * 512);
    }
    __syncthreads();
#pragma unroll
    for (int ks = 0; ks < 2; ++ks) {
      s16x8 sf[4], u0f[4], u1f[4];
#pragma unroll
      for (int f = 0; f < 4; ++f) {
        int rs = (ash ? wm : wn) * 64 + f * 16 + lc;
        sf[f] = *(const s16x8*)(lds + rs * 64 + (((ks * 4 + lg) ^ (rs & 7)) * 8));
        int ru = (ash ? wn : wm) * 64 + f * 16 + lc;
        int cu = (((ks * 4 + lg) ^ (ru & 7)) * 8);
        u0f[f] = *(const s16x8*)(lds + 8192 + ru * 64 + cu);
        u1f[f] = *(const s16x8*)(lds + 16384 + ru * 64 + cu);
      }
      if (ash) {
#pragma unroll
        for (int fi = 0; fi < 4; ++fi)
#pragma unroll
          for (int fj = 0; fj < 4; ++fj) {
            acc[fi][fj] = __builtin_amdgcn_mfma_f32_16x16x32_bf16(sf[fi], u0f[fj], acc[fi][fj], 0, 0, 0);
            acc[fi][fj] = __builtin_amdgcn_mfma_f32_16x16x32_bf16(sf[fi], u1f[fj], acc[fi][fj], 0, 0, 0);
          }
      } else {
#pragma unroll
        for (int fi = 0; fi < 4; ++fi)
#pragma unroll
          for (int fj = 0; fj < 4; ++fj) {
            acc[fi][fj] = __builtin_amdgcn_mfma_f32_16x16x32_bf16(u0f[fi], sf[fj], acc[fi][fj], 0, 0, 0);
            acc[fi][fj] = __builtin_amdgcn_mfma_f32_16x16x32_bf16(u1f[fi], sf[fj], acc[fi][fj], 0, 0, 0);
          }
      }
    }
  }
#pragma unroll
  for (int fi = 0; fi < 4; ++fi)
#pragma unroll
    for (int fj = 0; fj < 4; ++fj)
#pragma unroll
      for (int r = 0; r < 4; ++r)
        C[(size_t)(bm * 128 + wm * 64 + fi * 16 + lg * 4 + r) * N +
          bn * 128 + wn * 64 + fj * 16 + lc] = acc[fi][fj][r];
}

// ---------------- single-term GEMM with split-K (z = K-chunk of KSTEPS*64) ----------------
__global__ __launch_bounds__(256) void gemm1(const ushort_t* __restrict__ A,
                                             const ushort_t* __restrict__ B,
                                             float* __restrict__ Cbase,
                                             int M, int N, int K, int KSTEPS) {
  __shared__ ushort_t lds[2 * 128 * 64];
  const int t = threadIdx.x;
  const int wave = t >> 6, lane = t & 63;
  const int lc = lane & 15, lg = lane >> 4;
  const int bm = blockIdx.y, bn = blockIdx.x, z = blockIdx.z;
  const int wm = wave >> 1, wn = wave & 1;
  const int srow = t >> 3, schunk = t & 7;
  float* C = Cbase + (size_t)z * M * N;

  f32x4 acc[4][4];
#pragma unroll
  for (int fi = 0; fi < 4; ++fi)
#pragma unroll
    for (int fj = 0; fj < 4; ++fj) acc[fi][fj] = 0.f;

  for (int kb = z * KSTEPS; kb < z * KSTEPS + KSTEPS; ++kb) {
    __syncthreads();
#pragma unroll
    for (int g = 0; g < 4; ++g) {
      int row = g * 32 + srow;
      int sw = schunk ^ (row & 7);
      size_t co = kb * 64 + sw * 8;
      gload_lds16(A + (size_t)(bm * 128 + row) * K + co, lds + g * 2048 + wave * 512);
      gload_lds16(B + (size_t)(bn * 128 + row) * K + co, lds + 8192 + g * 2048 + wave * 512);
    }
    __syncthreads();
#pragma unroll
    for (int ks = 0; ks < 2; ++ks) {
      s16x8 af[4], bf[4];
#pragma unroll
      for (int f = 0; f < 4; ++f) {
        int ra = wm * 64 + f * 16 + lc;
        af[f] = *(const s16x8*)(lds + ra * 64 + (((ks * 4 + lg) ^ (ra & 7)) * 8));
        int rb = wn * 64 + f * 16 + lc;
        bf[f] = *(const s16x8*)(lds + 8192 + rb * 64 + (((ks * 4 + lg) ^ (rb & 7)) * 8));
      }
#pragma unroll
      for (int fi = 0; fi < 4; ++fi)
#pragma unroll
        for (int fj = 0; fj < 4; ++fj)
          acc[fi][fj] = __builtin_amdgcn_mfma_f32_16x16x32_bf16(af[fi], bf[fj], acc[fi][fj], 0, 0, 0);
    }
  }
#pragma unroll
  for (int fi = 0; fi < 4; ++fi)
#pragma unroll
    for (int fj = 0; fj < 4; ++fj)
#pragma unroll
      for (int r = 0; r < 4; ++r)
        C[(size_t)(bm * 128 + wm * 64 + fi * 16 + lg * 4 + r) * N +
          bn * 128 + wn * 64 + fj * 16 + lc] = acc[fi][fj][r];
}

// ---------------- obs-Q: M=128, all 6 terms, z = K-slice of 512 ----------------
__global__ __launch_bounds__(256) void gemm6k(TermPtrs P, float* __restrict__ Cp, int N) {
  __shared__ ushort_t lds[2 * 128 * 64];
  const int t = threadIdx.x;
  const int wave = t >> 6, lane = t & 63;
  const int lc = lane & 15, lg = lane >> 4;
  const int bn = blockIdx.x, z = blockIdx.z;
  const int wm = wave >> 1, wn = wave & 1;
  const int srow = t >> 3, schunk = t & 7;
  float* C = Cp + (size_t)z * 128 * N;

  f32x4 acc[4][4];
#pragma unroll
  for (int fi = 0; fi < 4; ++fi)
#pragma unroll
    for (int fj = 0; fj < 4; ++fj) acc[fi][fj] = 0.f;

  for (int tt = 0; tt < 6; ++tt) {
    const ushort_t *As, *Bs;
    term_sel(P, tt, As, Bs);
    for (int kb = z * 8; kb < z * 8 + 8; ++kb) {
      __syncthreads();
#pragma unroll
      for (int g = 0; g < 4; ++g) {
        int row = g * 32 + srow;
        int sw = schunk ^ (row & 7);
        gload_lds16(As + (size_t)row * HID_ + kb * 64 + sw * 8,
                    lds + g * 2048 + wave * 512);
        gload_lds16(Bs + (size_t)(bn * 128 + row) * HID_ + kb * 64 + sw * 8,
                    lds + 8192 + g * 2048 + wave * 512);
      }
      __syncthreads();
#pragma unroll
      for (int ks = 0; ks < 2; ++ks) {
        s16x8 af[4], bf[4];
#pragma unroll
        for (int f = 0; f < 4; ++f) {
          int ra = wm * 64 + f * 16 + lc;
          af[f] = *(const s16x8*)(lds + ra * 64 + (((ks * 4 + lg) ^ (ra & 7)) * 8));
          int rb = wn * 64 + f * 16 + lc;
          bf[f] = *(const s16x8*)(lds + 8192 + rb * 64 + (((ks * 4 + lg) ^ (rb & 7)) * 8));
        }
#pragma unroll
        for (int fi = 0; fi < 4; ++fi)
#pragma unroll
          for (int fj = 0; fj < 4; ++fj)
            acc[fi][fj] = __builtin_amdgcn_mfma_f32_16x16x32_bf16(af[fi], bf[fj], acc[fi][fj], 0, 0, 0);
      }
    }
  }
#pragma unroll
  for (int fi = 0; fi < 4; ++fi)
#pragma unroll
    for (int fj = 0; fj < 4; ++fj)
#pragma unroll
      for (int r = 0; r < 4; ++r)
        C[(size_t)(wm * 64 + fi * 16 + lg * 4 + r) * N +
          bn * 128 + wn * 64 + fj * 16 + lc] = acc[fi][fj][r];
}

// ---------------- s_obs: all 6 terms, z = kv-head, K=128 ----------------
__global__ __launch_bounds__(256) void gemm6z(TermPtrs P, float* __restrict__ Cg) {
  __shared__ ushort_t lds[2 * 128 * 64];
  const int t = threadIdx.x;
  const int wave = t >> 6, lane = t & 63;
  const int lc = lane & 15, lg = lane >> 4;
  const int bm = blockIdx.y, bn = blockIdx.x, z = blockIdx.z;
  const int wm = wave >> 1, wn = wave & 1;
  const int srow = t >> 3, schunk = t & 7;
  const size_t Aoff = (size_t)z * 512 * 128;
  const size_t Boff = (size_t)z * 2048 * 128;
  float* C = Cg + (size_t)z * 512 * 2048;

  f32x4 acc[4][4];
#pragma unroll
  for (int fi = 0; fi < 4; ++fi)
#pragma unroll
    for (int fj = 0; fj < 4; ++fj) acc[fi][fj] = 0.f;

  for (int tt = 0; tt < 6; ++tt) {
    const ushort_t *As, *Bs;
    term_sel(P, tt, As, Bs);
    As += Aoff; Bs += Boff;
    for (int kb = 0; kb < 2; ++kb) {
      __syncthreads();
#pragma unroll
      for (int g = 0; g < 4; ++g) {
        int row = g * 32 + srow;
        int sw = schunk ^ (row & 7);
        gload_lds16(As + (size_t)(bm * 128 + row) * 128 + kb * 64 + sw * 8,
                    lds + g * 2048 + wave * 512);
        gload_lds16(Bs + (size_t)(bn * 128 + row) * 128 + kb * 64 + sw * 8,
                    lds + 8192 + g * 2048 + wave * 512);
      }
      __syncthreads();
#pragma unroll
      for (int ks = 0; ks < 2; ++ks) {
        s16x8 af[4], bf[4];
#pragma unroll
        for (int f = 0; f < 4; ++f) {
          int ra = wm * 64 + f * 16 + lc;
          af[f] = *(const s16x8*)(lds + ra * 64 + (((ks * 4 + lg) ^ (ra & 7)) * 8));
          int rb = wn * 64 + f * 16 + lc;
          bf[f] = *(const s16x8*)(lds + 8192 + rb * 64 + (((ks * 4 + lg) ^ (rb & 7)) * 8));
        }
#pragma unroll
        for (int fi = 0; fi < 4; ++fi)
#pragma unroll
          for (int fj = 0; fj < 4; ++fj)
            acc[fi][fj] = __builtin_amdgcn_mfma_f32_16x16x32_bf16(af[fi], bf[fj], acc[fi][fj], 0, 0, 0);
      }
    }
  }
#pragma unroll
  for (int fi = 0; fi < 4; ++fi)
#pragma unroll
    for (int fj = 0; fj < 4; ++fj)
#pragma unroll
      for (int r = 0; r < 4; ++r)
        C[(size_t)(bm * 128 + wm * 64 + fi * 16 + lg * 4 + r) * 2048 +
          bn * 128 + wn * 64 + fj * 16 + lc] = acc[fi][fj][r];
}

// ---------------- reductions ----------------
__global__ void reduce3_kernel(const float* __restrict__ p, float* __restrict__ out, int n4) {
  int idx = blockIdx.x * 256 + threadIdx.x;
  if (idx >= n4) return;
  const size_t n = (size_t)n4 * 4;
  float4 a = ((const float4*)p)[idx];
  float4 b = ((const float4*)(p + n))[idx];
  float4 c = ((const float4*)(p + 2 * n))[idx];
  float4 o;
  o.x = a.x + b.x + c.x; o.y = a.y + b.y + c.y;
  o.z = a.z + b.z + c.z; o.w = a.w + b.w + c.w;
  ((float4*)out)[idx] = o;
}
__global__ void reduce2_kernel(const float* __restrict__ p, float* __restrict__ out, int n4) {
  int idx = blockIdx.x * 256 + threadIdx.x;
  if (idx >= n4) return;
  const size_t n = (size_t)n4 * 4;
  float4 a = ((const float4*)p)[idx];
  float4 b = ((const float4*)(p + n))[idx];
  float4 o;
  o.x = a.x + b.x; o.y = a.y + b.y; o.z = a.z + b.z; o.w = a.w + b.w;
  ((float4*)out)[idx] = o;
}

// ---------------- inv_freq ----------------
__global__ void freq_kernel(float* __restrict__ invf) {
  int j = threadIdx.x;
  if (j < 64) invf[j] = (float)(1.0 / pow(500000.0, (double)j / 64.0));
}

// ---------------- fused: sum8 partials + RoPE + 3-split for obs-Q ----------------
__global__ __launch_bounds__(256) void qobs_fuse(const float* __restrict__ qpart,
                                                 const float* __restrict__ invf,
                                                 ushort_t* __restrict__ q0,
                                                 ushort_t* __restrict__ q1,
                                                 ushort_t* __restrict__ q2) {
  int idx = blockIdx.x * 256 + threadIdx.x;   // 128*32*64 = 262144
  int j = idx & 63;
  int hq = (idx >> 6) & 31;
  int i = idx >> 11;
  size_t base = (size_t)i * NQ_ + hq * 128 + j;
  float x1 = 0.f, x2 = 0.f;
#pragma unroll
  for (int z = 0; z < 8; ++z) {
    x1 += qpart[(size_t)z * OBS_ * NQ_ + base];
    x2 += qpart[(size_t)z * OBS_ * NQ_ + base + 64];
  }
  float ang = (float)(S_ - OBS_ + i) * invf[j];
  float sn, cs; sincosf(ang, &sn, &cs);
  float o1 = x1 * cs - x2 * sn;
  float o2 = x2 * cs + x1 * sn;
  int hk = hq >> 2, g = hq & 3;
  size_t o = (size_t)hk * 65536 + (size_t)(g * 128 + i) * 128 + j;
  float ys[2] = {o1, o2};
#pragma unroll
  for (int e = 0; e < 2; ++e) {
    float x = ys[e];
    unsigned short b0 = f2bf(x);
    float r = x - bf2f(b0);
    unsigned short b1 = f2bf(r);
    q0[o + e * 64] = b0; q1[o + e * 64] = b1; q2[o + e * 64] = f2bf(r - bf2f(b1));
  }
}

// ---------------- fused: RoPE K-half of kvf (in place) + 3-split to kb ----------------
__global__ __launch_bounds__(256) void ropekv_splitk(float* __restrict__ kvf,
                                                     const float* __restrict__ invf,
                                                     ushort_t* __restrict__ k0,
                                                     ushort_t* __restrict__ k1,
                                                     ushort_t* __restrict__ k2) {
  int idx = blockIdx.x * 256 + threadIdx.x;   // 2048*8*64 = 1048576
  int j = idx & 63;
  int h = (idx >> 6) & 7;
  int s = idx >> 9;
  size_t base = (size_t)s * KLD_ + h * 128 + j;
  float x1 = kvf[base], x2 = kvf[base + 64];
  float ang = (float)s * invf[j];
  float sn, cs; sincosf(ang, &sn, &cs);
  float o1 = x1 * cs - x2 * sn;
  float o2 = x2 * cs + x1 * sn;
  kvf[base] = o1; kvf[base + 64] = o2;
  size_t o = (size_t)h * 262144 + (size_t)s * 128 + j;
  float ys[2] = {o1, o2};
#pragma unroll
  for (int e = 0; e < 2; ++e) {
    float x = ys[e];
    unsigned short b0 = f2bf(x);
    float r = x - bf2f(b0);
    unsigned short b1 = f2bf(r);
    k0[o + e * 64] = b0; k1[o + e * 64] = b1; k2[o + e * 64] = f2bf(r - bf2f(b1));
  }
}

// ---------------- fused: sum2 Q partials + RoPE -> qb16 ----------------
__global__ __launch_bounds__(256) void rope_q_fuse(const float* __restrict__ qp,
                                                   const float* __restrict__ invf,
                                                   ushort_t* __restrict__ qb16) {
  int idx = blockIdx.x * 256 + threadIdx.x;   // 2048*32*64 = 4194304
  int j = idx & 63;
  int h = (idx >> 6) & 31;
  int s = idx >> 11;
  size_t base = (size_t)s * NQ_ + h * 128 + j;
  const size_t zs = (size_t)S_ * NQ_;
  float x1 = qp[base] + qp[base + zs];
  float x2 = qp[base + 64] + qp[base + 64 + zs];
  float ang = (float)s * invf[j];
  float sn, cs; sincosf(ang, &sn, &cs);
  qb16[base] = f2bf(x1 * cs - x2 * sn);
  qb16[base + 64] = f2bf(x2 * cs + x1 * sn);
}

// ---------------- per-row max + inv-denominator (causal) ----------------
__global__ __launch_bounds__(256) void rowstat_kernel(const float* __restrict__ s,
                                                      float* __restrict__ mx,
                                                      float* __restrict__ dinv) {
  const int row = blockIdx.x * 4 + (threadIdx.x >> 6);
  const int lane = threadIdx.x & 63;
  const int i = row & 127;
  const int jmax = S_ - OBS_ + i;
  const float* sp = s + (size_t)row * S_;
  float vals[32];
  float m = -INFINITY;
#pragma unroll
  for (int c = 0; c < 8; ++c) {
    int j0 = c * 256 + lane * 4;
    float4 v = *(const float4*)(sp + j0);
    float e0 = (j0 + 0 <= jmax) ? v.x * SCALE_ : -INFINITY;
    float e1 = (j0 + 1 <= jmax) ? v.y * SCALE_ : -INFINITY;
    float e2 = (j0 + 2 <= jmax) ? v.z * SCALE_ : -INFINITY;
    float e3 = (j0 + 3 <= jmax) ? v.w * SCALE_ : -INFINITY;
    vals[c * 4 + 0] = e0; vals[c * 4 + 1] = e1; vals[c * 4 + 2] = e2; vals[c * 4 + 3] = e3;
    m = fmaxf(m, fmaxf(fmaxf(e0, e1), fmaxf(e2, e3)));
  }
#pragma unroll
  for (int off = 1; off < 64; off <<= 1) m = fmaxf(m, __shfl_xor(m, off, 64));
  float ssum = 0.f;
#pragma unroll
  for (int c = 0; c < 32; ++c) ssum += expf(vals[c] - m);
#pragma unroll
  for (int off = 1; off < 64; off <<= 1) ssum += __shfl_xor(ssum, off, 64);
  if (lane == 0) { mx[row] = m; dinv[row] = 1.0f / ssum; }
}

// ---------------- column-sum stage 1 ----------------
__global__ __launch_bounds__(256) void colsum_part(const float* __restrict__ s,
                                                   const float* __restrict__ mx,
                                                   const float* __restrict__ dinv,
                                                   float* __restrict__ part) {
  __shared__ float mxl[64], dvl[64];
  const int jt = blockIdx.x, hk = blockIdx.y, rc = blockIdx.z;
  const int t = threadIdx.x;
  if (t < 64) {
    mxl[t] = mx[hk * 512 + rc * 64 + t];
    dvl[t] = dinv[hk * 512 + rc * 64 + t];
  }
  __syncthreads();
  const int j = jt * 256 + t;
  const float* sp = s + ((size_t)hk * 512 + rc * 64) * S_ + j;
  float acc = 0.f;
  for (int rr = 0; rr < 64; ++rr) {
    int i = (rc * 64 + rr) & 127;
    if (j <= S_ - OBS_ + i)
      acc += expf(sp[(size_t)rr * S_] * SCALE_ - mxl[rr]) * dvl[rr];
  }
  part[((size_t)rc * 8 + hk) * S_ + j] = acc;
}

// ---------------- column-sum stage 2 -> imp ----------------
__global__ void colsum_fin(const float* __restrict__ part, float* __restrict__ imp) {
  int idx = blockIdx.x * 256 + threadIdx.x;
  int hk = idx >> 11, j = idx & 2047;
  float acc = 0.f;
#pragma unroll
  for (int rc = 0; rc < 8; ++rc) acc += part[((size_t)rc * 8 + hk) * S_ + j];
  float cnt = (float)min(OBS_, S_ - j);
  imp[idx] = acc * 0.25f / cnt;
}

// ---------------- single-block radix select ----------------
__global__ __launch_bounds__(1024) void radix_all(const float* __restrict__ imp,
                                                  float* __restrict__ thr) {
  __shared__ unsigned hist[4][256];
  __shared__ unsigned pfx_s[4], need_s[4];
  const int t = threadIdx.x;
  if (t < 4) {
    pfx_s[t] = 0u;
    need_s[t] = (t == 0) ? 3225u : (t == 1) ? 3226u : (t == 2) ? 15320u : 15321u;
  }
  __syncthreads();
  for (int pass = 0; pass < 4; ++pass) {
    ((unsigned*)hist)[t] = 0u;
    __syncthreads();
    int shift = 24 - pass * 8;
    for (int idx = t; idx < NC_; idx += 1024) {
      int h = idx / (S_ - W_), j = idx - h * (S_ - W_);
      union { float f; unsigned u; } cv; cv.f = imp[h * S_ + j];
      unsigned u = cv.u;
#pragma unroll
      for (int q = 0; q < 4; ++q) {
        bool m = (pass == 0) || ((u >> (shift + 8)) == (pfx_s[q] >> (shift + 8)));
        if (m) atomicAdd(&hist[q][(u >> shift) & 255u], 1u);
      }
    }
    __syncthreads();
    if (t < 4) {
      unsigned need = need_s[t], cum = 0, pfx = pfx_s[t];
      for (int d = 0; d < 256; ++d) {
        unsigned c = hist[t][d];
        if (cum + c > need) { pfx |= ((unsigned)d) << shift; need_s[t] = need - cum; break; }
        cum += c;
      }
      pfx_s[t] = pfx;
    }
    __syncthreads();
  }
  if (t == 0) {
    union { unsigned u; float f; } c0, c1, c2, c3;
    c0.u = pfx_s[0]; c1.u = pfx_s[1]; c2.u = pfx_s[2]; c3.u = pfx_s[3];
    double fl = 0.2 * (double)(NC_ - 1) - 3225.0;
    double fh = 0.95 * (double)(NC_ - 1) - 15320.0;
    thr[0] = (float)((double)c2.f + ((double)c3.f - (double)c2.f) * fh);
    thr[1] = (float)((double)c0.f + ((double)c1.f - (double)c0.f) * fl);
  }
}

// ---------------- sparsify ----------------
__global__ __launch_bounds__(128) void sparsify_kernel(const float* __restrict__ kv,
                                                       const float* __restrict__ imp,
                                                       const float* __restrict__ thr,
                                                       ushort_t* __restrict__ ksp,
                                                       ushort_t* __restrict__ vsp,
                                                       float* __restrict__ ebias) {
  const int b = blockIdx.x;
  const int j = b >> 3;
  const int h = b & 7;
  const int t = threadIdx.x;
  float ipv = imp[h * S_ + j];
  bool dense = (j >= S_ - W_) || (j < 2);
  int lvl = dense ? 0 : ((ipv >= thr[0]) ? 0 : ((ipv < thr[1]) ? 2 : 1));
  if (t == 0) ebias[h * S_ + j] = (lvl == 2) ? -INFINITY : 0.0f;
  __shared__ float av[128];
  __shared__ float thv;
  size_t base_in = (size_t)j * KLD_ + h * D_;
  size_t base_out = (size_t)j * NKV_ + h * D_;
  float kvv = kv[base_in + t];
  av[t] = fabsf(kvv);
  __syncthreads();
  {
    float at = av[t]; int cnt = 0;
    for (int m = 0; m < 128; ++m) { float am = av[m]; cnt += (am < at) || (am == at && m < t); }
    if (cnt == THR_IDX_) thv = at;
  }
  __syncthreads();
  {
    bool keep = (lvl == 0) || (lvl == 1 && fabsf(kvv) >= thv);
    ksp[base_out + t] = f2bf(keep ? kvv : 0.0f);
  }
  __syncthreads();
  float vvv = kv[base_in + 1024 + t];
  av[t] = fabsf(vvv);
  __syncthreads();
  {
    float at = av[t]; int cnt = 0;
    for (int m = 0; m < 128; ++m) { float am = av[m]; cnt += (am < at) || (am == at && m < t); }
    if (cnt == THR_IDX_) thv = at;
  }
  __syncthreads();
  {
    bool keep = (lvl == 0) || (lvl == 1 && fabsf(vvv) >= thv);
    vsp[base_out + t] = f2bf(keep ? vvv : 0.0f);
  }
}

// ---------------- V transpose ----------------
__global__ __launch_bounds__(256) void vtrans_kernel(const ushort_t* __restrict__ vsp,
                                                     ushort_t* __restrict__ vspT) {
  __shared__ ushort_t tl[64][136];
  const int jt = blockIdx.x;
  const int hk = blockIdx.y;
  const int t = threadIdx.x;
#pragma unroll
  for (int i = 0; i < 4; ++i) {
    int idx = i * 256 + t;
    int j = idx >> 4, c = idx & 15;
    *(u16x8*)&tl[j][c * 8] = *(const u16x8*)(vsp + (size_t)(jt * 64 + j) * NKV_ + hk * 128 + c * 8);
  }
  __syncthreads();
  int d = t >> 1, j0 = (t & 1) * 32;
#pragma unroll
  for (int jj = 0; jj < 4; ++jj) {
    u16x8 v;
#pragma unroll
    for (int e = 0; e < 8; ++e) v[e] = tl[j0 + jj * 8 + e][d];
    *(u16x8*)(vspT + ((size_t)hk * 128 + d) * S_ + jt * 64 + j0 + jj * 8) = v;
  }
}

// ---------------- main attention ----------------
#define SPAD_ 66
__global__ __launch_bounds__(256) void attn_kernel(const ushort_t* __restrict__ qbp,
                                                   const ushort_t* __restrict__ ksp,
                                                   const ushort_t* __restrict__ vspT,
                                                   const float* __restrict__ ebias,
                                                   ushort_t* __restrict__ ob16) {
  __shared__ ushort_t k_lds[64 * 128];
  __shared__ ushort_t vT_lds[128 * 64];
  __shared__ float s_lds[4][16][SPAD_];
  const int b = blockIdx.x;
  const int xcd = b & 7;
  const int idx = b >> 3;
  const int h = xcd * 4 + (idx >> 4);
  const int p = idx & 15;
  const int hk = h >> 2;
  const int t = threadIdx.x;
  const int w = t >> 6, lane = t & 63;
  const int lc = lane & 15, lg = lane >> 4;

  const ushort_t* kbase = ksp + hk * D_;
  const ushort_t* vbase = vspT + (size_t)hk * D_ * S_;

  for (int strip = 0; strip < 2; ++strip) {
    const int qb = (strip == 0) ? p : 31 - p;
    const int q0 = qb * 64 + w * 16;
    s16x8 qfrag[4];
#pragma unroll
    for (int db = 0; db < 4; ++db)
      qfrag[db] = *(const s16x8*)(qbp + (size_t)(q0 + lc) * NQ_ + h * D_ + db * 32 + lg * 8);

    f32x4 o[8];
#pragma unroll
    for (int n = 0; n < 8; ++n) o[n] = 0.f;
    float mr[4] = {-INFINITY, -INFINITY, -INFINITY, -INFINITY};
    float lr[4] = {0.f, 0.f, 0.f, 0.f};

    const int ntj = qb + 1;
    for (int tj = 0; tj < ntj; ++tj) {
      const int j0 = tj * 64;
      __syncthreads();
#pragma unroll
      for (int i = 0; i < 4; ++i) {
        int slot = i * 256 + w * 64 + lane;
        int row = slot >> 4, c = slot & 15;
        const ushort_t* gp = kbase + (size_t)(j0 + row) * NKV_ + ((c ^ (row & 7)) * 8);
        gload_lds16(gp, &k_lds[(i * 256 + w * 64) * 8]);
      }
#pragma unroll
      for (int i = 0; i < 4; ++i) {
        int slot = i * 256 + w * 64 + lane;
        int d = slot >> 3, c = slot & 7;
        const ushort_t* gp = vbase + (size_t)d * S_ + j0 + ((c ^ (d & 7)) * 8);
        gload_lds16(gp, &vT_lds[(i * 256 + w * 64) * 8]);
      }
      __syncthreads();

      f32x4 sfr[4];
#pragma unroll
      for (int js = 0; js < 4; ++js) sfr[js] = 0.f;
#pragma unroll
      for (int js = 0; js < 4; ++js) {
        int row = js * 16 + lc;
#pragma unroll
        for (int db = 0; db < 4; ++db) {
          s16x8 kf = *(const s16x8*)&k_lds[row * 128 + (((db * 4 + lg) ^ (lc & 7)) * 8)];
          sfr[js] = __builtin_amdgcn_mfma_f32_16x16x32_bf16(qfrag[db], kf, sfr[js], 0, 0, 0);
        }
      }
      float eb[4];
#pragma unroll
      for (int js = 0; js < 4; ++js) eb[js] = ebias[hk * S_ + j0 + js * 16 + lc];

      const bool diag = (tj == qb);
      float sclv[4];
#pragma unroll
      for (int r = 0; r < 4; ++r) {
        float sv[4];
#pragma unroll
        for (int js = 0; js < 4; ++js) sv[js] = sfr[js][r] * SCALE_ + eb[js];
        if (diag) {
          int qrow = w * 16 + lg * 4 + r;
#pragma unroll
          for (int js = 0; js < 4; ++js)
            if (js * 16 + lc > qrow) sv[js] = -INFINITY;
        }
        float tm = fmaxf(fmaxf(sv[0], sv[1]), fmaxf(sv[2], sv[3]));
#pragma unroll
        for (int off = 1; off < 16; off <<= 1) tm = fmaxf(tm, __shfl_xor(tm, off, 64));
        float mnew = fmaxf(mr[r], tm);
        float scl = __expf(mr[r] - mnew);
        float ps = 0.f;
#pragma unroll
        for (int js = 0; js < 4; ++js) {
          float e = __expf(sv[js] - mnew);
          s_lds[w][lg * 4 + r][js * 16 + lc] = e;
          ps += e;
        }
#pragma unroll
        for (int off = 1; off < 16; off <<= 1) ps += __shfl_xor(ps, off, 64);
        lr[r] = lr[r] * scl + ps;
        mr[r] = mnew;
        sclv[r] = scl;
      }
#pragma unroll
      for (int n = 0; n < 8; ++n) {
        f32x4 ov = o[n];
#pragma unroll
        for (int r = 0; r < 4; ++r) ov[r] *= sclv[r];
        o[n] = ov;
      }
      asm volatile("s_waitcnt lgkmcnt(0)" ::: "memory");
      s16x8 pa[2];
#pragma unroll
      for (int ks = 0; ks < 2; ++ks) {
        float pv[8];
        *(f32x4*)&pv[0] = *(const f32x4*)&s_lds[w][lc][ks * 32 + lg * 8];
        *(f32x4*)&pv[4] = *(const f32x4*)&s_lds[w][lc][ks * 32 + lg * 8 + 4];
        s16x8 pk;
#pragma unroll
        for (int e = 0; e < 8; ++e) pk[e] = (short)f2bf(pv[e]);
        pa[ks] = pk;
      }
#pragma unroll
      for (int n = 0; n < 8; ++n) {
        int d = n * 16 + lc;
#pragma unroll
        for (int ks = 0; ks < 2; ++ks) {
          s16x8 vf = *(const s16x8*)&vT_lds[d * 64 + (((ks * 4 + lg) ^ (lc & 7)) * 8)];
          o[n] = __builtin_amdgcn_mfma_f32_16x16x32_bf16(pa[ks], vf, o[n], 0, 0, 0);
        }
      }
    }
#pragma unroll
    for (int r = 0; r < 4; ++r) {
      float rinv = 1.0f / lr[r];
      int row = q0 + lg * 4 + r;
#pragma unroll
      for (int n = 0; n < 8; ++n)
        ob16[(size_t)row * NQ_ + h * D_ + n * 16 + lc] = f2bf(o[n][r] * rinv);
    }
  }
}

// ---------------- launcher ----------------
extern "C" void kernel_launch(void* const* d_in, const int* in_sizes, int n_in,
                              void* d_out, int out_size, void* d_ws, size_t ws_size,
                              hipStream_t stream) {
  (void)in_sizes; (void)n_in; (void)out_size; (void)ws_size;
  const float* hid = (const float*)d_in[0];
  const float* wq  = (const float*)d_in[1];
  const float* wk  = (const float*)d_in[2];
  const float* wv  = (const float*)d_in[3];
  const float* wo  = (const float*)d_in[4];
  float* out = (float*)d_out;
  char* ws = (char*)d_ws;
  const size_t MB = 1ull << 20;

  // Overlay map (liveness vs launch order annotated):
  ushort_t* h0     = (ushort_t*)(ws + 0 * MB);     // A -> gemm1 Q
  ushort_t* h1     = (ushort_t*)(ws + 16 * MB);    // A -> kvsh
  ushort_t* h2     = (ushort_t*)(ws + 32 * MB);    // A -> kvsh
  ushort_t* wq0T   = (ushort_t*)(ws + 48 * MB);    // A -> gemm1 Q
  ushort_t* wq1T   = (ushort_t*)(ws + 80 * MB);    // A -> gemm6k
  ushort_t* wq2T   = (ushort_t*)(ws + 112 * MB);   // A -> gemm6k
  ushort_t* wkv0T  = (ushort_t*)(ws + 144 * MB);   // A -> kvsh
  ushort_t* wkv1T  = (ushort_t*)(ws + 160 * MB);   // A -> kvsh
  ushort_t* wkv2T  = (ushort_t*)(ws + 176 * MB);   // A -> kvsh
  float*    qpart  = (float*)(ws + 192 * MB);      // gemm6k -> qobs_fuse (16 MB)
  float*    kvf    = (float*)(ws + 192 * MB);      // reduce3 -> sparsify (over dead qpart)
  float*    kvp    = (float*)(ws + 80 * MB);       // kvsh partials 48 MB (over dead wq1T/2T)
  float*    qp2    = (float*)(ws + 80 * MB);       // Q partials 64 MB (over dead kvp, wq2T)
  ushort_t* qb16   = (ushort_t*)(ws + 16 * MB);    // rope_q_fuse -> attn (over dead h1)
  ushort_t* kb0    = (ushort_t*)(ws + 32 * MB);    // ropekv_splitk -> gemm6z (over dead h2)
  ushort_t* kb1    = (ushort_t*)(ws + 36 * MB);
  ushort_t* kb2    = (ushort_t*)(ws + 40 * MB);
  float*    s_obs  = (float*)(ws + 48 * MB);       // gemm6z -> colsum (32 MB over dead wq0T)
  ushort_t* woT    = (ushort_t*)(ws + 144 * MB);   // splitT wo -> outproj (over dead wkv0T/1T)
  ushort_t* ksp    = (ushort_t*)(ws + 176 * MB);   // sparsify -> attn (over dead wkv2T)
  ushort_t* vsp    = (ushort_t*)(ws + 180 * MB);
  ushort_t* vspT   = (ushort_t*)(ws + 184 * MB);
  ushort_t* ob16   = (ushort_t*)(ws + 188 * MB + 512 * 1024);  // attn -> outproj (over dead qp2 tail? no: 188.5-204.5; over nothing live)
  float*    opart  = (float*)(ws + 0 * MB);        // outproj partials 64 MB (over dead h0/qb16/kb/s_obs-head)
  ushort_t* qo0    = (ushort_t*)(ws + 208 * MB);   // qobs_fuse -> gemm6z
  ushort_t* qo1    = (ushort_t*)(ws + 209 * MB);
  ushort_t* qo2    = (ushort_t*)(ws + 210 * MB);
  char*     misc   = ws + 212 * MB;
  float*    impv   = (float*)(misc + 0);
  float*    eb     = (float*)(misc + 64 * 1024);
  float*    invf   = (float*)(misc + 128 * 1024);
  float*    thr    = (float*)(misc + 132 * 1024);
  float*    mxbuf  = (float*)(misc + 160 * 1024);
  float*    dinvb  = (float*)(misc + 192 * 1024);
  float*    part   = (float*)(misc + 256 * 1024);  // 512 KB

  freq_kernel<<<1, 64, 0, stream>>>(invf);

  // A) splits
  split3_kernel<<<(S_ * HID_ / 4 + 255) / 256, 256, 0, stream>>>(hid, h0, h1, h2, S_ * HID_ / 4);
  splitT_kernel<<<dim3(NQ_ / 64, HID_ / 64), 256, 0, stream>>>(wq, NQ_, wq0T, wq1T, wq2T);
  splitT_kernel<<<dim3(NKV_ / 64, HID_ / 64), 256, 0, stream>>>(wk, NKV_, wkv0T, wkv1T, wkv2T);
  splitT_kernel<<<dim3(NKV_ / 64, HID_ / 64), 256, 0, stream>>>(
      wv, NKV_, wkv0T + (size_t)NKV_ * HID_, wkv1T + (size_t)NKV_ * HID_, wkv2T + (size_t)NKV_ * HID_);

  // B) obs-Q GEMM (needs wq1T/2T) then fused sum+rope+split (kills qpart)
  const size_t obs_off = (size_t)(S_ - OBS_) * HID_;
  {
    TermPtrs P;
    P.a[0] = h0 + obs_off; P.b[0] = wq0T;
    P.a[1] = h0 + obs_off; P.b[1] = wq1T;
    P.a[2] = h1 + obs_off; P.b[2] = wq0T;
    P.a[3] = h1 + obs_off; P.b[3] = wq1T;
    P.a[4] = h0 + obs_off; P.b[4] = wq2T;
    P.a[5] = h2 + obs_off; P.b[5] = wq0T;
    gemm6k<<<dim3(NQ_ / 128, 1, 8), 256, 0, stream>>>(P, qpart, NQ_);
  }
  qobs_fuse<<<(OBS_ * HQ_ * 64) / 256, 256, 0, stream>>>(qpart, invf, qo0, qo1, qo2);

  // C) KV GEMM: operand-shared 3-way split + reduce3 (kvp over dead wq1T/2T)
  {
    KvSh P;
    P.S[0] = h0;    P.U0[0] = wkv1T; P.U1[0] = wkv2T; P.ash[0] = 1;  // h0w1 + h0w2
    P.S[1] = h1;    P.U0[1] = wkv0T; P.U1[1] = wkv1T; P.ash[1] = 1;  // h1w0 + h1w1
    P.S[2] = wkv0T; P.U0[2] = h0;    P.U1[2] = h2;    P.ash[2] = 0;  // h0w0 + h2w0
    gemm_kvsh<<<dim3(KLD_ / 128, S_ / 128, 3), 256, 0, stream>>>(P, kvp, S_, KLD_, HID_);
  }
  reduce3_kernel<<<(S_ * KLD_ / 4 + 255) / 256, 256, 0, stream>>>(kvp, kvf, S_ * KLD_ / 4);

  // D) Q main GEMM split-K z=2 (partials over dead kvp/wq2T)
  gemm1<<<dim3(NQ_ / 128, S_ / 128, 2), 256, 0, stream>>>(h0, wq0T, qp2, S_, NQ_, HID_, 32);

  // E) wo transpose+cast (over dead wkv0T/1T)
  splitT_kernel<<<dim3(HID_ / 64, HID_ / 64), 256, 0, stream>>>(wo, HID_, woT, nullptr, nullptr);

  // F) fused RoPE passes
  rope_q_fuse<<<(S_ * HQ_ * 64) / 256, 256, 0, stream>>>(qp2, invf, qb16);
  ropekv_splitk<<<(S_ * HKV_ * 64) / 256, 256, 0, stream>>>(kvf, invf, kb0, kb1, kb2);

  // G) obs importance
  {
    TermPtrs P;
    P.a[0] = qo0; P.b[0] = kb0;
    P.a[1] = qo0; P.b[1] = kb1;
    P.a[2] = qo1; P.b[2] = kb0;
    P.a[3] = qo1; P.b[3] = kb1;
    P.a[4] = qo0; P.b[4] = kb2;
    P.a[5] = qo2; P.b[5] = kb0;
    gemm6z<<<dim3(16, 4, 8), 256, 0, stream>>>(P, s_obs);
  }
  rowstat_kernel<<<1024, 256, 0, stream>>>(s_obs, mxbuf, dinvb);
  colsum_part<<<dim3(8, 8, 8), 256, 0, stream>>>(s_obs, mxbuf, dinvb, part);
  colsum_fin<<<64, 256, 0, stream>>>(part, impv);

  // H) quantile thresholds
  radix_all<<<1, 1024, 0, stream>>>(impv, thr);

  // I) sparsify + V-transpose + attention + out projection (split-K z=2)
  sparsify_kernel<<<S_ * HKV_, 128, 0, stream>>>(kvf, impv, thr, ksp, vsp, eb);
  vtrans_kernel<<<dim3(S_ / 64, HKV_), 256, 0, stream>>>(vsp, vspT);
  attn_kernel<<<512, 256, 0, stream>>>(qb16, ksp, vspT, eb, ob16);
  gemm1<<<dim3(HID_ / 128, S_ / 128, 2), 256, 0, stream>>>(ob16, woT, opart, S_, HID_, HID_, 32);
  reduce2_kernel<<<(S_ * HID_ / 4 + 255) / 256, 256, 0, stream>>>(opart, out, S_ * HID_ / 4);
}

// Round 8
// 974.899 us; speedup vs baseline: 1.0756x; 1.0756x over previous
//
#include <hip/hip_runtime.h>
#include <hip/hip_bf16.h>
#include <math.h>

#define S_    2048
#define HID_  4096
#define HQ_   32
#define HKV_  8
#define D_    128
#define G_    4
#define OBS_  128
#define W_    32
#define NKV_  1024
#define NQ_   4096
#define KLD_  2048
#define SCALE_ 0.08838834764831845f
#define THR_IDX_ 89
#define NC_   16128

typedef __attribute__((ext_vector_type(4))) float f32x4;
typedef __attribute__((ext_vector_type(8))) short s16x8;
typedef __attribute__((ext_vector_type(8))) unsigned short u16x8;
typedef __attribute__((ext_vector_type(4))) unsigned short u16x4;
typedef unsigned short ushort_t;

struct TermPtrs { const ushort_t* a[6]; const ushort_t* b[6]; };

__device__ __forceinline__ unsigned short f2bf(float x) {
  union { float f; unsigned u; } v; v.f = x;
  unsigned r = v.u + 0x7FFFu + ((v.u >> 16) & 1u);
  return (unsigned short)(r >> 16);
}
__device__ __forceinline__ float bf2f(unsigned short b) {
  union { unsigned u; float f; } v; v.u = ((unsigned)b) << 16;
  return v.f;
}
__device__ __forceinline__ void gload_lds16(const void* g, void* l) {
  __builtin_amdgcn_global_load_lds((const __attribute__((address_space(1))) unsigned int*)g,
                                   (__attribute__((address_space(3))) unsigned int*)l, 16, 0, 0);
}
__device__ __forceinline__ void term_sel(const TermPtrs& P, int tt,
                                         const ushort_t*& As, const ushort_t*& Bs) {
  switch (tt) {
    case 0: As = P.a[0]; Bs = P.b[0]; break;
    case 1: As = P.a[1]; Bs = P.b[1]; break;
    case 2: As = P.a[2]; Bs = P.b[2]; break;
    case 3: As = P.a[3]; Bs = P.b[3]; break;
    case 4: As = P.a[4]; Bs = P.b[4]; break;
    default: As = P.a[5]; Bs = P.b[5]; break;
  }
}
// XCD-aware bijective swizzle within the (x,y) plane; plane size must be %8==0.
__device__ __forceinline__ void xcd_bmbn(int& bm, int& bn) {
  int nplane = gridDim.x * gridDim.y;
  int l = blockIdx.y * gridDim.x + blockIdx.x;
  int v = (l & 7) * (nplane >> 3) + (l >> 3);
  bm = v / gridDim.x;
  bn = v - bm * gridDim.x;
}

// ---------------- split fp32 -> 3 bf16 terms ----------------
__global__ __launch_bounds__(256) void split3_kernel(const float* __restrict__ src,
                                                     ushort_t* __restrict__ d0,
                                                     ushort_t* __restrict__ d1,
                                                     ushort_t* __restrict__ d2, int n4) {
  int idx = blockIdx.x * 256 + threadIdx.x;
  if (idx >= n4) return;
  float4 v = ((const float4*)src)[idx];
  u16x4 o0, o1, o2;
  float xs[4] = {v.x, v.y, v.z, v.w};
#pragma unroll
  for (int e = 0; e < 4; ++e) {
    float x = xs[e];
    unsigned short b0 = f2bf(x);
    float r = x - bf2f(b0);
    unsigned short b1 = f2bf(r);
    o0[e] = b0; o1[e] = b1; o2[e] = f2bf(r - bf2f(b1));
  }
  *(u16x4*)(d0 + (size_t)idx * 4) = o0;
  *(u16x4*)(d1 + (size_t)idx * 4) = o1;
  *(u16x4*)(d2 + (size_t)idx * 4) = o2;
}

// ---------------- split + transpose weights ----------------
__global__ __launch_bounds__(256) void splitT_kernel(const float* __restrict__ src, int N,
                                                     ushort_t* __restrict__ t0,
                                                     ushort_t* __restrict__ t1,
                                                     ushort_t* __restrict__ t2) {
  __shared__ float tile[64][65];
  const int t = threadIdx.x;
  const int n0 = blockIdx.x * 64, k0 = blockIdx.y * 64;
#pragma unroll
  for (int i = 0; i < 16; ++i) {
    int idx = i * 256 + t;
    int r = idx >> 6, c = idx & 63;
    tile[r][c] = src[(size_t)(k0 + r) * N + n0 + c];
  }
  __syncthreads();
#pragma unroll
  for (int i = 0; i < 16; ++i) {
    int idx = i * 256 + t;
    int n = idx >> 6, kk = idx & 63;
    float x = tile[kk][n];
    unsigned short b0 = f2bf(x);
    size_t o = (size_t)(n0 + n) * HID_ + k0 + kk;
    t0[o] = b0;
    if (t1) {
      float r = x - bf2f(b0);
      unsigned short b1 = f2bf(r);
      t1[o] = b1;
      t2[o] = f2bf(r - bf2f(b1));
    }
  }
}

// ---------------- virtual-K bf16 MFMA GEMM (TPZ terms per grid.z) ----------------
template<int TPZ>
__global__ __launch_bounds__(256) void gemm6(TermPtrs P, float* __restrict__ Cbase,
                                             int M, int N, int K) {
  __shared__ ushort_t lds[2 * 128 * 64];
  const int t = threadIdx.x;
  const int wave = t >> 6, lane = t & 63;
  const int lc = lane & 15, lg = lane >> 4;
  int bm, bn;
  xcd_bmbn(bm, bn);
  const int z = blockIdx.z;
  const int wm = wave >> 1, wn = wave & 1;
  const int srow = t >> 3, schunk = t & 7;
  float* C = Cbase + (size_t)z * M * N;

  f32x4 acc[4][4];
#pragma unroll
  for (int fi = 0; fi < 4; ++fi)
#pragma unroll
    for (int fj = 0; fj < 4; ++fj) acc[fi][fj] = 0.f;

  for (int tt = z * TPZ; tt < z * TPZ + TPZ; ++tt) {
    const ushort_t *As, *Bs;
    term_sel(P, tt, As, Bs);
    for (int kb = 0; kb < K / 64; ++kb) {
      __syncthreads();
#pragma unroll
      for (int g = 0; g < 4; ++g) {
        int row = g * 32 + srow;
        int sw = schunk ^ (row & 7);
        gload_lds16(As + (size_t)(bm * 128 + row) * K + kb * 64 + sw * 8,
                    lds + g * 2048 + wave * 512);
        gload_lds16(Bs + (size_t)(bn * 128 + row) * K + kb * 64 + sw * 8,
                    lds + 8192 + g * 2048 + wave * 512);
      }
      __syncthreads();
#pragma unroll
      for (int ks = 0; ks < 2; ++ks) {
        s16x8 af[4], bf[4];
#pragma unroll
        for (int f = 0; f < 4; ++f) {
          int ra = wm * 64 + f * 16 + lc;
          af[f] = *(const s16x8*)(lds + ra * 64 + (((ks * 4 + lg) ^ (ra & 7)) * 8));
          int rb = wn * 64 + f * 16 + lc;
          bf[f] = *(const s16x8*)(lds + 8192 + rb * 64 + (((ks * 4 + lg) ^ (rb & 7)) * 8));
        }
#pragma unroll
        for (int fi = 0; fi < 4; ++fi)
#pragma unroll
          for (int fj = 0; fj < 4; ++fj)
            acc[fi][fj] = __builtin_amdgcn_mfma_f32_16x16x32_bf16(af[fi], bf[fj], acc[fi][fj], 0, 0, 0);
      }
    }
  }
#pragma unroll
  for (int fi = 0; fi < 4; ++fi)
#pragma unroll
    for (int fj = 0; fj < 4; ++fj)
#pragma unroll
      for (int r = 0; r < 4; ++r)
        C[(size_t)(bm * 128 + wm * 64 + fi * 16 + lg * 4 + r) * N +
          bn * 128 + wn * 64 + fj * 16 + lc] = acc[fi][fj][r];
}

// ---------------- single-term GEMM with split-K (z = K-chunk of KSTEPS*64) ----------------
__global__ __launch_bounds__(256) void gemm1(const ushort_t* __restrict__ A,
                                             const ushort_t* __restrict__ B,
                                             float* __restrict__ Cbase,
                                             int M, int N, int K, int KSTEPS) {
  __shared__ ushort_t lds[2 * 128 * 64];
  const int t = threadIdx.x;
  const int wave = t >> 6, lane = t & 63;
  const int lc = lane & 15, lg = lane >> 4;
  int bm, bn;
  xcd_bmbn(bm, bn);
  const int z = blockIdx.z;
  const int wm = wave >> 1, wn = wave & 1;
  const int srow = t >> 3, schunk = t & 7;
  float* C = Cbase + (size_t)z * M * N;

  f32x4 acc[4][4];
#pragma unroll
  for (int fi = 0; fi < 4; ++fi)
#pragma unroll
    for (int fj = 0; fj < 4; ++fj) acc[fi][fj] = 0.f;

  for (int kb = z * KSTEPS; kb < z * KSTEPS + KSTEPS; ++kb) {
    __syncthreads();
#pragma unroll
    for (int g = 0; g < 4; ++g) {
      int row = g * 32 + srow;
      int sw = schunk ^ (row & 7);
      size_t co = kb * 64 + sw * 8;
      gload_lds16(A + (size_t)(bm * 128 + row) * K + co, lds + g * 2048 + wave * 512);
      gload_lds16(B + (size_t)(bn * 128 + row) * K + co, lds + 8192 + g * 2048 + wave * 512);
    }
    __syncthreads();
#pragma unroll
    for (int ks = 0; ks < 2; ++ks) {
      s16x8 af[4], bf[4];
#pragma unroll
      for (int f = 0; f < 4; ++f) {
        int ra = wm * 64 + f * 16 + lc;
        af[f] = *(const s16x8*)(lds + ra * 64 + (((ks * 4 + lg) ^ (ra & 7)) * 8));
        int rb = wn * 64 + f * 16 + lc;
        bf[f] = *(const s16x8*)(lds + 8192 + rb * 64 + (((ks * 4 + lg) ^ (rb & 7)) * 8));
      }
#pragma unroll
      for (int fi = 0; fi < 4; ++fi)
#pragma unroll
        for (int fj = 0; fj < 4; ++fj)
          acc[fi][fj] = __builtin_amdgcn_mfma_f32_16x16x32_bf16(af[fi], bf[fj], acc[fi][fj], 0, 0, 0);
    }
  }
#pragma unroll
  for (int fi = 0; fi < 4; ++fi)
#pragma unroll
    for (int fj = 0; fj < 4; ++fj)
#pragma unroll
      for (int r = 0; r < 4; ++r)
        C[(size_t)(bm * 128 + wm * 64 + fi * 16 + lg * 4 + r) * N +
          bn * 128 + wn * 64 + fj * 16 + lc] = acc[fi][fj][r];
}

// ---------------- obs-Q: M=128, all 6 terms, z = K-slice of 512 ----------------
__global__ __launch_bounds__(256) void gemm6k(TermPtrs P, float* __restrict__ Cp, int N) {
  __shared__ ushort_t lds[2 * 128 * 64];
  const int t = threadIdx.x;
  const int wave = t >> 6, lane = t & 63;
  const int lc = lane & 15, lg = lane >> 4;
  const int bn = blockIdx.x, z = blockIdx.z;
  const int wm = wave >> 1, wn = wave & 1;
  const int srow = t >> 3, schunk = t & 7;
  float* C = Cp + (size_t)z * 128 * N;

  f32x4 acc[4][4];
#pragma unroll
  for (int fi = 0; fi < 4; ++fi)
#pragma unroll
    for (int fj = 0; fj < 4; ++fj) acc[fi][fj] = 0.f;

  for (int tt = 0; tt < 6; ++tt) {
    const ushort_t *As, *Bs;
    term_sel(P, tt, As, Bs);
    for (int kb = z * 8; kb < z * 8 + 8; ++kb) {
      __syncthreads();
#pragma unroll
      for (int g = 0; g < 4; ++g) {
        int row = g * 32 + srow;
        int sw = schunk ^ (row & 7);
        gload_lds16(As + (size_t)row * HID_ + kb * 64 + sw * 8,
                    lds + g * 2048 + wave * 512);
        gload_lds16(Bs + (size_t)(bn * 128 + row) * HID_ + kb * 64 + sw * 8,
                    lds + 8192 + g * 2048 + wave * 512);
      }
      __syncthreads();
#pragma unroll
      for (int ks = 0; ks < 2; ++ks) {
        s16x8 af[4], bf[4];
#pragma unroll
        for (int f = 0; f < 4; ++f) {
          int ra = wm * 64 + f * 16 + lc;
          af[f] = *(const s16x8*)(lds + ra * 64 + (((ks * 4 + lg) ^ (ra & 7)) * 8));
          int rb = wn * 64 + f * 16 + lc;
          bf[f] = *(const s16x8*)(lds + 8192 + rb * 64 + (((ks * 4 + lg) ^ (rb & 7)) * 8));
        }
#pragma unroll
        for (int fi = 0; fi < 4; ++fi)
#pragma unroll
          for (int fj = 0; fj < 4; ++fj)
            acc[fi][fj] = __builtin_amdgcn_mfma_f32_16x16x32_bf16(af[fi], bf[fj], acc[fi][fj], 0, 0, 0);
      }
    }
  }
#pragma unroll
  for (int fi = 0; fi < 4; ++fi)
#pragma unroll
    for (int fj = 0; fj < 4; ++fj)
#pragma unroll
      for (int r = 0; r < 4; ++r)
        C[(size_t)(wm * 64 + fi * 16 + lg * 4 + r) * N +
          bn * 128 + wn * 64 + fj * 16 + lc] = acc[fi][fj][r];
}

// ---------------- s_obs: all 6 terms, z = kv-head, K=128 ----------------
__global__ __launch_bounds__(256) void gemm6z(TermPtrs P, float* __restrict__ Cg) {
  __shared__ ushort_t lds[2 * 128 * 64];
  const int t = threadIdx.x;
  const int wave = t >> 6, lane = t & 63;
  const int lc = lane & 15, lg = lane >> 4;
  const int bm = blockIdx.y, bn = blockIdx.x, z = blockIdx.z;
  const int wm = wave >> 1, wn = wave & 1;
  const int srow = t >> 3, schunk = t & 7;
  const size_t Aoff = (size_t)z * 512 * 128;
  const size_t Boff = (size_t)z * 2048 * 128;
  float* C = Cg + (size_t)z * 512 * 2048;

  f32x4 acc[4][4];
#pragma unroll
  for (int fi = 0; fi < 4; ++fi)
#pragma unroll
    for (int fj = 0; fj < 4; ++fj) acc[fi][fj] = 0.f;

  for (int tt = 0; tt < 6; ++tt) {
    const ushort_t *As, *Bs;
    term_sel(P, tt, As, Bs);
    As += Aoff; Bs += Boff;
    for (int kb = 0; kb < 2; ++kb) {
      __syncthreads();
#pragma unroll
      for (int g = 0; g < 4; ++g) {
        int row = g * 32 + srow;
        int sw = schunk ^ (row & 7);
        gload_lds16(As + (size_t)(bm * 128 + row) * 128 + kb * 64 + sw * 8,
                    lds + g * 2048 + wave * 512);
        gload_lds16(Bs + (size_t)(bn * 128 + row) * 128 + kb * 64 + sw * 8,
                    lds + 8192 + g * 2048 + wave * 512);
      }
      __syncthreads();
#pragma unroll
      for (int ks = 0; ks < 2; ++ks) {
        s16x8 af[4], bf[4];
#pragma unroll
        for (int f = 0; f < 4; ++f) {
          int ra = wm * 64 + f * 16 + lc;
          af[f] = *(const s16x8*)(lds + ra * 64 + (((ks * 4 + lg) ^ (ra & 7)) * 8));
          int rb = wn * 64 + f * 16 + lc;
          bf[f] = *(const s16x8*)(lds + 8192 + rb * 64 + (((ks * 4 + lg) ^ (rb & 7)) * 8));
        }
#pragma unroll
        for (int fi = 0; fi < 4; ++fi)
#pragma unroll
          for (int fj = 0; fj < 4; ++fj)
            acc[fi][fj] = __builtin_amdgcn_mfma_f32_16x16x32_bf16(af[fi], bf[fj], acc[fi][fj], 0, 0, 0);
      }
    }
  }
#pragma unroll
  for (int fi = 0; fi < 4; ++fi)
#pragma unroll
    for (int fj = 0; fj < 4; ++fj)
#pragma unroll
      for (int r = 0; r < 4; ++r)
        C[(size_t)(bm * 128 + wm * 64 + fi * 16 + lg * 4 + r) * 2048 +
          bn * 128 + wn * 64 + fj * 16 + lc] = acc[fi][fj][r];
}

// ---------------- reductions ----------------
__global__ void reduce3_kernel(const float* __restrict__ p, float* __restrict__ out, int n4) {
  int idx = blockIdx.x * 256 + threadIdx.x;
  if (idx >= n4) return;
  const size_t n = (size_t)n4 * 4;
  float4 a = ((const float4*)p)[idx];
  float4 b = ((const float4*)(p + n))[idx];
  float4 c = ((const float4*)(p + 2 * n))[idx];
  float4 o;
  o.x = a.x + b.x + c.x; o.y = a.y + b.y + c.y;
  o.z = a.z + b.z + c.z; o.w = a.w + b.w + c.w;
  ((float4*)out)[idx] = o;
}
__global__ void reduce2_kernel(const float* __restrict__ p, float* __restrict__ out, int n4) {
  int idx = blockIdx.x * 256 + threadIdx.x;
  if (idx >= n4) return;
  const size_t n = (size_t)n4 * 4;
  float4 a = ((const float4*)p)[idx];
  float4 b = ((const float4*)(p + n))[idx];
  float4 o;
  o.x = a.x + b.x; o.y = a.y + b.y; o.z = a.z + b.z; o.w = a.w + b.w;
  ((float4*)out)[idx] = o;
}

// ---------------- inv_freq ----------------
__global__ void freq_kernel(float* __restrict__ invf) {
  int j = threadIdx.x;
  if (j < 64) invf[j] = (float)(1.0 / pow(500000.0, (double)j / 64.0));
}

// ---------------- fused: sum8 partials + RoPE + 3-split for obs-Q ----------------
__global__ __launch_bounds__(256) void qobs_fuse(const float* __restrict__ qpart,
                                                 const float* __restrict__ invf,
                                                 ushort_t* __restrict__ q0,
                                                 ushort_t* __restrict__ q1,
                                                 ushort_t* __restrict__ q2) {
  int idx = blockIdx.x * 256 + threadIdx.x;   // 128*32*64 = 262144
  int j = idx & 63;
  int hq = (idx >> 6) & 31;
  int i = idx >> 11;
  size_t base = (size_t)i * NQ_ + hq * 128 + j;
  float x1 = 0.f, x2 = 0.f;
#pragma unroll
  for (int z = 0; z < 8; ++z) {
    x1 += qpart[(size_t)z * OBS_ * NQ_ + base];
    x2 += qpart[(size_t)z * OBS_ * NQ_ + base + 64];
  }
  float ang = (float)(S_ - OBS_ + i) * invf[j];
  float sn, cs; sincosf(ang, &sn, &cs);
  float o1 = x1 * cs - x2 * sn;
  float o2 = x2 * cs + x1 * sn;
  int hk = hq >> 2, g = hq & 3;
  size_t o = (size_t)hk * 65536 + (size_t)(g * 128 + i) * 128 + j;
  float ys[2] = {o1, o2};
#pragma unroll
  for (int e = 0; e < 2; ++e) {
    float x = ys[e];
    unsigned short b0 = f2bf(x);
    float r = x - bf2f(b0);
    unsigned short b1 = f2bf(r);
    q0[o + e * 64] = b0; q1[o + e * 64] = b1; q2[o + e * 64] = f2bf(r - bf2f(b1));
  }
}

// ---------------- fused: RoPE K-half of kvf (in place) + 3-split to kb ----------------
__global__ __launch_bounds__(256) void ropekv_splitk(float* __restrict__ kvf,
                                                     const float* __restrict__ invf,
                                                     ushort_t* __restrict__ k0,
                                                     ushort_t* __restrict__ k1,
                                                     ushort_t* __restrict__ k2) {
  int idx = blockIdx.x * 256 + threadIdx.x;   // 2048*8*64 = 1048576
  int j = idx & 63;
  int h = (idx >> 6) & 7;
  int s = idx >> 9;
  size_t base = (size_t)s * KLD_ + h * 128 + j;
  float x1 = kvf[base], x2 = kvf[base + 64];
  float ang = (float)s * invf[j];
  float sn, cs; sincosf(ang, &sn, &cs);
  float o1 = x1 * cs - x2 * sn;
  float o2 = x2 * cs + x1 * sn;
  kvf[base] = o1; kvf[base + 64] = o2;
  size_t o = (size_t)h * 262144 + (size_t)s * 128 + j;
  float ys[2] = {o1, o2};
#pragma unroll
  for (int e = 0; e < 2; ++e) {
    float x = ys[e];
    unsigned short b0 = f2bf(x);
    float r = x - bf2f(b0);
    unsigned short b1 = f2bf(r);
    k0[o + e * 64] = b0; k1[o + e * 64] = b1; k2[o + e * 64] = f2bf(r - bf2f(b1));
  }
}

// ---------------- fused: sum2 Q partials + RoPE -> qb16 ----------------
__global__ __launch_bounds__(256) void rope_q_fuse(const float* __restrict__ qp,
                                                   const float* __restrict__ invf,
                                                   ushort_t* __restrict__ qb16) {
  int idx = blockIdx.x * 256 + threadIdx.x;   // 2048*32*64 = 4194304
  int j = idx & 63;
  int h = (idx >> 6) & 31;
  int s = idx >> 11;
  size_t base = (size_t)s * NQ_ + h * 128 + j;
  const size_t zs = (size_t)S_ * NQ_;
  float x1 = qp[base] + qp[base + zs];
  float x2 = qp[base + 64] + qp[base + 64 + zs];
  float ang = (float)s * invf[j];
  float sn, cs; sincosf(ang, &sn, &cs);
  qb16[base] = f2bf(x1 * cs - x2 * sn);
  qb16[base + 64] = f2bf(x2 * cs + x1 * sn);
}

// ---------------- per-row max + inv-denominator (causal) ----------------
__global__ __launch_bounds__(256) void rowstat_kernel(const float* __restrict__ s,
                                                      float* __restrict__ mx,
                                                      float* __restrict__ dinv) {
  const int row = blockIdx.x * 4 + (threadIdx.x >> 6);
  const int lane = threadIdx.x & 63;
  const int i = row & 127;
  const int jmax = S_ - OBS_ + i;
  const float* sp = s + (size_t)row * S_;
  float vals[32];
  float m = -INFINITY;
#pragma unroll
  for (int c = 0; c < 8; ++c) {
    int j0 = c * 256 + lane * 4;
    float4 v = *(const float4*)(sp + j0);
    float e0 = (j0 + 0 <= jmax) ? v.x * SCALE_ : -INFINITY;
    float e1 = (j0 + 1 <= jmax) ? v.y * SCALE_ : -INFINITY;
    float e2 = (j0 + 2 <= jmax) ? v.z * SCALE_ : -INFINITY;
    float e3 = (j0 + 3 <= jmax) ? v.w * SCALE_ : -INFINITY;
    vals[c * 4 + 0] = e0; vals[c * 4 + 1] = e1; vals[c * 4 + 2] = e2; vals[c * 4 + 3] = e3;
    m = fmaxf(m, fmaxf(fmaxf(e0, e1), fmaxf(e2, e3)));
  }
#pragma unroll
  for (int off = 1; off < 64; off <<= 1) m = fmaxf(m, __shfl_xor(m, off, 64));
  float ssum = 0.f;
#pragma unroll
  for (int c = 0; c < 32; ++c) ssum += expf(vals[c] - m);
#pragma unroll
  for (int off = 1; off < 64; off <<= 1) ssum += __shfl_xor(ssum, off, 64);
  if (lane == 0) { mx[row] = m; dinv[row] = 1.0f / ssum; }
}

// ---------------- column-sum stage 1 ----------------
__global__ __launch_bounds__(256) void colsum_part(const float* __restrict__ s,
                                                   const float* __restrict__ mx,
                                                   const float* __restrict__ dinv,
                                                   float* __restrict__ part) {
  __shared__ float mxl[64], dvl[64];
  const int jt = blockIdx.x, hk = blockIdx.y, rc = blockIdx.z;
  const int t = threadIdx.x;
  if (t < 64) {
    mxl[t] = mx[hk * 512 + rc * 64 + t];
    dvl[t] = dinv[hk * 512 + rc * 64 + t];
  }
  __syncthreads();
  const int j = jt * 256 + t;
  const float* sp = s + ((size_t)hk * 512 + rc * 64) * S_ + j;
  float acc = 0.f;
  for (int rr = 0; rr < 64; ++rr) {
    int i = (rc * 64 + rr) & 127;
    if (j <= S_ - OBS_ + i)
      acc += expf(sp[(size_t)rr * S_] * SCALE_ - mxl[rr]) * dvl[rr];
  }
  part[((size_t)rc * 8 + hk) * S_ + j] = acc;
}

// ---------------- column-sum stage 2 -> imp ----------------
__global__ void colsum_fin(const float* __restrict__ part, float* __restrict__ imp) {
  int idx = blockIdx.x * 256 + threadIdx.x;
  int hk = idx >> 11, j = idx & 2047;
  float acc = 0.f;
#pragma unroll
  for (int rc = 0; rc < 8; ++rc) acc += part[((size_t)rc * 8 + hk) * S_ + j];
  float cnt = (float)min(OBS_, S_ - j);
  imp[idx] = acc * 0.25f / cnt;
}

// ---------------- single-block radix select ----------------
__global__ __launch_bounds__(1024) void radix_all(const float* __restrict__ imp,
                                                  float* __restrict__ thr) {
  __shared__ unsigned hist[4][256];
  __shared__ unsigned pfx_s[4], need_s[4];
  const int t = threadIdx.x;
  if (t < 4) {
    pfx_s[t] = 0u;
    need_s[t] = (t == 0) ? 3225u : (t == 1) ? 3226u : (t == 2) ? 15320u : 15321u;
  }
  __syncthreads();
  for (int pass = 0; pass < 4; ++pass) {
    ((unsigned*)hist)[t] = 0u;
    __syncthreads();
    int shift = 24 - pass * 8;
    for (int idx = t; idx < NC_; idx += 1024) {
      int h = idx / (S_ - W_), j = idx - h * (S_ - W_);
      union { float f; unsigned u; } cv; cv.f = imp[h * S_ + j];
      unsigned u = cv.u;
#pragma unroll
      for (int q = 0; q < 4; ++q) {
        bool m = (pass == 0) || ((u >> (shift + 8)) == (pfx_s[q] >> (shift + 8)));
        if (m) atomicAdd(&hist[q][(u >> shift) & 255u], 1u);
      }
    }
    __syncthreads();
    if (t < 4) {
      unsigned need = need_s[t], cum = 0, pfx = pfx_s[t];
      for (int d = 0; d < 256; ++d) {
        unsigned c = hist[t][d];
        if (cum + c > need) { pfx |= ((unsigned)d) << shift; need_s[t] = need - cum; break; }
        cum += c;
      }
      pfx_s[t] = pfx;
    }
    __syncthreads();
  }
  if (t == 0) {
    union { unsigned u; float f; } c0, c1, c2, c3;
    c0.u = pfx_s[0]; c1.u = pfx_s[1]; c2.u = pfx_s[2]; c3.u = pfx_s[3];
    double fl = 0.2 * (double)(NC_ - 1) - 3225.0;
    double fh = 0.95 * (double)(NC_ - 1) - 15320.0;
    thr[0] = (float)((double)c2.f + ((double)c3.f - (double)c2.f) * fh);
    thr[1] = (float)((double)c0.f + ((double)c1.f - (double)c0.f) * fl);
  }
}

// ---------------- sparsify ----------------
__global__ __launch_bounds__(128) void sparsify_kernel(const float* __restrict__ kv,
                                                       const float* __restrict__ imp,
                                                       const float* __restrict__ thr,
                                                       ushort_t* __restrict__ ksp,
                                                       ushort_t* __restrict__ vsp,
                                                       float* __restrict__ ebias) {
  const int b = blockIdx.x;
  const int j = b >> 3;
  const int h = b & 7;
  const int t = threadIdx.x;
  float ipv = imp[h * S_ + j];
  bool dense = (j >= S_ - W_) || (j < 2);
  int lvl = dense ? 0 : ((ipv >= thr[0]) ? 0 : ((ipv < thr[1]) ? 2 : 1));
  if (t == 0) ebias[h * S_ + j] = (lvl == 2) ? -INFINITY : 0.0f;
  __shared__ float av[128];
  __shared__ float thv;
  size_t base_in = (size_t)j * KLD_ + h * D_;
  size_t base_out = (size_t)j * NKV_ + h * D_;
  float kvv = kv[base_in + t];
  av[t] = fabsf(kvv);
  __syncthreads();
  {
    float at = av[t]; int cnt = 0;
    for (int m = 0; m < 128; ++m) { float am = av[m]; cnt += (am < at) || (am == at && m < t); }
    if (cnt == THR_IDX_) thv = at;
  }
  __syncthreads();
  {
    bool keep = (lvl == 0) || (lvl == 1 && fabsf(kvv) >= thv);
    ksp[base_out + t] = f2bf(keep ? kvv : 0.0f);
  }
  __syncthreads();
  float vvv = kv[base_in + 1024 + t];
  av[t] = fabsf(vvv);
  __syncthreads();
  {
    float at = av[t]; int cnt = 0;
    for (int m = 0; m < 128; ++m) { float am = av[m]; cnt += (am < at) || (am == at && m < t); }
    if (cnt == THR_IDX_) thv = at;
  }
  __syncthreads();
  {
    bool keep = (lvl == 0) || (lvl == 1 && fabsf(vvv) >= thv);
    vsp[base_out + t] = f2bf(keep ? vvv : 0.0f);
  }
}

// ---------------- V transpose ----------------
__global__ __launch_bounds__(256) void vtrans_kernel(const ushort_t* __restrict__ vsp,
                                                     ushort_t* __restrict__ vspT) {
  __shared__ ushort_t tl[64][136];
  const int jt = blockIdx.x;
  const int hk = blockIdx.y;
  const int t = threadIdx.x;
#pragma unroll
  for (int i = 0; i < 4; ++i) {
    int idx = i * 256 + t;
    int j = idx >> 4, c = idx & 15;
    *(u16x8*)&tl[j][c * 8] = *(const u16x8*)(vsp + (size_t)(jt * 64 + j) * NKV_ + hk * 128 + c * 8);
  }
  __syncthreads();
  int d = t >> 1, j0 = (t & 1) * 32;
#pragma unroll
  for (int jj = 0; jj < 4; ++jj) {
    u16x8 v;
#pragma unroll
    for (int e = 0; e < 8; ++e) v[e] = tl[j0 + jj * 8 + e][d];
    *(u16x8*)(vspT + ((size_t)hk * 128 + d) * S_ + jt * 64 + j0 + jj * 8) = v;
  }
}

// ---------------- main attention ----------------
#define SPAD_ 66
__global__ __launch_bounds__(256) void attn_kernel(const ushort_t* __restrict__ qbp,
                                                   const ushort_t* __restrict__ ksp,
                                                   const ushort_t* __restrict__ vspT,
                                                   const float* __restrict__ ebias,
                                                   ushort_t* __restrict__ ob16) {
  __shared__ ushort_t k_lds[64 * 128];
  __shared__ ushort_t vT_lds[128 * 64];
  __shared__ float s_lds[4][16][SPAD_];
  const int b = blockIdx.x;
  const int xcd = b & 7;
  const int idx = b >> 3;
  const int h = xcd * 4 + (idx >> 4);
  const int p = idx & 15;
  const int hk = h >> 2;
  const int t = threadIdx.x;
  const int w = t >> 6, lane = t & 63;
  const int lc = lane & 15, lg = lane >> 4;

  const ushort_t* kbase = ksp + hk * D_;
  const ushort_t* vbase = vspT + (size_t)hk * D_ * S_;

  for (int strip = 0; strip < 2; ++strip) {
    const int qb = (strip == 0) ? p : 31 - p;
    const int q0 = qb * 64 + w * 16;
    s16x8 qfrag[4];
#pragma unroll
    for (int db = 0; db < 4; ++db)
      qfrag[db] = *(const s16x8*)(qbp + (size_t)(q0 + lc) * NQ_ + h * D_ + db * 32 + lg * 8);

    f32x4 o[8];
#pragma unroll
    for (int n = 0; n < 8; ++n) o[n] = 0.f;
    float mr[4] = {-INFINITY, -INFINITY, -INFINITY, -INFINITY};
    float lr[4] = {0.f, 0.f, 0.f, 0.f};

    const int ntj = qb + 1;
    for (int tj = 0; tj < ntj; ++tj) {
      const int j0 = tj * 64;
      __syncthreads();
#pragma unroll
      for (int i = 0; i < 4; ++i) {
        int slot = i * 256 + w * 64 + lane;
        int row = slot >> 4, c = slot & 15;
        const ushort_t* gp = kbase + (size_t)(j0 + row) * NKV_ + ((c ^ (row & 7)) * 8);
        gload_lds16(gp, &k_lds[(i * 256 + w * 64) * 8]);
      }
#pragma unroll
      for (int i = 0; i < 4; ++i) {
        int slot = i * 256 + w * 64 + lane;
        int d = slot >> 3, c = slot & 7;
        const ushort_t* gp = vbase + (size_t)d * S_ + j0 + ((c ^ (d & 7)) * 8);
        gload_lds16(gp, &vT_lds[(i * 256 + w * 64) * 8]);
      }
      __syncthreads();

      f32x4 sfr[4];
#pragma unroll
      for (int js = 0; js < 4; ++js) sfr[js] = 0.f;
#pragma unroll
      for (int js = 0; js < 4; ++js) {
        int row = js * 16 + lc;
#pragma unroll
        for (int db = 0; db < 4; ++db) {
          s16x8 kf = *(const s16x8*)&k_lds[row * 128 + (((db * 4 + lg) ^ (lc & 7)) * 8)];
          sfr[js] = __builtin_amdgcn_mfma_f32_16x16x32_bf16(qfrag[db], kf, sfr[js], 0, 0, 0);
        }
      }
      float eb[4];
#pragma unroll
      for (int js = 0; js < 4; ++js) eb[js] = ebias[hk * S_ + j0 + js * 16 + lc];

      const bool diag = (tj == qb);
      float sclv[4];
#pragma unroll
      for (int r = 0; r < 4; ++r) {
        float sv[4];
#pragma unroll
        for (int js = 0; js < 4; ++js) sv[js] = sfr[js][r] * SCALE_ + eb[js];
        if (diag) {
          int qrow = w * 16 + lg * 4 + r;
#pragma unroll
          for (int js = 0; js < 4; ++js)
            if (js * 16 + lc > qrow) sv[js] = -INFINITY;
        }
        float tm = fmaxf(fmaxf(sv[0], sv[1]), fmaxf(sv[2], sv[3]));
#pragma unroll
        for (int off = 1; off < 16; off <<= 1) tm = fmaxf(tm, __shfl_xor(tm, off, 64));
        float mnew = fmaxf(mr[r], tm);
        float scl = __expf(mr[r] - mnew);
        float ps = 0.f;
#pragma unroll
        for (int js = 0; js < 4; ++js) {
          float e = __expf(sv[js] - mnew);
          s_lds[w][lg * 4 + r][js * 16 + lc] = e;
          ps += e;
        }
#pragma unroll
        for (int off = 1; off < 16; off <<= 1) ps += __shfl_xor(ps, off, 64);
        lr[r] = lr[r] * scl + ps;
        mr[r] = mnew;
        sclv[r] = scl;
      }
#pragma unroll
      for (int n = 0; n < 8; ++n) {
        f32x4 ov = o[n];
#pragma unroll
        for (int r = 0; r < 4; ++r) ov[r] *= sclv[r];
        o[n] = ov;
      }
      asm volatile("s_waitcnt lgkmcnt(0)" ::: "memory");
      s16x8 pa[2];
#pragma unroll
      for (int ks = 0; ks < 2; ++ks) {
        float pv[8];
        *(f32x4*)&pv[0] = *(const f32x4*)&s_lds[w][lc][ks * 32 + lg * 8];
        *(f32x4*)&pv[4] = *(const f32x4*)&s_lds[w][lc][ks * 32 + lg * 8 + 4];
        s16x8 pk;
#pragma unroll
        for (int e = 0; e < 8; ++e) pk[e] = (short)f2bf(pv[e]);
        pa[ks] = pk;
      }
#pragma unroll
      for (int n = 0; n < 8; ++n) {
        int d = n * 16 + lc;
#pragma unroll
        for (int ks = 0; ks < 2; ++ks) {
          s16x8 vf = *(const s16x8*)&vT_lds[d * 64 + (((ks * 4 + lg) ^ (lc & 7)) * 8)];
          o[n] = __builtin_amdgcn_mfma_f32_16x16x32_bf16(pa[ks], vf, o[n], 0, 0, 0);
        }
      }
    }
#pragma unroll
    for (int r = 0; r < 4; ++r) {
      float rinv = 1.0f / lr[r];
      int row = q0 + lg * 4 + r;
#pragma unroll
      for (int n = 0; n < 8; ++n)
        ob16[(size_t)row * NQ_ + h * D_ + n * 16 + lc] = f2bf(o[n][r] * rinv);
    }
  }
}

// ---------------- launcher ----------------
extern "C" void kernel_launch(void* const* d_in, const int* in_sizes, int n_in,
                              void* d_out, int out_size, void* d_ws, size_t ws_size,
                              hipStream_t stream) {
  (void)in_sizes; (void)n_in; (void)out_size; (void)ws_size;
  const float* hid = (const float*)d_in[0];
  const float* wq  = (const float*)d_in[1];
  const float* wk  = (const float*)d_in[2];
  const float* wv  = (const float*)d_in[3];
  const float* wo  = (const float*)d_in[4];
  float* out = (float*)d_out;
  char* ws = (char*)d_ws;
  const size_t MB = 1ull << 20;

  // Overlay map (liveness vs launch order annotated):
  ushort_t* h0     = (ushort_t*)(ws + 0 * MB);     // A -> gemm1 Q (D)
  ushort_t* h1     = (ushort_t*)(ws + 16 * MB);    // A -> gemm6 KV (C)
  ushort_t* h2     = (ushort_t*)(ws + 32 * MB);    // A -> gemm6 KV (C)
  ushort_t* wq0T   = (ushort_t*)(ws + 48 * MB);    // A -> gemm1 Q (D); 32 MB
  ushort_t* wq1T   = (ushort_t*)(ws + 80 * MB);    // A -> gemm6k (B); 32 MB
  ushort_t* wq2T   = (ushort_t*)(ws + 112 * MB);   // A -> gemm6k (B); 32 MB
  ushort_t* wkv0T  = (ushort_t*)(ws + 144 * MB);   // A -> gemm6 KV (C)
  ushort_t* wkv1T  = (ushort_t*)(ws + 160 * MB);   // A -> gemm6 KV (C)
  ushort_t* wkv2T  = (ushort_t*)(ws + 176 * MB);   // A -> gemm6 KV (C)
  float*    qpart  = (float*)(ws + 192 * MB);      // gemm6k -> qobs_fuse (16 MB)
  float*    kvf    = (float*)(ws + 192 * MB);      // reduce3 (C) -> sparsify (I), over dead qpart
  float*    kvp    = (float*)(ws + 80 * MB);       // gemm6 KV partials 48 MB (over dead wq1T/2T)
  float*    qp2    = (float*)(ws + 80 * MB);       // Q partials 64 MB (over dead kvp)
  ushort_t* qb16   = (ushort_t*)(ws + 16 * MB);    // rope_q_fuse (F) -> attn (I), over dead h1
  ushort_t* kb0    = (ushort_t*)(ws + 32 * MB);    // ropekv_splitk (F) -> gemm6z (G), over dead h2
  ushort_t* kb1    = (ushort_t*)(ws + 36 * MB);
  ushort_t* kb2    = (ushort_t*)(ws + 40 * MB);
  float*    s_obs  = (float*)(ws + 48 * MB);       // gemm6z (G) -> colsum (G), 32 MB over dead wq0T
  ushort_t* woT    = (ushort_t*)(ws + 144 * MB);   // splitT wo (E) -> outproj (I)
  ushort_t* ksp    = (ushort_t*)(ws + 176 * MB);   // sparsify -> attn (I)
  ushort_t* vsp    = (ushort_t*)(ws + 180 * MB);
  ushort_t* vspT   = (ushort_t*)(ws + 184 * MB);
  ushort_t* ob16   = (ushort_t*)(ws + 188 * MB + 512 * 1024);  // attn -> outproj (I)
  float*    opart  = (float*)(ws + 0 * MB);        // outproj partials 64 MB (I-last)
  ushort_t* qo0    = (ushort_t*)(ws + 208 * MB);   // qobs_fuse -> gemm6z
  ushort_t* qo1    = (ushort_t*)(ws + 209 * MB);
  ushort_t* qo2    = (ushort_t*)(ws + 210 * MB);
  char*     misc   = ws + 212 * MB;
  float*    impv   = (float*)(misc + 0);
  float*    eb     = (float*)(misc + 64 * 1024);
  float*    invf   = (float*)(misc + 128 * 1024);
  float*    thr    = (float*)(misc + 132 * 1024);
  float*    mxbuf  = (float*)(misc + 160 * 1024);
  float*    dinvb  = (float*)(misc + 192 * 1024);
  float*    part   = (float*)(misc + 256 * 1024);  // 512 KB

  freq_kernel<<<1, 64, 0, stream>>>(invf);

  // A) splits
  split3_kernel<<<(S_ * HID_ / 4 + 255) / 256, 256, 0, stream>>>(hid, h0, h1, h2, S_ * HID_ / 4);
  splitT_kernel<<<dim3(NQ_ / 64, HID_ / 64), 256, 0, stream>>>(wq, NQ_, wq0T, wq1T, wq2T);
  splitT_kernel<<<dim3(NKV_ / 64, HID_ / 64), 256, 0, stream>>>(wk, NKV_, wkv0T, wkv1T, wkv2T);
  splitT_kernel<<<dim3(NKV_ / 64, HID_ / 64), 256, 0, stream>>>(
      wv, NKV_, wkv0T + (size_t)NKV_ * HID_, wkv1T + (size_t)NKV_ * HID_, wkv2T + (size_t)NKV_ * HID_);

  // B) obs-Q GEMM then fused sum+rope+split (kills qpart)
  const size_t obs_off = (size_t)(S_ - OBS_) * HID_;
  {
    TermPtrs P;
    P.a[0] = h0 + obs_off; P.b[0] = wq0T;
    P.a[1] = h0 + obs_off; P.b[1] = wq1T;
    P.a[2] = h1 + obs_off; P.b[2] = wq0T;
    P.a[3] = h1 + obs_off; P.b[3] = wq1T;
    P.a[4] = h0 + obs_off; P.b[4] = wq2T;
    P.a[5] = h2 + obs_off; P.b[5] = wq0T;
    gemm6k<<<dim3(NQ_ / 128, 1, 8), 256, 0, stream>>>(P, qpart, NQ_);
  }
  qobs_fuse<<<(OBS_ * HQ_ * 64) / 256, 256, 0, stream>>>(qpart, invf, qo0, qo1, qo2);

  // C) KV GEMM: 6-term virtual-K, 2 terms per z (round-6 best: 92 VGPR, 32 KB LDS) + reduce3
  {
    TermPtrs P;
    P.a[0] = h0; P.b[0] = wkv0T;
    P.a[1] = h0; P.b[1] = wkv1T;
    P.a[2] = h1; P.b[2] = wkv0T;
    P.a[3] = h1; P.b[3] = wkv1T;
    P.a[4] = h0; P.b[4] = wkv2T;
    P.a[5] = h2; P.b[5] = wkv0T;
    gemm6<2><<<dim3(KLD_ / 128, S_ / 128, 3), 256, 0, stream>>>(P, kvp, S_, KLD_, HID_);
  }
  reduce3_kernel<<<(S_ * KLD_ / 4 + 255) / 256, 256, 0, stream>>>(kvp, kvf, S_ * KLD_ / 4);

  // D) Q main GEMM split-K z=2 (partials over dead kvp)
  gemm1<<<dim3(NQ_ / 128, S_ / 128, 2), 256, 0, stream>>>(h0, wq0T, qp2, S_, NQ_, HID_, 32);

  // E) wo transpose+cast
  splitT_kernel<<<dim3(HID_ / 64, HID_ / 64), 256, 0, stream>>>(wo, HID_, woT, nullptr, nullptr);

  // F) fused RoPE passes
  rope_q_fuse<<<(S_ * HQ_ * 64) / 256, 256, 0, stream>>>(qp2, invf, qb16);
  ropekv_splitk<<<(S_ * HKV_ * 64) / 256, 256, 0, stream>>>(kvf, invf, kb0, kb1, kb2);

  // G) obs importance
  {
    TermPtrs P;
    P.a[0] = qo0; P.b[0] = kb0;
    P.a[1] = qo0; P.b[1] = kb1;
    P.a[2] = qo1; P.b[2] = kb0;
    P.a[3] = qo1; P.b[3] = kb1;
    P.a[4] = qo0; P.b[4] = kb2;
    P.a[5] = qo2; P.b[5] = kb0;
    gemm6z<<<dim3(16, 4, 8), 256, 0, stream>>>(P, s_obs);
  }
  rowstat_kernel<<<1024, 256, 0, stream>>>(s_obs, mxbuf, dinvb);
  colsum_part<<<dim3(8, 8, 8), 256, 0, stream>>>(s_obs, mxbuf, dinvb, part);
  colsum_fin<<<64, 256, 0, stream>>>(part, impv);

  // H) quantile thresholds
  radix_all<<<1, 1024, 0, stream>>>(impv, thr);

  // I) sparsify + V-transpose + attention + out projection (split-K z=2)
  sparsify_kernel<<<S_ * HKV_, 128, 0, stream>>>(kvf, impv, thr, ksp, vsp, eb);
  vtrans_kernel<<<dim3(S_ / 64, HKV_), 256, 0, stream>>>(vsp, vspT);
  attn_kernel<<<512, 256, 0, stream>>>(qb16, ksp, vspT, eb, ob16);
  gemm1<<<dim3(HID_ / 128, S_ / 128, 2), 256, 0, stream>>>(ob16, woT, opart, S_, HID_, HID_, 32);
  reduce2_kernel<<<(S_ * HID_ / 4 + 255) / 256, 256, 0, stream>>>(opart, out, S_ * HID_ / 4);
}

// Round 9
// 855.871 us; speedup vs baseline: 1.2252x; 1.1391x over previous
//
#include <hip/hip_runtime.h>
#include <hip/hip_bf16.h>
#include <math.h>

#define S_    2048
#define HID_  4096
#define HQ_   32
#define HKV_  8
#define D_    128
#define G_    4
#define OBS_  128
#define W_    32
#define NKV_  1024
#define NQ_   4096
#define KLD_  2048
#define SCALE_ 0.08838834764831845f
#define THR_IDX_ 89
#define NC_   16128

typedef __attribute__((ext_vector_type(4))) float f32x4;
typedef __attribute__((ext_vector_type(8))) short s16x8;
typedef __attribute__((ext_vector_type(8))) unsigned short u16x8;
typedef __attribute__((ext_vector_type(4))) unsigned short u16x4;
typedef unsigned short ushort_t;

struct TermPtrs { const ushort_t* a[6]; const ushort_t* b[6]; };
struct Six { const ushort_t* A[3]; const ushort_t* B[3]; };

__device__ __forceinline__ unsigned short f2bf(float x) {
  union { float f; unsigned u; } v; v.f = x;
  unsigned r = v.u + 0x7FFFu + ((v.u >> 16) & 1u);
  return (unsigned short)(r >> 16);
}
__device__ __forceinline__ float bf2f(unsigned short b) {
  union { unsigned u; float f; } v; v.u = ((unsigned)b) << 16;
  return v.f;
}
__device__ __forceinline__ void gload_lds16(const void* g, void* l) {
  __builtin_amdgcn_global_load_lds((const __attribute__((address_space(1))) unsigned int*)g,
                                   (__attribute__((address_space(3))) unsigned int*)l, 16, 0, 0);
}
__device__ __forceinline__ void term_sel(const TermPtrs& P, int tt,
                                         const ushort_t*& As, const ushort_t*& Bs) {
  switch (tt) {
    case 0: As = P.a[0]; Bs = P.b[0]; break;
    case 1: As = P.a[1]; Bs = P.b[1]; break;
    case 2: As = P.a[2]; Bs = P.b[2]; break;
    case 3: As = P.a[3]; Bs = P.b[3]; break;
    case 4: As = P.a[4]; Bs = P.b[4]; break;
    default: As = P.a[5]; Bs = P.b[5]; break;
  }
}
// XCD-aware bijective swizzle within the (x,y) plane; plane size must be %8==0.
__device__ __forceinline__ void xcd_bmbn(int& bm, int& bn) {
  int nplane = gridDim.x * gridDim.y;
  int l = blockIdx.y * gridDim.x + blockIdx.x;
  int v = (l & 7) * (nplane >> 3) + (l >> 3);
  bm = v / gridDim.x;
  bn = v - bm * gridDim.x;
}

// ---------------- split fp32 -> 3 bf16 terms ----------------
__global__ __launch_bounds__(256) void split3_kernel(const float* __restrict__ src,
                                                     ushort_t* __restrict__ d0,
                                                     ushort_t* __restrict__ d1,
                                                     ushort_t* __restrict__ d2, int n4) {
  int idx = blockIdx.x * 256 + threadIdx.x;
  if (idx >= n4) return;
  float4 v = ((const float4*)src)[idx];
  u16x4 o0, o1, o2;
  float xs[4] = {v.x, v.y, v.z, v.w};
#pragma unroll
  for (int e = 0; e < 4; ++e) {
    float x = xs[e];
    unsigned short b0 = f2bf(x);
    float r = x - bf2f(b0);
    unsigned short b1 = f2bf(r);
    o0[e] = b0; o1[e] = b1; o2[e] = f2bf(r - bf2f(b1));
  }
  *(u16x4*)(d0 + (size_t)idx * 4) = o0;
  *(u16x4*)(d1 + (size_t)idx * 4) = o1;
  *(u16x4*)(d2 + (size_t)idx * 4) = o2;
}

// ---------------- split + transpose weights ----------------
__global__ __launch_bounds__(256) void splitT_kernel(const float* __restrict__ src, int N,
                                                     ushort_t* __restrict__ t0,
                                                     ushort_t* __restrict__ t1,
                                                     ushort_t* __restrict__ t2) {
  __shared__ float tile[64][65];
  const int t = threadIdx.x;
  const int n0 = blockIdx.x * 64, k0 = blockIdx.y * 64;
#pragma unroll
  for (int i = 0; i < 16; ++i) {
    int idx = i * 256 + t;
    int r = idx >> 6, c = idx & 63;
    tile[r][c] = src[(size_t)(k0 + r) * N + n0 + c];
  }
  __syncthreads();
#pragma unroll
  for (int i = 0; i < 16; ++i) {
    int idx = i * 256 + t;
    int n = idx >> 6, kk = idx & 63;
    float x = tile[kk][n];
    unsigned short b0 = f2bf(x);
    size_t o = (size_t)(n0 + n) * HID_ + k0 + kk;
    t0[o] = b0;
    if (t1) {
      float r = x - bf2f(b0);
      unsigned short b1 = f2bf(r);
      t1[o] = b1;
      t2[o] = f2bf(r - bf2f(b1));
    }
  }
}

// ---------------- 6-term shared-stage GEMM (BK=32, all terms into one acc) ----------
// Terms: A0B0, A0B1, A0B2, A1B0, A1B1, A2B0. C partial per z (split-K, KSTEPS kb of 32).
__global__ __launch_bounds__(256) void gemm6s(Six P, float* __restrict__ Cbase,
                                              int M, int N, int K, int KSTEPS) {
  __shared__ ushort_t lds[6 * 128 * 32];   // 6 x 8KB = 48KB
  const int t = threadIdx.x;
  const int wave = t >> 6, lane = t & 63;
  const int lc = lane & 15, lg = lane >> 4;
  int bm, bn;
  xcd_bmbn(bm, bn);
  const int z = blockIdx.z;
  const int wm = wave >> 1, wn = wave & 1;
  float* C = Cbase + (size_t)z * M * N;

  f32x4 acc[4][4];
#pragma unroll
  for (int fi = 0; fi < 4; ++fi)
#pragma unroll
    for (int fj = 0; fj < 4; ++fj) acc[fi][fj] = 0.f;

  for (int kb = z * KSTEPS; kb < z * KSTEPS + KSTEPS; ++kb) {
    __syncthreads();
#pragma unroll
    for (int ti = 0; ti < 6; ++ti) {
      const ushort_t* src = (ti < 3) ? P.A[ti] : P.B[ti - 3];
      const int rb = ((ti < 3) ? bm : bn) * 128;
#pragma unroll
      for (int it = 0; it < 2; ++it) {
        int slot = it * 256 + t;            // 512 x 16B chunks per tile
        int row = slot >> 2, c = slot & 3;
        int sw = c ^ (row & 3);
        gload_lds16(src + (size_t)(rb + row) * K + kb * 32 + sw * 8,
                    lds + ti * 4096 + it * 2048 + wave * 512);
      }
    }
    __syncthreads();
    // load A fragments once
    s16x8 a0[4], a1[4], a2[4], bfr[4];
#pragma unroll
    for (int f = 0; f < 4; ++f) {
      int ra = wm * 64 + f * 16 + lc;
      int ca = (lg ^ (ra & 3)) * 8;
      a0[f] = *(const s16x8*)(lds + 0 * 4096 + ra * 32 + ca);
      a1[f] = *(const s16x8*)(lds + 1 * 4096 + ra * 32 + ca);
      a2[f] = *(const s16x8*)(lds + 2 * 4096 + ra * 32 + ca);
    }
    // B0: products A0B0, A1B0, A2B0
#pragma unroll
    for (int f = 0; f < 4; ++f) {
      int rb2 = wn * 64 + f * 16 + lc;
      bfr[f] = *(const s16x8*)(lds + 3 * 4096 + rb2 * 32 + ((lg ^ (rb2 & 3)) * 8));
    }
#pragma unroll
    for (int fi = 0; fi < 4; ++fi)
#pragma unroll
      for (int fj = 0; fj < 4; ++fj) {
        acc[fi][fj] = __builtin_amdgcn_mfma_f32_16x16x32_bf16(a0[fi], bfr[fj], acc[fi][fj], 0, 0, 0);
        acc[fi][fj] = __builtin_amdgcn_mfma_f32_16x16x32_bf16(a1[fi], bfr[fj], acc[fi][fj], 0, 0, 0);
        acc[fi][fj] = __builtin_amdgcn_mfma_f32_16x16x32_bf16(a2[fi], bfr[fj], acc[fi][fj], 0, 0, 0);
      }
    // B1: products A0B1, A1B1
#pragma unroll
    for (int f = 0; f < 4; ++f) {
      int rb2 = wn * 64 + f * 16 + lc;
      bfr[f] = *(const s16x8*)(lds + 4 * 4096 + rb2 * 32 + ((lg ^ (rb2 & 3)) * 8));
    }
#pragma unroll
    for (int fi = 0; fi < 4; ++fi)
#pragma unroll
      for (int fj = 0; fj < 4; ++fj) {
        acc[fi][fj] = __builtin_amdgcn_mfma_f32_16x16x32_bf16(a0[fi], bfr[fj], acc[fi][fj], 0, 0, 0);
        acc[fi][fj] = __builtin_amdgcn_mfma_f32_16x16x32_bf16(a1[fi], bfr[fj], acc[fi][fj], 0, 0, 0);
      }
    // B2: product A0B2
#pragma unroll
    for (int f = 0; f < 4; ++f) {
      int rb2 = wn * 64 + f * 16 + lc;
      bfr[f] = *(const s16x8*)(lds + 5 * 4096 + rb2 * 32 + ((lg ^ (rb2 & 3)) * 8));
    }
#pragma unroll
    for (int fi = 0; fi < 4; ++fi)
#pragma unroll
      for (int fj = 0; fj < 4; ++fj)
        acc[fi][fj] = __builtin_amdgcn_mfma_f32_16x16x32_bf16(a0[fi], bfr[fj], acc[fi][fj], 0, 0, 0);
  }
#pragma unroll
  for (int fi = 0; fi < 4; ++fi)
#pragma unroll
    for (int fj = 0; fj < 4; ++fj)
#pragma unroll
      for (int r = 0; r < 4; ++r)
        C[(size_t)(bm * 128 + wm * 64 + fi * 16 + lg * 4 + r) * N +
          bn * 128 + wn * 64 + fj * 16 + lc] = acc[fi][fj][r];
}

// ---------------- single-term GEMM with split-K (z = K-chunk of KSTEPS*64) ----------------
__global__ __launch_bounds__(256) void gemm1(const ushort_t* __restrict__ A,
                                             const ushort_t* __restrict__ B,
                                             float* __restrict__ Cbase,
                                             int M, int N, int K, int KSTEPS) {
  __shared__ ushort_t lds[2 * 128 * 64];
  const int t = threadIdx.x;
  const int wave = t >> 6, lane = t & 63;
  const int lc = lane & 15, lg = lane >> 4;
  int bm, bn;
  xcd_bmbn(bm, bn);
  const int z = blockIdx.z;
  const int wm = wave >> 1, wn = wave & 1;
  const int srow = t >> 3, schunk = t & 7;
  float* C = Cbase + (size_t)z * M * N;

  f32x4 acc[4][4];
#pragma unroll
  for (int fi = 0; fi < 4; ++fi)
#pragma unroll
    for (int fj = 0; fj < 4; ++fj) acc[fi][fj] = 0.f;

  for (int kb = z * KSTEPS; kb < z * KSTEPS + KSTEPS; ++kb) {
    __syncthreads();
#pragma unroll
    for (int g = 0; g < 4; ++g) {
      int row = g * 32 + srow;
      int sw = schunk ^ (row & 7);
      size_t co = kb * 64 + sw * 8;
      gload_lds16(A + (size_t)(bm * 128 + row) * K + co, lds + g * 2048 + wave * 512);
      gload_lds16(B + (size_t)(bn * 128 + row) * K + co, lds + 8192 + g * 2048 + wave * 512);
    }
    __syncthreads();
#pragma unroll
    for (int ks = 0; ks < 2; ++ks) {
      s16x8 af[4], bf[4];
#pragma unroll
      for (int f = 0; f < 4; ++f) {
        int ra = wm * 64 + f * 16 + lc;
        af[f] = *(const s16x8*)(lds + ra * 64 + (((ks * 4 + lg) ^ (ra & 7)) * 8));
        int rb = wn * 64 + f * 16 + lc;
        bf[f] = *(const s16x8*)(lds + 8192 + rb * 64 + (((ks * 4 + lg) ^ (rb & 7)) * 8));
      }
#pragma unroll
      for (int fi = 0; fi < 4; ++fi)
#pragma unroll
        for (int fj = 0; fj < 4; ++fj)
          acc[fi][fj] = __builtin_amdgcn_mfma_f32_16x16x32_bf16(af[fi], bf[fj], acc[fi][fj], 0, 0, 0);
    }
  }
#pragma unroll
  for (int fi = 0; fi < 4; ++fi)
#pragma unroll
    for (int fj = 0; fj < 4; ++fj)
#pragma unroll
      for (int r = 0; r < 4; ++r)
        C[(size_t)(bm * 128 + wm * 64 + fi * 16 + lg * 4 + r) * N +
          bn * 128 + wn * 64 + fj * 16 + lc] = acc[fi][fj][r];
}

// ---------------- s_obs: all 6 terms, z = kv-head, K=128 ----------------
__global__ __launch_bounds__(256) void gemm6z(TermPtrs P, float* __restrict__ Cg) {
  __shared__ ushort_t lds[2 * 128 * 64];
  const int t = threadIdx.x;
  const int wave = t >> 6, lane = t & 63;
  const int lc = lane & 15, lg = lane >> 4;
  const int bm = blockIdx.y, bn = blockIdx.x, z = blockIdx.z;
  const int wm = wave >> 1, wn = wave & 1;
  const int srow = t >> 3, schunk = t & 7;
  const size_t Aoff = (size_t)z * 512 * 128;
  const size_t Boff = (size_t)z * 2048 * 128;
  float* C = Cg + (size_t)z * 512 * 2048;

  f32x4 acc[4][4];
#pragma unroll
  for (int fi = 0; fi < 4; ++fi)
#pragma unroll
    for (int fj = 0; fj < 4; ++fj) acc[fi][fj] = 0.f;

  for (int tt = 0; tt < 6; ++tt) {
    const ushort_t *As, *Bs;
    term_sel(P, tt, As, Bs);
    As += Aoff; Bs += Boff;
    for (int kb = 0; kb < 2; ++kb) {
      __syncthreads();
#pragma unroll
      for (int g = 0; g < 4; ++g) {
        int row = g * 32 + srow;
        int sw = schunk ^ (row & 7);
        gload_lds16(As + (size_t)(bm * 128 + row) * 128 + kb * 64 + sw * 8,
                    lds + g * 2048 + wave * 512);
        gload_lds16(Bs + (size_t)(bn * 128 + row) * 128 + kb * 64 + sw * 8,
                    lds + 8192 + g * 2048 + wave * 512);
      }
      __syncthreads();
#pragma unroll
      for (int ks = 0; ks < 2; ++ks) {
        s16x8 af[4], bf[4];
#pragma unroll
        for (int f = 0; f < 4; ++f) {
          int ra = wm * 64 + f * 16 + lc;
          af[f] = *(const s16x8*)(lds + ra * 64 + (((ks * 4 + lg) ^ (ra & 7)) * 8));
          int rb = wn * 64 + f * 16 + lc;
          bf[f] = *(const s16x8*)(lds + 8192 + rb * 64 + (((ks * 4 + lg) ^ (rb & 7)) * 8));
        }
#pragma unroll
        for (int fi = 0; fi < 4; ++fi)
#pragma unroll
          for (int fj = 0; fj < 4; ++fj)
            acc[fi][fj] = __builtin_amdgcn_mfma_f32_16x16x32_bf16(af[fi], bf[fj], acc[fi][fj], 0, 0, 0);
      }
    }
  }
#pragma unroll
  for (int fi = 0; fi < 4; ++fi)
#pragma unroll
    for (int fj = 0; fj < 4; ++fj)
#pragma unroll
      for (int r = 0; r < 4; ++r)
        C[(size_t)(bm * 128 + wm * 64 + fi * 16 + lg * 4 + r) * 2048 +
          bn * 128 + wn * 64 + fj * 16 + lc] = acc[fi][fj][r];
}

// ---------------- reductions ----------------
__global__ void reduce4_kernel(const float* __restrict__ p, float* __restrict__ out, int n4) {
  int idx = blockIdx.x * 256 + threadIdx.x;
  if (idx >= n4) return;
  const size_t n = (size_t)n4 * 4;
  float4 a = ((const float4*)p)[idx];
  float4 b = ((const float4*)(p + n))[idx];
  float4 c = ((const float4*)(p + 2 * n))[idx];
  float4 d = ((const float4*)(p + 3 * n))[idx];
  float4 o;
  o.x = a.x + b.x + c.x + d.x; o.y = a.y + b.y + c.y + d.y;
  o.z = a.z + b.z + c.z + d.z; o.w = a.w + b.w + c.w + d.w;
  ((float4*)out)[idx] = o;
}
__global__ void reduce2_kernel(const float* __restrict__ p, float* __restrict__ out, int n4) {
  int idx = blockIdx.x * 256 + threadIdx.x;
  if (idx >= n4) return;
  const size_t n = (size_t)n4 * 4;
  float4 a = ((const float4*)p)[idx];
  float4 b = ((const float4*)(p + n))[idx];
  float4 o;
  o.x = a.x + b.x; o.y = a.y + b.y; o.z = a.z + b.z; o.w = a.w + b.w;
  ((float4*)out)[idx] = o;
}

// ---------------- inv_freq ----------------
__global__ void freq_kernel(float* __restrict__ invf) {
  int j = threadIdx.x;
  if (j < 64) invf[j] = (float)(1.0 / pow(500000.0, (double)j / 64.0));
}

// ---------------- fused: sum8 partials + RoPE + 3-split for obs-Q ----------------
__global__ __launch_bounds__(256) void qobs_fuse(const float* __restrict__ qpart,
                                                 const float* __restrict__ invf,
                                                 ushort_t* __restrict__ q0,
                                                 ushort_t* __restrict__ q1,
                                                 ushort_t* __restrict__ q2) {
  int idx = blockIdx.x * 256 + threadIdx.x;   // 128*32*64 = 262144
  int j = idx & 63;
  int hq = (idx >> 6) & 31;
  int i = idx >> 11;
  size_t base = (size_t)i * NQ_ + hq * 128 + j;
  float x1 = 0.f, x2 = 0.f;
#pragma unroll
  for (int z = 0; z < 8; ++z) {
    x1 += qpart[(size_t)z * OBS_ * NQ_ + base];
    x2 += qpart[(size_t)z * OBS_ * NQ_ + base + 64];
  }
  float ang = (float)(S_ - OBS_ + i) * invf[j];
  float sn, cs; sincosf(ang, &sn, &cs);
  float o1 = x1 * cs - x2 * sn;
  float o2 = x2 * cs + x1 * sn;
  int hk = hq >> 2, g = hq & 3;
  size_t o = (size_t)hk * 65536 + (size_t)(g * 128 + i) * 128 + j;
  float ys[2] = {o1, o2};
#pragma unroll
  for (int e = 0; e < 2; ++e) {
    float x = ys[e];
    unsigned short b0 = f2bf(x);
    float r = x - bf2f(b0);
    unsigned short b1 = f2bf(r);
    q0[o + e * 64] = b0; q1[o + e * 64] = b1; q2[o + e * 64] = f2bf(r - bf2f(b1));
  }
}

// ---------------- fused: RoPE K-half of kvf (in place) + 3-split to kb ----------------
__global__ __launch_bounds__(256) void ropekv_splitk(float* __restrict__ kvf,
                                                     const float* __restrict__ invf,
                                                     ushort_t* __restrict__ k0,
                                                     ushort_t* __restrict__ k1,
                                                     ushort_t* __restrict__ k2) {
  int idx = blockIdx.x * 256 + threadIdx.x;   // 2048*8*64 = 1048576
  int j = idx & 63;
  int h = (idx >> 6) & 7;
  int s = idx >> 9;
  size_t base = (size_t)s * KLD_ + h * 128 + j;
  float x1 = kvf[base], x2 = kvf[base + 64];
  float ang = (float)s * invf[j];
  float sn, cs; sincosf(ang, &sn, &cs);
  float o1 = x1 * cs - x2 * sn;
  float o2 = x2 * cs + x1 * sn;
  kvf[base] = o1; kvf[base + 64] = o2;
  size_t o = (size_t)h * 262144 + (size_t)s * 128 + j;
  float ys[2] = {o1, o2};
#pragma unroll
  for (int e = 0; e < 2; ++e) {
    float x = ys[e];
    unsigned short b0 = f2bf(x);
    float r = x - bf2f(b0);
    unsigned short b1 = f2bf(r);
    k0[o + e * 64] = b0; k1[o + e * 64] = b1; k2[o + e * 64] = f2bf(r - bf2f(b1));
  }
}

// ---------------- fused: sum2 Q partials + RoPE -> qb16 ----------------
__global__ __launch_bounds__(256) void rope_q_fuse(const float* __restrict__ qp,
                                                   const float* __restrict__ invf,
                                                   ushort_t* __restrict__ qb16) {
  int idx = blockIdx.x * 256 + threadIdx.x;   // 2048*32*64 = 4194304
  int j = idx & 63;
  int h = (idx >> 6) & 31;
  int s = idx >> 11;
  size_t base = (size_t)s * NQ_ + h * 128 + j;
  const size_t zs = (size_t)S_ * NQ_;
  float x1 = qp[base] + qp[base + zs];
  float x2 = qp[base + 64] + qp[base + 64 + zs];
  float ang = (float)s * invf[j];
  float sn, cs; sincosf(ang, &sn, &cs);
  qb16[base] = f2bf(x1 * cs - x2 * sn);
  qb16[base + 64] = f2bf(x2 * cs + x1 * sn);
}

// ---------------- per-row max + inv-denominator (causal) ----------------
__global__ __launch_bounds__(256) void rowstat_kernel(const float* __restrict__ s,
                                                      float* __restrict__ mx,
                                                      float* __restrict__ dinv) {
  const int row = blockIdx.x * 4 + (threadIdx.x >> 6);
  const int lane = threadIdx.x & 63;
  const int i = row & 127;
  const int jmax = S_ - OBS_ + i;
  const float* sp = s + (size_t)row * S_;
  float vals[32];
  float m = -INFINITY;
#pragma unroll
  for (int c = 0; c < 8; ++c) {
    int j0 = c * 256 + lane * 4;
    float4 v = *(const float4*)(sp + j0);
    float e0 = (j0 + 0 <= jmax) ? v.x * SCALE_ : -INFINITY;
    float e1 = (j0 + 1 <= jmax) ? v.y * SCALE_ : -INFINITY;
    float e2 = (j0 + 2 <= jmax) ? v.z * SCALE_ : -INFINITY;
    float e3 = (j0 + 3 <= jmax) ? v.w * SCALE_ : -INFINITY;
    vals[c * 4 + 0] = e0; vals[c * 4 + 1] = e1; vals[c * 4 + 2] = e2; vals[c * 4 + 3] = e3;
    m = fmaxf(m, fmaxf(fmaxf(e0, e1), fmaxf(e2, e3)));
  }
#pragma unroll
  for (int off = 1; off < 64; off <<= 1) m = fmaxf(m, __shfl_xor(m, off, 64));
  float ssum = 0.f;
#pragma unroll
  for (int c = 0; c < 32; ++c) ssum += expf(vals[c] - m);
#pragma unroll
  for (int off = 1; off < 64; off <<= 1) ssum += __shfl_xor(ssum, off, 64);
  if (lane == 0) { mx[row] = m; dinv[row] = 1.0f / ssum; }
}

// ---------------- column-sum stage 1 ----------------
__global__ __launch_bounds__(256) void colsum_part(const float* __restrict__ s,
                                                   const float* __restrict__ mx,
                                                   const float* __restrict__ dinv,
                                                   float* __restrict__ part) {
  __shared__ float mxl[64], dvl[64];
  const int jt = blockIdx.x, hk = blockIdx.y, rc = blockIdx.z;
  const int t = threadIdx.x;
  if (t < 64) {
    mxl[t] = mx[hk * 512 + rc * 64 + t];
    dvl[t] = dinv[hk * 512 + rc * 64 + t];
  }
  __syncthreads();
  const int j = jt * 256 + t;
  const float* sp = s + ((size_t)hk * 512 + rc * 64) * S_ + j;
  float acc = 0.f;
  for (int rr = 0; rr < 64; ++rr) {
    int i = (rc * 64 + rr) & 127;
    if (j <= S_ - OBS_ + i)
      acc += expf(sp[(size_t)rr * S_] * SCALE_ - mxl[rr]) * dvl[rr];
  }
  part[((size_t)rc * 8 + hk) * S_ + j] = acc;
}

// ---------------- column-sum stage 2 -> imp ----------------
__global__ void colsum_fin(const float* __restrict__ part, float* __restrict__ imp) {
  int idx = blockIdx.x * 256 + threadIdx.x;
  int hk = idx >> 11, j = idx & 2047;
  float acc = 0.f;
#pragma unroll
  for (int rc = 0; rc < 8; ++rc) acc += part[((size_t)rc * 8 + hk) * S_ + j];
  float cnt = (float)min(OBS_, S_ - j);
  imp[idx] = acc * 0.25f / cnt;
}

// ---------------- single-block radix select ----------------
__global__ __launch_bounds__(1024) void radix_all(const float* __restrict__ imp,
                                                  float* __restrict__ thr) {
  __shared__ unsigned hist[4][256];
  __shared__ unsigned pfx_s[4], need_s[4];
  const int t = threadIdx.x;
  if (t < 4) {
    pfx_s[t] = 0u;
    need_s[t] = (t == 0) ? 3225u : (t == 1) ? 3226u : (t == 2) ? 15320u : 15321u;
  }
  __syncthreads();
  for (int pass = 0; pass < 4; ++pass) {
    ((unsigned*)hist)[t] = 0u;
    __syncthreads();
    int shift = 24 - pass * 8;
    for (int idx = t; idx < NC_; idx += 1024) {
      int h = idx / (S_ - W_), j = idx - h * (S_ - W_);
      union { float f; unsigned u; } cv; cv.f = imp[h * S_ + j];
      unsigned u = cv.u;
#pragma unroll
      for (int q = 0; q < 4; ++q) {
        bool m = (pass == 0) || ((u >> (shift + 8)) == (pfx_s[q] >> (shift + 8)));
        if (m) atomicAdd(&hist[q][(u >> shift) & 255u], 1u);
      }
    }
    __syncthreads();
    if (t < 4) {
      unsigned need = need_s[t], cum = 0, pfx = pfx_s[t];
      for (int d = 0; d < 256; ++d) {
        unsigned c = hist[t][d];
        if (cum + c > need) { pfx |= ((unsigned)d) << shift; need_s[t] = need - cum; break; }
        cum += c;
      }
      pfx_s[t] = pfx;
    }
    __syncthreads();
  }
  if (t == 0) {
    union { unsigned u; float f; } c0, c1, c2, c3;
    c0.u = pfx_s[0]; c1.u = pfx_s[1]; c2.u = pfx_s[2]; c3.u = pfx_s[3];
    double fl = 0.2 * (double)(NC_ - 1) - 3225.0;
    double fh = 0.95 * (double)(NC_ - 1) - 15320.0;
    thr[0] = (float)((double)c2.f + ((double)c3.f - (double)c2.f) * fh);
    thr[1] = (float)((double)c0.f + ((double)c1.f - (double)c0.f) * fl);
  }
}

// ---------------- sparsify ----------------
__global__ __launch_bounds__(128) void sparsify_kernel(const float* __restrict__ kv,
                                                       const float* __restrict__ imp,
                                                       const float* __restrict__ thr,
                                                       ushort_t* __restrict__ ksp,
                                                       ushort_t* __restrict__ vsp,
                                                       float* __restrict__ ebias) {
  const int b = blockIdx.x;
  const int j = b >> 3;
  const int h = b & 7;
  const int t = threadIdx.x;
  float ipv = imp[h * S_ + j];
  bool dense = (j >= S_ - W_) || (j < 2);
  int lvl = dense ? 0 : ((ipv >= thr[0]) ? 0 : ((ipv < thr[1]) ? 2 : 1));
  if (t == 0) ebias[h * S_ + j] = (lvl == 2) ? -INFINITY : 0.0f;
  __shared__ float av[128];
  __shared__ float thv;
  size_t base_in = (size_t)j * KLD_ + h * D_;
  size_t base_out = (size_t)j * NKV_ + h * D_;
  float kvv = kv[base_in + t];
  av[t] = fabsf(kvv);
  __syncthreads();
  {
    float at = av[t]; int cnt = 0;
    for (int m = 0; m < 128; ++m) { float am = av[m]; cnt += (am < at) || (am == at && m < t); }
    if (cnt == THR_IDX_) thv = at;
  }
  __syncthreads();
  {
    bool keep = (lvl == 0) || (lvl == 1 && fabsf(kvv) >= thv);
    ksp[base_out + t] = f2bf(keep ? kvv : 0.0f);
  }
  __syncthreads();
  float vvv = kv[base_in + 1024 + t];
  av[t] = fabsf(vvv);
  __syncthreads();
  {
    float at = av[t]; int cnt = 0;
    for (int m = 0; m < 128; ++m) { float am = av[m]; cnt += (am < at) || (am == at && m < t); }
    if (cnt == THR_IDX_) thv = at;
  }
  __syncthreads();
  {
    bool keep = (lvl == 0) || (lvl == 1 && fabsf(vvv) >= thv);
    vsp[base_out + t] = f2bf(keep ? vvv : 0.0f);
  }
}

// ---------------- V transpose ----------------
__global__ __launch_bounds__(256) void vtrans_kernel(const ushort_t* __restrict__ vsp,
                                                     ushort_t* __restrict__ vspT) {
  __shared__ ushort_t tl[64][136];
  const int jt = blockIdx.x;
  const int hk = blockIdx.y;
  const int t = threadIdx.x;
#pragma unroll
  for (int i = 0; i < 4; ++i) {
    int idx = i * 256 + t;
    int j = idx >> 4, c = idx & 15;
    *(u16x8*)&tl[j][c * 8] = *(const u16x8*)(vsp + (size_t)(jt * 64 + j) * NKV_ + hk * 128 + c * 8);
  }
  __syncthreads();
  int d = t >> 1, j0 = (t & 1) * 32;
#pragma unroll
  for (int jj = 0; jj < 4; ++jj) {
    u16x8 v;
#pragma unroll
    for (int e = 0; e < 8; ++e) v[e] = tl[j0 + jj * 8 + e][d];
    *(u16x8*)(vspT + ((size_t)hk * 128 + d) * S_ + jt * 64 + j0 + jj * 8) = v;
  }
}

// ---------------- main attention ----------------
#define SPAD_ 66
__global__ __launch_bounds__(256) void attn_kernel(const ushort_t* __restrict__ qbp,
                                                   const ushort_t* __restrict__ ksp,
                                                   const ushort_t* __restrict__ vspT,
                                                   const float* __restrict__ ebias,
                                                   ushort_t* __restrict__ ob16) {
  __shared__ ushort_t k_lds[64 * 128];
  __shared__ ushort_t vT_lds[128 * 64];
  __shared__ float s_lds[4][16][SPAD_];
  const int b = blockIdx.x;
  const int xcd = b & 7;
  const int idx = b >> 3;
  const int h = xcd * 4 + (idx >> 4);
  const int p = idx & 15;
  const int hk = h >> 2;
  const int t = threadIdx.x;
  const int w = t >> 6, lane = t & 63;
  const int lc = lane & 15, lg = lane >> 4;

  const ushort_t* kbase = ksp + hk * D_;
  const ushort_t* vbase = vspT + (size_t)hk * D_ * S_;

  for (int strip = 0; strip < 2; ++strip) {
    const int qb = (strip == 0) ? p : 31 - p;
    const int q0 = qb * 64 + w * 16;
    s16x8 qfrag[4];
#pragma unroll
    for (int db = 0; db < 4; ++db)
      qfrag[db] = *(const s16x8*)(qbp + (size_t)(q0 + lc) * NQ_ + h * D_ + db * 32 + lg * 8);

    f32x4 o[8];
#pragma unroll
    for (int n = 0; n < 8; ++n) o[n] = 0.f;
    float mr[4] = {-INFINITY, -INFINITY, -INFINITY, -INFINITY};
    float lr[4] = {0.f, 0.f, 0.f, 0.f};

    const int ntj = qb + 1;
    for (int tj = 0; tj < ntj; ++tj) {
      const int j0 = tj * 64;
      __syncthreads();
#pragma unroll
      for (int i = 0; i < 4; ++i) {
        int slot = i * 256 + w * 64 + lane;
        int row = slot >> 4, c = slot & 15;
        const ushort_t* gp = kbase + (size_t)(j0 + row) * NKV_ + ((c ^ (row & 7)) * 8);
        gload_lds16(gp, &k_lds[(i * 256 + w * 64) * 8]);
      }
#pragma unroll
      for (int i = 0; i < 4; ++i) {
        int slot = i * 256 + w * 64 + lane;
        int d = slot >> 3, c = slot & 7;
        const ushort_t* gp = vbase + (size_t)d * S_ + j0 + ((c ^ (d & 7)) * 8);
        gload_lds16(gp, &vT_lds[(i * 256 + w * 64) * 8]);
      }
      __syncthreads();

      f32x4 sfr[4];
#pragma unroll
      for (int js = 0; js < 4; ++js) sfr[js] = 0.f;
#pragma unroll
      for (int js = 0; js < 4; ++js) {
        int row = js * 16 + lc;
#pragma unroll
        for (int db = 0; db < 4; ++db) {
          s16x8 kf = *(const s16x8*)&k_lds[row * 128 + (((db * 4 + lg) ^ (lc & 7)) * 8)];
          sfr[js] = __builtin_amdgcn_mfma_f32_16x16x32_bf16(qfrag[db], kf, sfr[js], 0, 0, 0);
        }
      }
      float eb[4];
#pragma unroll
      for (int js = 0; js < 4; ++js) eb[js] = ebias[hk * S_ + j0 + js * 16 + lc];

      const bool diag = (tj == qb);
      float sclv[4];
#pragma unroll
      for (int r = 0; r < 4; ++r) {
        float sv[4];
#pragma unroll
        for (int js = 0; js < 4; ++js) sv[js] = sfr[js][r] * SCALE_ + eb[js];
        if (diag) {
          int qrow = w * 16 + lg * 4 + r;
#pragma unroll
          for (int js = 0; js < 4; ++js)
            if (js * 16 + lc > qrow) sv[js] = -INFINITY;
        }
        float tm = fmaxf(fmaxf(sv[0], sv[1]), fmaxf(sv[2], sv[3]));
#pragma unroll
        for (int off = 1; off < 16; off <<= 1) tm = fmaxf(tm, __shfl_xor(tm, off, 64));
        float mnew = fmaxf(mr[r], tm);
        float scl = __expf(mr[r] - mnew);
        float ps = 0.f;
#pragma unroll
        for (int js = 0; js < 4; ++js) {
          float e = __expf(sv[js] - mnew);
          s_lds[w][lg * 4 + r][js * 16 + lc] = e;
          ps += e;
        }
#pragma unroll
        for (int off = 1; off < 16; off <<= 1) ps += __shfl_xor(ps, off, 64);
        lr[r] = lr[r] * scl + ps;
        mr[r] = mnew;
        sclv[r] = scl;
      }
#pragma unroll
      for (int n = 0; n < 8; ++n) {
        f32x4 ov = o[n];
#pragma unroll
        for (int r = 0; r < 4; ++r) ov[r] *= sclv[r];
        o[n] = ov;
      }
      asm volatile("s_waitcnt lgkmcnt(0)" ::: "memory");
      s16x8 pa[2];
#pragma unroll
      for (int ks = 0; ks < 2; ++ks) {
        float pv[8];
        *(f32x4*)&pv[0] = *(const f32x4*)&s_lds[w][lc][ks * 32 + lg * 8];
        *(f32x4*)&pv[4] = *(const f32x4*)&s_lds[w][lc][ks * 32 + lg * 8 + 4];
        s16x8 pk;
#pragma unroll
        for (int e = 0; e < 8; ++e) pk[e] = (short)f2bf(pv[e]);
        pa[ks] = pk;
      }
#pragma unroll
      for (int n = 0; n < 8; ++n) {
        int d = n * 16 + lc;
#pragma unroll
        for (int ks = 0; ks < 2; ++ks) {
          s16x8 vf = *(const s16x8*)&vT_lds[d * 64 + (((ks * 4 + lg) ^ (lc & 7)) * 8)];
          o[n] = __builtin_amdgcn_mfma_f32_16x16x32_bf16(pa[ks], vf, o[n], 0, 0, 0);
        }
      }
    }
#pragma unroll
    for (int r = 0; r < 4; ++r) {
      float rinv = 1.0f / lr[r];
      int row = q0 + lg * 4 + r;
#pragma unroll
      for (int n = 0; n < 8; ++n)
        ob16[(size_t)row * NQ_ + h * D_ + n * 16 + lc] = f2bf(o[n][r] * rinv);
    }
  }
}

// ---------------- launcher ----------------
extern "C" void kernel_launch(void* const* d_in, const int* in_sizes, int n_in,
                              void* d_out, int out_size, void* d_ws, size_t ws_size,
                              hipStream_t stream) {
  (void)in_sizes; (void)n_in; (void)out_size; (void)ws_size;
  const float* hid = (const float*)d_in[0];
  const float* wq  = (const float*)d_in[1];
  const float* wk  = (const float*)d_in[2];
  const float* wv  = (const float*)d_in[3];
  const float* wo  = (const float*)d_in[4];
  float* out = (float*)d_out;
  char* ws = (char*)d_ws;
  const size_t MB = 1ull << 20;

  // Overlay map (liveness vs launch order annotated):
  ushort_t* h0     = (ushort_t*)(ws + 0 * MB);     // A -> gemm1 Q (D)
  ushort_t* h1     = (ushort_t*)(ws + 16 * MB);    // A -> gemm6s KV (C)
  ushort_t* h2     = (ushort_t*)(ws + 32 * MB);    // A -> gemm6s KV (C)
  ushort_t* wq0T   = (ushort_t*)(ws + 48 * MB);    // A -> gemm1 Q (D)
  ushort_t* wq1T   = (ushort_t*)(ws + 80 * MB);    // A -> gemm6s obsQ (B)
  ushort_t* wq2T   = (ushort_t*)(ws + 112 * MB);   // A -> gemm6s obsQ (B)
  ushort_t* wkv0T  = (ushort_t*)(ws + 144 * MB);   // A -> gemm6s KV (C)
  ushort_t* wkv1T  = (ushort_t*)(ws + 160 * MB);   // A -> gemm6s KV (C)
  ushort_t* wkv2T  = (ushort_t*)(ws + 176 * MB);   // A -> gemm6s KV (C)
  float*    qpart  = (float*)(ws + 192 * MB);      // gemm6s obsQ -> qobs_fuse (16 MB)
  float*    kvf    = (float*)(ws + 192 * MB);      // reduce4 (C) -> sparsify (I), over dead qpart
  float*    kvp    = (float*)(ws + 80 * MB);       // KV partials 64 MB (over dead wq1T/2T)
  float*    qp2    = (float*)(ws + 80 * MB);       // Q partials 64 MB (over dead kvp)
  ushort_t* qb16   = (ushort_t*)(ws + 16 * MB);    // rope_q_fuse (F) -> attn (I), over dead h1
  ushort_t* kb0    = (ushort_t*)(ws + 32 * MB);    // ropekv_splitk (F) -> gemm6z (G), over dead h2
  ushort_t* kb1    = (ushort_t*)(ws + 36 * MB);
  ushort_t* kb2    = (ushort_t*)(ws + 40 * MB);
  float*    s_obs  = (float*)(ws + 48 * MB);       // gemm6z (G) -> colsum (G), 32 MB over dead wq0T
  ushort_t* woT    = (ushort_t*)(ws + 144 * MB);   // splitT wo (E) -> outproj (I)
  ushort_t* ksp    = (ushort_t*)(ws + 176 * MB);   // sparsify -> attn (I)
  ushort_t* vsp    = (ushort_t*)(ws + 180 * MB);
  ushort_t* vspT   = (ushort_t*)(ws + 184 * MB);
  ushort_t* ob16   = (ushort_t*)(ws + 188 * MB + 512 * 1024);  // attn -> outproj (I)
  float*    opart  = (float*)(ws + 0 * MB);        // outproj partials 64 MB (I-last)
  ushort_t* qo0    = (ushort_t*)(ws + 208 * MB);   // qobs_fuse -> gemm6z
  ushort_t* qo1    = (ushort_t*)(ws + 209 * MB);
  ushort_t* qo2    = (ushort_t*)(ws + 210 * MB);
  char*     misc   = ws + 212 * MB;
  float*    impv   = (float*)(misc + 0);
  float*    eb     = (float*)(misc + 64 * 1024);
  float*    invf   = (float*)(misc + 128 * 1024);
  float*    thr    = (float*)(misc + 132 * 1024);
  float*    mxbuf  = (float*)(misc + 160 * 1024);
  float*    dinvb  = (float*)(misc + 192 * 1024);
  float*    part   = (float*)(misc + 256 * 1024);  // 512 KB

  freq_kernel<<<1, 64, 0, stream>>>(invf);

  // A) splits
  split3_kernel<<<(S_ * HID_ / 4 + 255) / 256, 256, 0, stream>>>(hid, h0, h1, h2, S_ * HID_ / 4);
  splitT_kernel<<<dim3(NQ_ / 64, HID_ / 64), 256, 0, stream>>>(wq, NQ_, wq0T, wq1T, wq2T);
  splitT_kernel<<<dim3(NKV_ / 64, HID_ / 64), 256, 0, stream>>>(wk, NKV_, wkv0T, wkv1T, wkv2T);
  splitT_kernel<<<dim3(NKV_ / 64, HID_ / 64), 256, 0, stream>>>(
      wv, NKV_, wkv0T + (size_t)NKV_ * HID_, wkv1T + (size_t)NKV_ * HID_, wkv2T + (size_t)NKV_ * HID_);

  // B) obs-Q: 6-term shared-stage GEMM (M=128, z=8 K-slices of 512) + fused sum+rope+split
  const size_t obs_off = (size_t)(S_ - OBS_) * HID_;
  {
    Six P;
    P.A[0] = h0 + obs_off; P.A[1] = h1 + obs_off; P.A[2] = h2 + obs_off;
    P.B[0] = wq0T; P.B[1] = wq1T; P.B[2] = wq2T;
    gemm6s<<<dim3(NQ_ / 128, 1, 8), 256, 0, stream>>>(P, qpart, 128, NQ_, HID_, 16);
  }
  qobs_fuse<<<(OBS_ * HQ_ * 64) / 256, 256, 0, stream>>>(qpart, invf, qo0, qo1, qo2);

  // C) KV: 6-term shared-stage GEMM (split-K z=4) + reduce4
  {
    Six P;
    P.A[0] = h0; P.A[1] = h1; P.A[2] = h2;
    P.B[0] = wkv0T; P.B[1] = wkv1T; P.B[2] = wkv2T;
    gemm6s<<<dim3(KLD_ / 128, S_ / 128, 4), 256, 0, stream>>>(P, kvp, S_, KLD_, HID_, 32);
  }
  reduce4_kernel<<<(S_ * KLD_ / 4 + 255) / 256, 256, 0, stream>>>(kvp, kvf, S_ * KLD_ / 4);

  // D) Q main GEMM split-K z=2 (partials over dead kvp)
  gemm1<<<dim3(NQ_ / 128, S_ / 128, 2), 256, 0, stream>>>(h0, wq0T, qp2, S_, NQ_, HID_, 32);

  // E) wo transpose+cast
  splitT_kernel<<<dim3(HID_ / 64, HID_ / 64), 256, 0, stream>>>(wo, HID_, woT, nullptr, nullptr);

  // F) fused RoPE passes
  rope_q_fuse<<<(S_ * HQ_ * 64) / 256, 256, 0, stream>>>(qp2, invf, qb16);
  ropekv_splitk<<<(S_ * HKV_ * 64) / 256, 256, 0, stream>>>(kvf, invf, kb0, kb1, kb2);

  // G) obs importance
  {
    TermPtrs P;
    P.a[0] = qo0; P.b[0] = kb0;
    P.a[1] = qo0; P.b[1] = kb1;
    P.a[2] = qo1; P.b[2] = kb0;
    P.a[3] = qo1; P.b[3] = kb1;
    P.a[4] = qo0; P.b[4] = kb2;
    P.a[5] = qo2; P.b[5] = kb0;
    gemm6z<<<dim3(16, 4, 8), 256, 0, stream>>>(P, s_obs);
  }
  rowstat_kernel<<<1024, 256, 0, stream>>>(s_obs, mxbuf, dinvb);
  colsum_part<<<dim3(8, 8, 8), 256, 0, stream>>>(s_obs, mxbuf, dinvb, part);
  colsum_fin<<<64, 256, 0, stream>>>(part, impv);

  // H) quantile thresholds
  radix_all<<<1, 1024, 0, stream>>>(impv, thr);

  // I) sparsify + V-transpose + attention + out projection (split-K z=2)
  sparsify_kernel<<<S_ * HKV_, 128, 0, stream>>>(kvf, impv, thr, ksp, vsp, eb);
  vtrans_kernel<<<dim3(S_ / 64, HKV_), 256, 0, stream>>>(vsp, vspT);
  attn_kernel<<<512, 256, 0, stream>>>(qb16, ksp, vspT, eb, ob16);
  gemm1<<<dim3(HID_ / 128, S_ / 128, 2), 256, 0, stream>>>(ob16, woT, opart, S_, HID_, HID_, 32);
  reduce2_kernel<<<(S_ * HID_ / 4 + 255) / 256, 256, 0, stream>>>(opart, out, S_ * HID_ / 4);
}

// Round 10
// 847.296 us; speedup vs baseline: 1.2376x; 1.0101x over previous
//
#include <hip/hip_runtime.h>
#include <hip/hip_bf16.h>
#include <math.h>

#define S_    2048
#define HID_  4096
#define HQ_   32
#define HKV_  8
#define D_    128
#define G_    4
#define OBS_  128
#define W_    32
#define NKV_  1024
#define NQ_   4096
#define KLD_  2048
#define SCALE_ 0.08838834764831845f
#define THR_IDX_ 89
#define NC_   16128

typedef __attribute__((ext_vector_type(4))) float f32x4;
typedef __attribute__((ext_vector_type(8))) short s16x8;
typedef __attribute__((ext_vector_type(8))) unsigned short u16x8;
typedef __attribute__((ext_vector_type(4))) unsigned short u16x4;
typedef unsigned short ushort_t;

struct TermPtrs { const ushort_t* a[6]; const ushort_t* b[6]; };
struct Six { const ushort_t* A[3]; const ushort_t* B[3]; };

__device__ __forceinline__ unsigned short f2bf(float x) {
  union { float f; unsigned u; } v; v.f = x;
  unsigned r = v.u + 0x7FFFu + ((v.u >> 16) & 1u);
  return (unsigned short)(r >> 16);
}
__device__ __forceinline__ float bf2f(unsigned short b) {
  union { unsigned u; float f; } v; v.u = ((unsigned)b) << 16;
  return v.f;
}
__device__ __forceinline__ void gload_lds16(const void* g, void* l) {
  __builtin_amdgcn_global_load_lds((const __attribute__((address_space(1))) unsigned int*)g,
                                   (__attribute__((address_space(3))) unsigned int*)l, 16, 0, 0);
}
__device__ __forceinline__ void term_sel(const TermPtrs& P, int tt,
                                         const ushort_t*& As, const ushort_t*& Bs) {
  switch (tt) {
    case 0: As = P.a[0]; Bs = P.b[0]; break;
    case 1: As = P.a[1]; Bs = P.b[1]; break;
    case 2: As = P.a[2]; Bs = P.b[2]; break;
    case 3: As = P.a[3]; Bs = P.b[3]; break;
    case 4: As = P.a[4]; Bs = P.b[4]; break;
    default: As = P.a[5]; Bs = P.b[5]; break;
  }
}
// XCD-aware bijective swizzle within the (x,y) plane; plane size must be %8==0.
__device__ __forceinline__ void xcd_bmbn(int& bm, int& bn) {
  int nplane = gridDim.x * gridDim.y;
  int l = blockIdx.y * gridDim.x + blockIdx.x;
  int v = (l & 7) * (nplane >> 3) + (l >> 3);
  bm = v / gridDim.x;
  bn = v - bm * gridDim.x;
}

// ---------------- split fp32 -> 3 bf16 terms ----------------
__global__ __launch_bounds__(256) void split3_kernel(const float* __restrict__ src,
                                                     ushort_t* __restrict__ d0,
                                                     ushort_t* __restrict__ d1,
                                                     ushort_t* __restrict__ d2, int n4) {
  int idx = blockIdx.x * 256 + threadIdx.x;
  if (idx >= n4) return;
  float4 v = ((const float4*)src)[idx];
  u16x4 o0, o1, o2;
  float xs[4] = {v.x, v.y, v.z, v.w};
#pragma unroll
  for (int e = 0; e < 4; ++e) {
    float x = xs[e];
    unsigned short b0 = f2bf(x);
    float r = x - bf2f(b0);
    unsigned short b1 = f2bf(r);
    o0[e] = b0; o1[e] = b1; o2[e] = f2bf(r - bf2f(b1));
  }
  *(u16x4*)(d0 + (size_t)idx * 4) = o0;
  *(u16x4*)(d1 + (size_t)idx * 4) = o1;
  *(u16x4*)(d2 + (size_t)idx * 4) = o2;
}

// ---------------- split + transpose weights ----------------
__global__ __launch_bounds__(256) void splitT_kernel(const float* __restrict__ src, int N,
                                                     ushort_t* __restrict__ t0,
                                                     ushort_t* __restrict__ t1,
                                                     ushort_t* __restrict__ t2) {
  __shared__ float tile[64][65];
  const int t = threadIdx.x;
  const int n0 = blockIdx.x * 64, k0 = blockIdx.y * 64;
#pragma unroll
  for (int i = 0; i < 16; ++i) {
    int idx = i * 256 + t;
    int r = idx >> 6, c = idx & 63;
    tile[r][c] = src[(size_t)(k0 + r) * N + n0 + c];
  }
  __syncthreads();
#pragma unroll
  for (int i = 0; i < 16; ++i) {
    int idx = i * 256 + t;
    int n = idx >> 6, kk = idx & 63;
    float x = tile[kk][n];
    unsigned short b0 = f2bf(x);
    size_t o = (size_t)(n0 + n) * HID_ + k0 + kk;
    t0[o] = b0;
    if (t1) {
      float r = x - bf2f(b0);
      unsigned short b1 = f2bf(r);
      t1[o] = b1;
      t2[o] = f2bf(r - bf2f(b1));
    }
  }
}

// ---------------- 6-term shared-stage GEMM (BK=32, rotation swizzle) ----------
// Terms: A0B0, A0B1, A0B2, A1B0, A1B1, A2B0. C partial per z (split-K, KSTEPS kb of 32).
// LDS chunk placement: logical chunk c stored at physical (c + (row>>1)) & 3
// -> ds_read bank group (4l + (lg+(l>>1))&3) mod 8 is bijective over 8 rows = 2-way (free).
__global__ __launch_bounds__(256) void gemm6s(Six P, float* __restrict__ Cbase,
                                              int M, int N, int K, int KSTEPS) {
  __shared__ ushort_t lds[6 * 128 * 32];   // 6 x 8KB = 48KB
  const int t = threadIdx.x;
  const int wave = t >> 6, lane = t & 63;
  const int lc = lane & 15, lg = lane >> 4;
  int bm, bn;
  xcd_bmbn(bm, bn);
  const int z = blockIdx.z;
  const int wm = wave >> 1, wn = wave & 1;
  float* C = Cbase + (size_t)z * M * N;

  f32x4 acc[4][4];
#pragma unroll
  for (int fi = 0; fi < 4; ++fi)
#pragma unroll
    for (int fj = 0; fj < 4; ++fj) acc[fi][fj] = 0.f;

  for (int kb = z * KSTEPS; kb < z * KSTEPS + KSTEPS; ++kb) {
    __syncthreads();
#pragma unroll
    for (int ti = 0; ti < 6; ++ti) {
      const ushort_t* src = (ti < 3) ? P.A[ti] : P.B[ti - 3];
      const int rb = ((ti < 3) ? bm : bn) * 128;
#pragma unroll
      for (int it = 0; it < 2; ++it) {
        int slot = it * 256 + t;            // 512 x 16B chunks per tile
        int row = slot >> 2, cp = slot & 3;
        int c = (cp - (row >> 1)) & 3;      // inverse rotation on the SOURCE
        gload_lds16(src + (size_t)(rb + row) * K + kb * 32 + c * 8,
                    lds + ti * 4096 + it * 2048 + wave * 512);
      }
    }
    __syncthreads();
    // load A fragments once (physical chunk = (lg + row>>1) & 3)
    s16x8 a0[4], a1[4], a2[4], bfr[4];
#pragma unroll
    for (int f = 0; f < 4; ++f) {
      int ra = wm * 64 + f * 16 + lc;
      int ca = ((lg + (ra >> 1)) & 3) * 8;
      a0[f] = *(const s16x8*)(lds + 0 * 4096 + ra * 32 + ca);
      a1[f] = *(const s16x8*)(lds + 1 * 4096 + ra * 32 + ca);
      a2[f] = *(const s16x8*)(lds + 2 * 4096 + ra * 32 + ca);
    }
    // B0: products A0B0, A1B0, A2B0
#pragma unroll
    for (int f = 0; f < 4; ++f) {
      int rb2 = wn * 64 + f * 16 + lc;
      bfr[f] = *(const s16x8*)(lds + 3 * 4096 + rb2 * 32 + (((lg + (rb2 >> 1)) & 3) * 8));
    }
#pragma unroll
    for (int fi = 0; fi < 4; ++fi)
#pragma unroll
      for (int fj = 0; fj < 4; ++fj) {
        acc[fi][fj] = __builtin_amdgcn_mfma_f32_16x16x32_bf16(a0[fi], bfr[fj], acc[fi][fj], 0, 0, 0);
        acc[fi][fj] = __builtin_amdgcn_mfma_f32_16x16x32_bf16(a1[fi], bfr[fj], acc[fi][fj], 0, 0, 0);
        acc[fi][fj] = __builtin_amdgcn_mfma_f32_16x16x32_bf16(a2[fi], bfr[fj], acc[fi][fj], 0, 0, 0);
      }
    // B1: products A0B1, A1B1
#pragma unroll
    for (int f = 0; f < 4; ++f) {
      int rb2 = wn * 64 + f * 16 + lc;
      bfr[f] = *(const s16x8*)(lds + 4 * 4096 + rb2 * 32 + (((lg + (rb2 >> 1)) & 3) * 8));
    }
#pragma unroll
    for (int fi = 0; fi < 4; ++fi)
#pragma unroll
      for (int fj = 0; fj < 4; ++fj) {
        acc[fi][fj] = __builtin_amdgcn_mfma_f32_16x16x32_bf16(a0[fi], bfr[fj], acc[fi][fj], 0, 0, 0);
        acc[fi][fj] = __builtin_amdgcn_mfma_f32_16x16x32_bf16(a1[fi], bfr[fj], acc[fi][fj], 0, 0, 0);
      }
    // B2: product A0B2
#pragma unroll
    for (int f = 0; f < 4; ++f) {
      int rb2 = wn * 64 + f * 16 + lc;
      bfr[f] = *(const s16x8*)(lds + 5 * 4096 + rb2 * 32 + (((lg + (rb2 >> 1)) & 3) * 8));
    }
#pragma unroll
    for (int fi = 0; fi < 4; ++fi)
#pragma unroll
      for (int fj = 0; fj < 4; ++fj)
        acc[fi][fj] = __builtin_amdgcn_mfma_f32_16x16x32_bf16(a0[fi], bfr[fj], acc[fi][fj], 0, 0, 0);
  }
#pragma unroll
  for (int fi = 0; fi < 4; ++fi)
#pragma unroll
    for (int fj = 0; fj < 4; ++fj)
#pragma unroll
      for (int r = 0; r < 4; ++r)
        C[(size_t)(bm * 128 + wm * 64 + fi * 16 + lg * 4 + r) * N +
          bn * 128 + wn * 64 + fj * 16 + lc] = acc[fi][fj][r];
}

// ---------------- single-term GEMM with split-K (z = K-chunk of KSTEPS*64) ----------------
__global__ __launch_bounds__(256) void gemm1(const ushort_t* __restrict__ A,
                                             const ushort_t* __restrict__ B,
                                             float* __restrict__ Cbase,
                                             int M, int N, int K, int KSTEPS) {
  __shared__ ushort_t lds[2 * 128 * 64];
  const int t = threadIdx.x;
  const int wave = t >> 6, lane = t & 63;
  const int lc = lane & 15, lg = lane >> 4;
  int bm, bn;
  xcd_bmbn(bm, bn);
  const int z = blockIdx.z;
  const int wm = wave >> 1, wn = wave & 1;
  const int srow = t >> 3, schunk = t & 7;
  float* C = Cbase + (size_t)z * M * N;

  f32x4 acc[4][4];
#pragma unroll
  for (int fi = 0; fi < 4; ++fi)
#pragma unroll
    for (int fj = 0; fj < 4; ++fj) acc[fi][fj] = 0.f;

  for (int kb = z * KSTEPS; kb < z * KSTEPS + KSTEPS; ++kb) {
    __syncthreads();
#pragma unroll
    for (int g = 0; g < 4; ++g) {
      int row = g * 32 + srow;
      int sw = schunk ^ (row & 7);
      size_t co = kb * 64 + sw * 8;
      gload_lds16(A + (size_t)(bm * 128 + row) * K + co, lds + g * 2048 + wave * 512);
      gload_lds16(B + (size_t)(bn * 128 + row) * K + co, lds + 8192 + g * 2048 + wave * 512);
    }
    __syncthreads();
#pragma unroll
    for (int ks = 0; ks < 2; ++ks) {
      s16x8 af[4], bf[4];
#pragma unroll
      for (int f = 0; f < 4; ++f) {
        int ra = wm * 64 + f * 16 + lc;
        af[f] = *(const s16x8*)(lds + ra * 64 + (((ks * 4 + lg) ^ (ra & 7)) * 8));
        int rb = wn * 64 + f * 16 + lc;
        bf[f] = *(const s16x8*)(lds + 8192 + rb * 64 + (((ks * 4 + lg) ^ (rb & 7)) * 8));
      }
#pragma unroll
      for (int fi = 0; fi < 4; ++fi)
#pragma unroll
        for (int fj = 0; fj < 4; ++fj)
          acc[fi][fj] = __builtin_amdgcn_mfma_f32_16x16x32_bf16(af[fi], bf[fj], acc[fi][fj], 0, 0, 0);
    }
  }
#pragma unroll
  for (int fi = 0; fi < 4; ++fi)
#pragma unroll
    for (int fj = 0; fj < 4; ++fj)
#pragma unroll
      for (int r = 0; r < 4; ++r)
        C[(size_t)(bm * 128 + wm * 64 + fi * 16 + lg * 4 + r) * N +
          bn * 128 + wn * 64 + fj * 16 + lc] = acc[fi][fj][r];
}

// ---------------- s_obs: all 6 terms, z = kv-head, K=128 ----------------
__global__ __launch_bounds__(256) void gemm6z(TermPtrs P, float* __restrict__ Cg) {
  __shared__ ushort_t lds[2 * 128 * 64];
  const int t = threadIdx.x;
  const int wave = t >> 6, lane = t & 63;
  const int lc = lane & 15, lg = lane >> 4;
  const int bm = blockIdx.y, bn = blockIdx.x, z = blockIdx.z;
  const int wm = wave >> 1, wn = wave & 1;
  const int srow = t >> 3, schunk = t & 7;
  const size_t Aoff = (size_t)z * 512 * 128;
  const size_t Boff = (size_t)z * 2048 * 128;
  float* C = Cg + (size_t)z * 512 * 2048;

  f32x4 acc[4][4];
#pragma unroll
  for (int fi = 0; fi < 4; ++fi)
#pragma unroll
    for (int fj = 0; fj < 4; ++fj) acc[fi][fj] = 0.f;

  for (int tt = 0; tt < 6; ++tt) {
    const ushort_t *As, *Bs;
    term_sel(P, tt, As, Bs);
    As += Aoff; Bs += Boff;
    for (int kb = 0; kb < 2; ++kb) {
      __syncthreads();
#pragma unroll
      for (int g = 0; g < 4; ++g) {
        int row = g * 32 + srow;
        int sw = schunk ^ (row & 7);
        gload_lds16(As + (size_t)(bm * 128 + row) * 128 + kb * 64 + sw * 8,
                    lds + g * 2048 + wave * 512);
        gload_lds16(Bs + (size_t)(bn * 128 + row) * 128 + kb * 64 + sw * 8,
                    lds + 8192 + g * 2048 + wave * 512);
      }
      __syncthreads();
#pragma unroll
      for (int ks = 0; ks < 2; ++ks) {
        s16x8 af[4], bf[4];
#pragma unroll
        for (int f = 0; f < 4; ++f) {
          int ra = wm * 64 + f * 16 + lc;
          af[f] = *(const s16x8*)(lds + ra * 64 + (((ks * 4 + lg) ^ (ra & 7)) * 8));
          int rb = wn * 64 + f * 16 + lc;
          bf[f] = *(const s16x8*)(lds + 8192 + rb * 64 + (((ks * 4 + lg) ^ (rb & 7)) * 8));
        }
#pragma unroll
        for (int fi = 0; fi < 4; ++fi)
#pragma unroll
          for (int fj = 0; fj < 4; ++fj)
            acc[fi][fj] = __builtin_amdgcn_mfma_f32_16x16x32_bf16(af[fi], bf[fj], acc[fi][fj], 0, 0, 0);
      }
    }
  }
#pragma unroll
  for (int fi = 0; fi < 4; ++fi)
#pragma unroll
    for (int fj = 0; fj < 4; ++fj)
#pragma unroll
      for (int r = 0; r < 4; ++r)
        C[(size_t)(bm * 128 + wm * 64 + fi * 16 + lg * 4 + r) * 2048 +
          bn * 128 + wn * 64 + fj * 16 + lc] = acc[fi][fj][r];
}

// ---------------- fused: sum4 KV partials + RoPE K-half + 3-split K -> kb, kvf ----------
__global__ __launch_bounds__(256) void kv_finish(const float* __restrict__ kvp,
                                                 const float* __restrict__ invf,
                                                 float* __restrict__ kvf,
                                                 ushort_t* __restrict__ k0,
                                                 ushort_t* __restrict__ k1,
                                                 ushort_t* __restrict__ k2) {
  const size_t n = (size_t)S_ * KLD_;
  int b = blockIdx.x;
  if (b < 4096) {
    // K half: rope pairs (j, j+64)
    int idx = b * 256 + threadIdx.x;   // 0..1048575
    int j = idx & 63;
    int h = (idx >> 6) & 7;
    int s = idx >> 9;
    size_t base = (size_t)s * KLD_ + h * 128 + j;
    float x1 = kvp[base] + kvp[base + n] + kvp[base + 2 * n] + kvp[base + 3 * n];
    float x2 = kvp[base + 64] + kvp[base + 64 + n] + kvp[base + 64 + 2 * n] + kvp[base + 64 + 3 * n];
    float ang = (float)s * invf[j];
    float sn, cs; sincosf(ang, &sn, &cs);
    float o1 = x1 * cs - x2 * sn;
    float o2 = x2 * cs + x1 * sn;
    kvf[base] = o1; kvf[base + 64] = o2;
    size_t o = (size_t)h * 262144 + (size_t)s * 128 + j;
    float ys[2] = {o1, o2};
#pragma unroll
    for (int e = 0; e < 2; ++e) {
      float x = ys[e];
      unsigned short b0 = f2bf(x);
      float r = x - bf2f(b0);
      unsigned short b1 = f2bf(r);
      k0[o + e * 64] = b0; k1[o + e * 64] = b1; k2[o + e * 64] = f2bf(r - bf2f(b1));
    }
  } else {
    // V half: plain sum4, float4
    int idx = (b - 4096) * 256 + threadIdx.x;   // 0..524287
    int s = idx >> 8, c4 = idx & 255;
    size_t base = (size_t)s * KLD_ + 1024 + c4 * 4;
    float4 a = *(const float4*)(kvp + base);
    float4 bb = *(const float4*)(kvp + base + n);
    float4 c = *(const float4*)(kvp + base + 2 * n);
    float4 d = *(const float4*)(kvp + base + 3 * n);
    float4 o;
    o.x = a.x + bb.x + c.x + d.x; o.y = a.y + bb.y + c.y + d.y;
    o.z = a.z + bb.z + c.z + d.z; o.w = a.w + bb.w + c.w + d.w;
    *(float4*)(kvf + base) = o;
  }
}

// ---------------- reductions ----------------
__global__ void reduce2_kernel(const float* __restrict__ p, float* __restrict__ out, int n4) {
  int idx = blockIdx.x * 256 + threadIdx.x;
  if (idx >= n4) return;
  const size_t n = (size_t)n4 * 4;
  float4 a = ((const float4*)p)[idx];
  float4 b = ((const float4*)(p + n))[idx];
  float4 o;
  o.x = a.x + b.x; o.y = a.y + b.y; o.z = a.z + b.z; o.w = a.w + b.w;
  ((float4*)out)[idx] = o;
}

// ---------------- inv_freq ----------------
__global__ void freq_kernel(float* __restrict__ invf) {
  int j = threadIdx.x;
  if (j < 64) invf[j] = (float)(1.0 / pow(500000.0, (double)j / 64.0));
}

// ---------------- fused: sum8 partials + RoPE + 3-split for obs-Q ----------------
__global__ __launch_bounds__(256) void qobs_fuse(const float* __restrict__ qpart,
                                                 const float* __restrict__ invf,
                                                 ushort_t* __restrict__ q0,
                                                 ushort_t* __restrict__ q1,
                                                 ushort_t* __restrict__ q2) {
  int idx = blockIdx.x * 256 + threadIdx.x;   // 128*32*64 = 262144
  int j = idx & 63;
  int hq = (idx >> 6) & 31;
  int i = idx >> 11;
  size_t base = (size_t)i * NQ_ + hq * 128 + j;
  float x1 = 0.f, x2 = 0.f;
#pragma unroll
  for (int z = 0; z < 8; ++z) {
    x1 += qpart[(size_t)z * OBS_ * NQ_ + base];
    x2 += qpart[(size_t)z * OBS_ * NQ_ + base + 64];
  }
  float ang = (float)(S_ - OBS_ + i) * invf[j];
  float sn, cs; sincosf(ang, &sn, &cs);
  float o1 = x1 * cs - x2 * sn;
  float o2 = x2 * cs + x1 * sn;
  int hk = hq >> 2, g = hq & 3;
  size_t o = (size_t)hk * 65536 + (size_t)(g * 128 + i) * 128 + j;
  float ys[2] = {o1, o2};
#pragma unroll
  for (int e = 0; e < 2; ++e) {
    float x = ys[e];
    unsigned short b0 = f2bf(x);
    float r = x - bf2f(b0);
    unsigned short b1 = f2bf(r);
    q0[o + e * 64] = b0; q1[o + e * 64] = b1; q2[o + e * 64] = f2bf(r - bf2f(b1));
  }
}

// ---------------- fused: sum2 Q partials + RoPE -> qb16 ----------------
__global__ __launch_bounds__(256) void rope_q_fuse(const float* __restrict__ qp,
                                                   const float* __restrict__ invf,
                                                   ushort_t* __restrict__ qb16) {
  int idx = blockIdx.x * 256 + threadIdx.x;   // 2048*32*64 = 4194304
  int j = idx & 63;
  int h = (idx >> 6) & 31;
  int s = idx >> 11;
  size_t base = (size_t)s * NQ_ + h * 128 + j;
  const size_t zs = (size_t)S_ * NQ_;
  float x1 = qp[base] + qp[base + zs];
  float x2 = qp[base + 64] + qp[base + 64 + zs];
  float ang = (float)s * invf[j];
  float sn, cs; sincosf(ang, &sn, &cs);
  qb16[base] = f2bf(x1 * cs - x2 * sn);
  qb16[base + 64] = f2bf(x2 * cs + x1 * sn);
}

// ---------------- per-row max + inv-denominator (causal) ----------------
__global__ __launch_bounds__(256) void rowstat_kernel(const float* __restrict__ s,
                                                      float* __restrict__ mx,
                                                      float* __restrict__ dinv) {
  const int row = blockIdx.x * 4 + (threadIdx.x >> 6);
  const int lane = threadIdx.x & 63;
  const int i = row & 127;
  const int jmax = S_ - OBS_ + i;
  const float* sp = s + (size_t)row * S_;
  float vals[32];
  float m = -INFINITY;
#pragma unroll
  for (int c = 0; c < 8; ++c) {
    int j0 = c * 256 + lane * 4;
    float4 v = *(const float4*)(sp + j0);
    float e0 = (j0 + 0 <= jmax) ? v.x * SCALE_ : -INFINITY;
    float e1 = (j0 + 1 <= jmax) ? v.y * SCALE_ : -INFINITY;
    float e2 = (j0 + 2 <= jmax) ? v.z * SCALE_ : -INFINITY;
    float e3 = (j0 + 3 <= jmax) ? v.w * SCALE_ : -INFINITY;
    vals[c * 4 + 0] = e0; vals[c * 4 + 1] = e1; vals[c * 4 + 2] = e2; vals[c * 4 + 3] = e3;
    m = fmaxf(m, fmaxf(fmaxf(e0, e1), fmaxf(e2, e3)));
  }
#pragma unroll
  for (int off = 1; off < 64; off <<= 1) m = fmaxf(m, __shfl_xor(m, off, 64));
  float ssum = 0.f;
#pragma unroll
  for (int c = 0; c < 32; ++c) ssum += expf(vals[c] - m);
#pragma unroll
  for (int off = 1; off < 64; off <<= 1) ssum += __shfl_xor(ssum, off, 64);
  if (lane == 0) { mx[row] = m; dinv[row] = 1.0f / ssum; }
}

// ---------------- column-sum stage 1 ----------------
__global__ __launch_bounds__(256) void colsum_part(const float* __restrict__ s,
                                                   const float* __restrict__ mx,
                                                   const float* __restrict__ dinv,
                                                   float* __restrict__ part) {
  __shared__ float mxl[64], dvl[64];
  const int jt = blockIdx.x, hk = blockIdx.y, rc = blockIdx.z;
  const int t = threadIdx.x;
  if (t < 64) {
    mxl[t] = mx[hk * 512 + rc * 64 + t];
    dvl[t] = dinv[hk * 512 + rc * 64 + t];
  }
  __syncthreads();
  const int j = jt * 256 + t;
  const float* sp = s + ((size_t)hk * 512 + rc * 64) * S_ + j;
  float acc = 0.f;
  for (int rr = 0; rr < 64; ++rr) {
    int i = (rc * 64 + rr) & 127;
    if (j <= S_ - OBS_ + i)
      acc += expf(sp[(size_t)rr * S_] * SCALE_ - mxl[rr]) * dvl[rr];
  }
  part[((size_t)rc * 8 + hk) * S_ + j] = acc;
}

// ---------------- column-sum stage 2 -> imp ----------------
__global__ void colsum_fin(const float* __restrict__ part, float* __restrict__ imp) {
  int idx = blockIdx.x * 256 + threadIdx.x;
  int hk = idx >> 11, j = idx & 2047;
  float acc = 0.f;
#pragma unroll
  for (int rc = 0; rc < 8; ++rc) acc += part[((size_t)rc * 8 + hk) * S_ + j];
  float cnt = (float)min(OBS_, S_ - j);
  imp[idx] = acc * 0.25f / cnt;
}

// ---------------- single-block radix select ----------------
__global__ __launch_bounds__(1024) void radix_all(const float* __restrict__ imp,
                                                  float* __restrict__ thr) {
  __shared__ unsigned hist[4][256];
  __shared__ unsigned pfx_s[4], need_s[4];
  const int t = threadIdx.x;
  if (t < 4) {
    pfx_s[t] = 0u;
    need_s[t] = (t == 0) ? 3225u : (t == 1) ? 3226u : (t == 2) ? 15320u : 15321u;
  }
  __syncthreads();
  for (int pass = 0; pass < 4; ++pass) {
    ((unsigned*)hist)[t] = 0u;
    __syncthreads();
    int shift = 24 - pass * 8;
    for (int idx = t; idx < NC_; idx += 1024) {
      int h = idx / (S_ - W_), j = idx - h * (S_ - W_);
      union { float f; unsigned u; } cv; cv.f = imp[h * S_ + j];
      unsigned u = cv.u;
#pragma unroll
      for (int q = 0; q < 4; ++q) {
        bool m = (pass == 0) || ((u >> (shift + 8)) == (pfx_s[q] >> (shift + 8)));
        if (m) atomicAdd(&hist[q][(u >> shift) & 255u], 1u);
      }
    }
    __syncthreads();
    if (t < 4) {
      unsigned need = need_s[t], cum = 0, pfx = pfx_s[t];
      for (int d = 0; d < 256; ++d) {
        unsigned c = hist[t][d];
        if (cum + c > need) { pfx |= ((unsigned)d) << shift; need_s[t] = need - cum; break; }
        cum += c;
      }
      pfx_s[t] = pfx;
    }
    __syncthreads();
  }
  if (t == 0) {
    union { unsigned u; float f; } c0, c1, c2, c3;
    c0.u = pfx_s[0]; c1.u = pfx_s[1]; c2.u = pfx_s[2]; c3.u = pfx_s[3];
    double fl = 0.2 * (double)(NC_ - 1) - 3225.0;
    double fh = 0.95 * (double)(NC_ - 1) - 15320.0;
    thr[0] = (float)((double)c2.f + ((double)c3.f - (double)c2.f) * fh);
    thr[1] = (float)((double)c0.f + ((double)c1.f - (double)c0.f) * fl);
  }
}

// ---------------- sparsify ----------------
__global__ __launch_bounds__(128) void sparsify_kernel(const float* __restrict__ kv,
                                                       const float* __restrict__ imp,
                                                       const float* __restrict__ thr,
                                                       ushort_t* __restrict__ ksp,
                                                       ushort_t* __restrict__ vsp,
                                                       float* __restrict__ ebias) {
  const int b = blockIdx.x;
  const int j = b >> 3;
  const int h = b & 7;
  const int t = threadIdx.x;
  float ipv = imp[h * S_ + j];
  bool dense = (j >= S_ - W_) || (j < 2);
  int lvl = dense ? 0 : ((ipv >= thr[0]) ? 0 : ((ipv < thr[1]) ? 2 : 1));
  if (t == 0) ebias[h * S_ + j] = (lvl == 2) ? -INFINITY : 0.0f;
  __shared__ float av[128];
  __shared__ float thv;
  size_t base_in = (size_t)j * KLD_ + h * D_;
  size_t base_out = (size_t)j * NKV_ + h * D_;
  float kvv = kv[base_in + t];
  av[t] = fabsf(kvv);
  __syncthreads();
  {
    float at = av[t]; int cnt = 0;
    for (int m = 0; m < 128; ++m) { float am = av[m]; cnt += (am < at) || (am == at && m < t); }
    if (cnt == THR_IDX_) thv = at;
  }
  __syncthreads();
  {
    bool keep = (lvl == 0) || (lvl == 1 && fabsf(kvv) >= thv);
    ksp[base_out + t] = f2bf(keep ? kvv : 0.0f);
  }
  __syncthreads();
  float vvv = kv[base_in + 1024 + t];
  av[t] = fabsf(vvv);
  __syncthreads();
  {
    float at = av[t]; int cnt = 0;
    for (int m = 0; m < 128; ++m) { float am = av[m]; cnt += (am < at) || (am == at && m < t); }
    if (cnt == THR_IDX_) thv = at;
  }
  __syncthreads();
  {
    bool keep = (lvl == 0) || (lvl == 1 && fabsf(vvv) >= thv);
    vsp[base_out + t] = f2bf(keep ? vvv : 0.0f);
  }
}

// ---------------- V transpose ----------------
__global__ __launch_bounds__(256) void vtrans_kernel(const ushort_t* __restrict__ vsp,
                                                     ushort_t* __restrict__ vspT) {
  __shared__ ushort_t tl[64][136];
  const int jt = blockIdx.x;
  const int hk = blockIdx.y;
  const int t = threadIdx.x;
#pragma unroll
  for (int i = 0; i < 4; ++i) {
    int idx = i * 256 + t;
    int j = idx >> 4, c = idx & 15;
    *(u16x8*)&tl[j][c * 8] = *(const u16x8*)(vsp + (size_t)(jt * 64 + j) * NKV_ + hk * 128 + c * 8);
  }
  __syncthreads();
  int d = t >> 1, j0 = (t & 1) * 32;
#pragma unroll
  for (int jj = 0; jj < 4; ++jj) {
    u16x8 v;
#pragma unroll
    for (int e = 0; e < 8; ++e) v[e] = tl[j0 + jj * 8 + e][d];
    *(u16x8*)(vspT + ((size_t)hk * 128 + d) * S_ + jt * 64 + j0 + jj * 8) = v;
  }
}

// ---------------- main attention ----------------
#define SPAD_ 66
__global__ __launch_bounds__(256) void attn_kernel(const ushort_t* __restrict__ qbp,
                                                   const ushort_t* __restrict__ ksp,
                                                   const ushort_t* __restrict__ vspT,
                                                   const float* __restrict__ ebias,
                                                   ushort_t* __restrict__ ob16) {
  __shared__ ushort_t k_lds[64 * 128];
  __shared__ ushort_t vT_lds[128 * 64];
  __shared__ float s_lds[4][16][SPAD_];
  const int b = blockIdx.x;
  const int xcd = b & 7;
  const int idx = b >> 3;
  const int h = xcd * 4 + (idx >> 4);
  const int p = idx & 15;
  const int hk = h >> 2;
  const int t = threadIdx.x;
  const int w = t >> 6, lane = t & 63;
  const int lc = lane & 15, lg = lane >> 4;

  const ushort_t* kbase = ksp + hk * D_;
  const ushort_t* vbase = vspT + (size_t)hk * D_ * S_;

  for (int strip = 0; strip < 2; ++strip) {
    const int qb = (strip == 0) ? p : 31 - p;
    const int q0 = qb * 64 + w * 16;
    s16x8 qfrag[4];
#pragma unroll
    for (int db = 0; db < 4; ++db)
      qfrag[db] = *(const s16x8*)(qbp + (size_t)(q0 + lc) * NQ_ + h * D_ + db * 32 + lg * 8);

    f32x4 o[8];
#pragma unroll
    for (int n = 0; n < 8; ++n) o[n] = 0.f;
    float mr[4] = {-INFINITY, -INFINITY, -INFINITY, -INFINITY};
    float lr[4] = {0.f, 0.f, 0.f, 0.f};

    const int ntj = qb + 1;
    for (int tj = 0; tj < ntj; ++tj) {
      const int j0 = tj * 64;
      __syncthreads();
#pragma unroll
      for (int i = 0; i < 4; ++i) {
        int slot = i * 256 + w * 64 + lane;
        int row = slot >> 4, c = slot & 15;
        const ushort_t* gp = kbase + (size_t)(j0 + row) * NKV_ + ((c ^ (row & 7)) * 8);
        gload_lds16(gp, &k_lds[(i * 256 + w * 64) * 8]);
      }
#pragma unroll
      for (int i = 0; i < 4; ++i) {
        int slot = i * 256 + w * 64 + lane;
        int d = slot >> 3, c = slot & 7;
        const ushort_t* gp = vbase + (size_t)d * S_ + j0 + ((c ^ (d & 7)) * 8);
        gload_lds16(gp, &vT_lds[(i * 256 + w * 64) * 8]);
      }
      __syncthreads();

      f32x4 sfr[4];
#pragma unroll
      for (int js = 0; js < 4; ++js) sfr[js] = 0.f;
#pragma unroll
      for (int js = 0; js < 4; ++js) {
        int row = js * 16 + lc;
#pragma unroll
        for (int db = 0; db < 4; ++db) {
          s16x8 kf = *(const s16x8*)&k_lds[row * 128 + (((db * 4 + lg) ^ (lc & 7)) * 8)];
          sfr[js] = __builtin_amdgcn_mfma_f32_16x16x32_bf16(qfrag[db], kf, sfr[js], 0, 0, 0);
        }
      }
      float eb[4];
#pragma unroll
      for (int js = 0; js < 4; ++js) eb[js] = ebias[hk * S_ + j0 + js * 16 + lc];

      const bool diag = (tj == qb);
      float sclv[4];
#pragma unroll
      for (int r = 0; r < 4; ++r) {
        float sv[4];
#pragma unroll
        for (int js = 0; js < 4; ++js) sv[js] = sfr[js][r] * SCALE_ + eb[js];
        if (diag) {
          int qrow = w * 16 + lg * 4 + r;
#pragma unroll
          for (int js = 0; js < 4; ++js)
            if (js * 16 + lc > qrow) sv[js] = -INFINITY;
        }
        float tm = fmaxf(fmaxf(sv[0], sv[1]), fmaxf(sv[2], sv[3]));
#pragma unroll
        for (int off = 1; off < 16; off <<= 1) tm = fmaxf(tm, __shfl_xor(tm, off, 64));
        float mnew = fmaxf(mr[r], tm);
        float scl = __expf(mr[r] - mnew);
        float ps = 0.f;
#pragma unroll
        for (int js = 0; js < 4; ++js) {
          float e = __expf(sv[js] - mnew);
          s_lds[w][lg * 4 + r][js * 16 + lc] = e;
          ps += e;
        }
#pragma unroll
        for (int off = 1; off < 16; off <<= 1) ps += __shfl_xor(ps, off, 64);
        lr[r] = lr[r] * scl + ps;
        mr[r] = mnew;
        sclv[r] = scl;
      }
#pragma unroll
      for (int n = 0; n < 8; ++n) {
        f32x4 ov = o[n];
#pragma unroll
        for (int r = 0; r < 4; ++r) ov[r] *= sclv[r];
        o[n] = ov;
      }
      asm volatile("s_waitcnt lgkmcnt(0)" ::: "memory");
      s16x8 pa[2];
#pragma unroll
      for (int ks = 0; ks < 2; ++ks) {
        float pv[8];
        *(f32x4*)&pv[0] = *(const f32x4*)&s_lds[w][lc][ks * 32 + lg * 8];
        *(f32x4*)&pv[4] = *(const f32x4*)&s_lds[w][lc][ks * 32 + lg * 8 + 4];
        s16x8 pk;
#pragma unroll
        for (int e = 0; e < 8; ++e) pk[e] = (short)f2bf(pv[e]);
        pa[ks] = pk;
      }
#pragma unroll
      for (int n = 0; n < 8; ++n) {
        int d = n * 16 + lc;
#pragma unroll
        for (int ks = 0; ks < 2; ++ks) {
          s16x8 vf = *(const s16x8*)&vT_lds[d * 64 + (((ks * 4 + lg) ^ (lc & 7)) * 8)];
          o[n] = __builtin_amdgcn_mfma_f32_16x16x32_bf16(pa[ks], vf, o[n], 0, 0, 0);
        }
      }
    }
#pragma unroll
    for (int r = 0; r < 4; ++r) {
      float rinv = 1.0f / lr[r];
      int row = q0 + lg * 4 + r;
#pragma unroll
      for (int n = 0; n < 8; ++n)
        ob16[(size_t)row * NQ_ + h * D_ + n * 16 + lc] = f2bf(o[n][r] * rinv);
    }
  }
}

// ---------------- launcher ----------------
extern "C" void kernel_launch(void* const* d_in, const int* in_sizes, int n_in,
                              void* d_out, int out_size, void* d_ws, size_t ws_size,
                              hipStream_t stream) {
  (void)in_sizes; (void)n_in; (void)out_size; (void)ws_size;
  const float* hid = (const float*)d_in[0];
  const float* wq  = (const float*)d_in[1];
  const float* wk  = (const float*)d_in[2];
  const float* wv  = (const float*)d_in[3];
  const float* wo  = (const float*)d_in[4];
  float* out = (float*)d_out;
  char* ws = (char*)d_ws;
  const size_t MB = 1ull << 20;

  ushort_t* h0     = (ushort_t*)(ws + 0 * MB);     // A -> gemm1 Q (D)
  ushort_t* h1     = (ushort_t*)(ws + 16 * MB);    // A -> gemm6s KV (C)
  ushort_t* h2     = (ushort_t*)(ws + 32 * MB);    // A -> gemm6s KV (C)
  ushort_t* wq0T   = (ushort_t*)(ws + 48 * MB);    // A -> gemm1 Q (D)
  ushort_t* wq1T   = (ushort_t*)(ws + 80 * MB);    // A -> gemm6s obsQ (B)
  ushort_t* wq2T   = (ushort_t*)(ws + 112 * MB);   // A -> gemm6s obsQ (B)
  ushort_t* wkv0T  = (ushort_t*)(ws + 144 * MB);   // A -> gemm6s KV (C)
  ushort_t* wkv1T  = (ushort_t*)(ws + 160 * MB);   // A -> gemm6s KV (C)
  ushort_t* wkv2T  = (ushort_t*)(ws + 176 * MB);   // A -> gemm6s KV (C)
  float*    qpart  = (float*)(ws + 192 * MB);      // gemm6s obsQ -> qobs_fuse (16 MB)
  float*    kvf    = (float*)(ws + 192 * MB);      // kv_finish (C) -> sparsify (I), over dead qpart
  float*    kvp    = (float*)(ws + 80 * MB);       // KV partials 64 MB (over dead wq1T/2T)
  float*    qp2    = (float*)(ws + 80 * MB);       // Q partials 64 MB (over dead kvp)
  ushort_t* qb16   = (ushort_t*)(ws + 16 * MB);    // rope_q_fuse (F) -> attn (I), over dead h1
  ushort_t* kb0    = (ushort_t*)(ws + 32 * MB);    // kv_finish (C) -> gemm6z (G), over dead h2
  ushort_t* kb1    = (ushort_t*)(ws + 36 * MB);
  ushort_t* kb2    = (ushort_t*)(ws + 40 * MB);
  float*    s_obs  = (float*)(ws + 48 * MB);       // gemm6z (G) -> colsum (G), 32 MB over dead wq0T
  ushort_t* woT    = (ushort_t*)(ws + 144 * MB);   // splitT wo (E) -> outproj (I)
  ushort_t* ksp    = (ushort_t*)(ws + 176 * MB);   // sparsify -> attn (I)
  ushort_t* vsp    = (ushort_t*)(ws + 180 * MB);
  ushort_t* vspT   = (ushort_t*)(ws + 184 * MB);
  ushort_t* ob16   = (ushort_t*)(ws + 188 * MB + 512 * 1024);  // attn -> outproj (I)
  float*    opart  = (float*)(ws + 0 * MB);        // outproj partials 64 MB (I-last)
  ushort_t* qo0    = (ushort_t*)(ws + 208 * MB);   // qobs_fuse -> gemm6z
  ushort_t* qo1    = (ushort_t*)(ws + 209 * MB);
  ushort_t* qo2    = (ushort_t*)(ws + 210 * MB);
  char*     misc   = ws + 212 * MB;
  float*    impv   = (float*)(misc + 0);
  float*    eb     = (float*)(misc + 64 * 1024);
  float*    invf   = (float*)(misc + 128 * 1024);
  float*    thr    = (float*)(misc + 132 * 1024);
  float*    mxbuf  = (float*)(misc + 160 * 1024);
  float*    dinvb  = (float*)(misc + 192 * 1024);
  float*    part   = (float*)(misc + 256 * 1024);  // 512 KB

  freq_kernel<<<1, 64, 0, stream>>>(invf);

  // A) splits
  split3_kernel<<<(S_ * HID_ / 4 + 255) / 256, 256, 0, stream>>>(hid, h0, h1, h2, S_ * HID_ / 4);
  splitT_kernel<<<dim3(NQ_ / 64, HID_ / 64), 256, 0, stream>>>(wq, NQ_, wq0T, wq1T, wq2T);
  splitT_kernel<<<dim3(NKV_ / 64, HID_ / 64), 256, 0, stream>>>(wk, NKV_, wkv0T, wkv1T, wkv2T);
  splitT_kernel<<<dim3(NKV_ / 64, HID_ / 64), 256, 0, stream>>>(
      wv, NKV_, wkv0T + (size_t)NKV_ * HID_, wkv1T + (size_t)NKV_ * HID_, wkv2T + (size_t)NKV_ * HID_);

  // B) obs-Q: 6-term shared-stage GEMM (z=8 K-slices) + fused sum+rope+split
  const size_t obs_off = (size_t)(S_ - OBS_) * HID_;
  {
    Six P;
    P.A[0] = h0 + obs_off; P.A[1] = h1 + obs_off; P.A[2] = h2 + obs_off;
    P.B[0] = wq0T; P.B[1] = wq1T; P.B[2] = wq2T;
    gemm6s<<<dim3(NQ_ / 128, 1, 8), 256, 0, stream>>>(P, qpart, 128, NQ_, HID_, 16);
  }
  qobs_fuse<<<(OBS_ * HQ_ * 64) / 256, 256, 0, stream>>>(qpart, invf, qo0, qo1, qo2);

  // C) KV: 6-term shared-stage GEMM (split-K z=4) + fused sum4/rope/split
  {
    Six P;
    P.A[0] = h0; P.A[1] = h1; P.A[2] = h2;
    P.B[0] = wkv0T; P.B[1] = wkv1T; P.B[2] = wkv2T;
    gemm6s<<<dim3(KLD_ / 128, S_ / 128, 4), 256, 0, stream>>>(P, kvp, S_, KLD_, HID_, 32);
  }
  kv_finish<<<6144, 256, 0, stream>>>(kvp, invf, kvf, kb0, kb1, kb2);

  // D) Q main GEMM split-K z=2 (partials over dead kvp)
  gemm1<<<dim3(NQ_ / 128, S_ / 128, 2), 256, 0, stream>>>(h0, wq0T, qp2, S_, NQ_, HID_, 32);

  // E) wo transpose+cast
  splitT_kernel<<<dim3(HID_ / 64, HID_ / 64), 256, 0, stream>>>(wo, HID_, woT, nullptr, nullptr);

  // F) fused RoPE for Q
  rope_q_fuse<<<(S_ * HQ_ * 64) / 256, 256, 0, stream>>>(qp2, invf, qb16);

  // G) obs importance
  {
    TermPtrs P;
    P.a[0] = qo0; P.b[0] = kb0;
    P.a[1] = qo0; P.b[1] = kb1;
    P.a[2] = qo1; P.b[2] = kb0;
    P.a[3] = qo1; P.b[3] = kb1;
    P.a[4] = qo0; P.b[4] = kb2;
    P.a[5] = qo2; P.b[5] = kb0;
    gemm6z<<<dim3(16, 4, 8), 256, 0, stream>>>(P, s_obs);
  }
  rowstat_kernel<<<1024, 256, 0, stream>>>(s_obs, mxbuf, dinvb);
  colsum_part<<<dim3(8, 8, 8), 256, 0, stream>>>(s_obs, mxbuf, dinvb, part);
  colsum_fin<<<64, 256, 0, stream>>>(part, impv);

  // H) quantile thresholds
  radix_all<<<1, 1024, 0, stream>>>(impv, thr);

  // I) sparsify + V-transpose + attention + out projection (split-K z=2)
  sparsify_kernel<<<S_ * HKV_, 128, 0, stream>>>(kvf, impv, thr, ksp, vsp, eb);
  vtrans_kernel<<<dim3(S_ / 64, HKV_), 256, 0, stream>>>(vsp, vspT);
  attn_kernel<<<512, 256, 0, stream>>>(qb16, ksp, vspT, eb, ob16);
  gemm1<<<dim3(HID_ / 128, S_ / 128, 2), 256, 0, stream>>>(ob16, woT, opart, S_, HID_, HID_, 32);
  reduce2_kernel<<<(S_ * HID_ / 4 + 255) / 256, 256, 0, stream>>>(opart, out, S_ * HID_ / 4);
}

// Round 11
// 786.724 us; speedup vs baseline: 1.3329x; 1.0770x over previous
//
#include <hip/hip_runtime.h>
#include <hip/hip_bf16.h>
#include <math.h>

#define S_    2048
#define HID_  4096
#define HQ_   32
#define HKV_  8
#define D_    128
#define G_    4
#define OBS_  128
#define W_    32
#define NKV_  1024
#define NQ_   4096
#define KLD_  2048
#define SCALE_ 0.08838834764831845f
#define THR_IDX_ 89
#define NC_   16128

typedef __attribute__((ext_vector_type(4))) float f32x4;
typedef __attribute__((ext_vector_type(8))) short s16x8;
typedef __attribute__((ext_vector_type(8))) unsigned short u16x8;
typedef __attribute__((ext_vector_type(4))) unsigned short u16x4;
typedef unsigned short ushort_t;

struct TermPtrs { const ushort_t* a[6]; const ushort_t* b[6]; };
struct M1A { const ushort_t* A[3]; const ushort_t* B[3];
             const ushort_t* QA[3]; const ushort_t* QB[3]; };

__device__ __forceinline__ unsigned short f2bf(float x) {
  union { float f; unsigned u; } v; v.f = x;
  unsigned r = v.u + 0x7FFFu + ((v.u >> 16) & 1u);
  return (unsigned short)(r >> 16);
}
__device__ __forceinline__ float bf2f(unsigned short b) {
  union { unsigned u; float f; } v; v.u = ((unsigned)b) << 16;
  return v.f;
}
__device__ __forceinline__ void gload_lds16(const void* g, void* l) {
  __builtin_amdgcn_global_load_lds((const __attribute__((address_space(1))) unsigned int*)g,
                                   (__attribute__((address_space(3))) unsigned int*)l, 16, 0, 0);
}
__device__ __forceinline__ void term_sel(const TermPtrs& P, int tt,
                                         const ushort_t*& As, const ushort_t*& Bs) {
  switch (tt) {
    case 0: As = P.a[0]; Bs = P.b[0]; break;
    case 1: As = P.a[1]; Bs = P.b[1]; break;
    case 2: As = P.a[2]; Bs = P.b[2]; break;
    case 3: As = P.a[3]; Bs = P.b[3]; break;
    case 4: As = P.a[4]; Bs = P.b[4]; break;
    default: As = P.a[5]; Bs = P.b[5]; break;
  }
}
// XCD-aware bijective swizzle within the (x,y) plane; plane size must be %8==0.
__device__ __forceinline__ void xcd_bmbn(int& bm, int& bn) {
  int nplane = gridDim.x * gridDim.y;
  int l = blockIdx.y * gridDim.x + blockIdx.x;
  int v = (l & 7) * (nplane >> 3) + (l >> 3);
  bm = v / gridDim.x;
  bn = v - bm * gridDim.x;
}

// ---------------- device body: split+transpose one 64x64 tile ----------------
__device__ __forceinline__ void splitT_body(const float* __restrict__ src, int N,
                                            ushort_t* __restrict__ t0,
                                            ushort_t* __restrict__ t1,
                                            ushort_t* __restrict__ t2,
                                            int idx, float (*tile)[65]) {
  const int t = threadIdx.x;
  const int ntx = N >> 6;
  const int n0 = (idx % ntx) * 64, k0 = (idx / ntx) * 64;
#pragma unroll
  for (int i = 0; i < 16; ++i) {
    int s = i * 256 + t;
    int r = s >> 6, c = s & 63;
    tile[r][c] = src[(size_t)(k0 + r) * N + n0 + c];
  }
  __syncthreads();
#pragma unroll
  for (int i = 0; i < 16; ++i) {
    int s = i * 256 + t;
    int n = s >> 6, kk = s & 63;
    float x = tile[kk][n];
    unsigned short b0 = f2bf(x);
    size_t o = (size_t)(n0 + n) * HID_ + k0 + kk;
    t0[o] = b0;
    if (t1) {
      float r = x - bf2f(b0);
      unsigned short b1 = f2bf(r);
      t1[o] = b1;
      t2[o] = f2bf(r - bf2f(b1));
    }
  }
}

// ---------------- prep: freq + split3(hidden) + splitT(wq,wk,wv) ----------------
__global__ __launch_bounds__(256) void prep_kernel(const float* __restrict__ hid,
                                                   const float* __restrict__ wq,
                                                   const float* __restrict__ wk,
                                                   const float* __restrict__ wv,
                                                   ushort_t* h0, ushort_t* h1, ushort_t* h2,
                                                   ushort_t* wq0T, ushort_t* wq1T, ushort_t* wq2T,
                                                   ushort_t* wkv0T, ushort_t* wkv1T, ushort_t* wkv2T,
                                                   float* invf) {
  __shared__ float tile[64][65];
  const int b = blockIdx.x;
  if (b < 8192) {
    int idx = b * 256 + threadIdx.x;
    float4 v = ((const float4*)hid)[idx];
    u16x4 o0, o1, o2;
    float xs[4] = {v.x, v.y, v.z, v.w};
#pragma unroll
    for (int e = 0; e < 4; ++e) {
      float x = xs[e];
      unsigned short b0 = f2bf(x);
      float r = x - bf2f(b0);
      unsigned short b1 = f2bf(r);
      o0[e] = b0; o1[e] = b1; o2[e] = f2bf(r - bf2f(b1));
    }
    *(u16x4*)(h0 + (size_t)idx * 4) = o0;
    *(u16x4*)(h1 + (size_t)idx * 4) = o1;
    *(u16x4*)(h2 + (size_t)idx * 4) = o2;
  } else if (b < 12288) {
    splitT_body(wq, NQ_, wq0T, wq1T, wq2T, b - 8192, tile);
  } else if (b < 13312) {
    splitT_body(wk, NKV_, wkv0T, wkv1T, wkv2T, b - 12288, tile);
  } else if (b < 14336) {
    splitT_body(wv, NKV_, wkv0T + (size_t)NKV_ * HID_, wkv1T + (size_t)NKV_ * HID_,
                wkv2T + (size_t)NKV_ * HID_, b - 13312, tile);
  } else {
    int j = threadIdx.x;
    if (j < 64) invf[j] = (float)(1.0 / pow(500000.0, (double)j / 64.0));
  }
}

// ---------------- merged 6-term shared-stage GEMM: KV (z<2) + obsQ (z==2) ----------
// Terms accumulated: A0B0, A0B1, A0B2, A1B0, A1B1, A2B0. Rotation swizzle (verified 0-conflict).
__global__ __launch_bounds__(256) void gemm6m(M1A P, float* __restrict__ kvp,
                                              float* __restrict__ qpart) {
  __shared__ ushort_t lds[6 * 128 * 32];   // 48KB
  const int t = threadIdx.x;
  const int wave = t >> 6, lane = t & 63;
  const int lc = lane & 15, lg = lane >> 4;
  const int wm = wave >> 1, wn = wave & 1;
  const int z = blockIdx.z;

  const ushort_t *As0, *As1, *As2, *Bs0, *Bs1, *Bs2;
  float* C;
  int rowA, rowB, kbeg, ksteps, N, crow0, ccol0;
  if (z < 2) {
    int bm, bn;
    xcd_bmbn(bm, bn);
    As0 = P.A[0]; As1 = P.A[1]; As2 = P.A[2];
    Bs0 = P.B[0]; Bs1 = P.B[1]; Bs2 = P.B[2];
    rowA = bm * 128; rowB = bn * 128;
    kbeg = z * 64; ksteps = 64; N = KLD_;
    C = kvp + (size_t)z * S_ * KLD_;
    crow0 = bm * 128; ccol0 = bn * 128;
  } else {
    int l = blockIdx.y * gridDim.x + blockIdx.x;
    int bn = l & 31, ks = l >> 5;
    As0 = P.QA[0]; As1 = P.QA[1]; As2 = P.QA[2];
    Bs0 = P.QB[0]; Bs1 = P.QB[1]; Bs2 = P.QB[2];
    rowA = 0; rowB = bn * 128;
    kbeg = ks * 16; ksteps = 16; N = NQ_;
    C = qpart + (size_t)ks * 128 * NQ_;
    crow0 = 0; ccol0 = bn * 128;
  }

  f32x4 acc[4][4];
#pragma unroll
  for (int fi = 0; fi < 4; ++fi)
#pragma unroll
    for (int fj = 0; fj < 4; ++fj) acc[fi][fj] = 0.f;

  for (int kb = kbeg; kb < kbeg + ksteps; ++kb) {
    __syncthreads();
#pragma unroll
    for (int ti = 0; ti < 6; ++ti) {
      const ushort_t* src = (ti == 0) ? As0 : (ti == 1) ? As1 : (ti == 2) ? As2
                          : (ti == 3) ? Bs0 : (ti == 4) ? Bs1 : Bs2;
      const int rb = (ti < 3) ? rowA : rowB;
#pragma unroll
      for (int it = 0; it < 2; ++it) {
        int slot = it * 256 + t;
        int row = slot >> 2, cp = slot & 3;
        int c = (cp - (row >> 1)) & 3;      // inverse rotation on SOURCE
        gload_lds16(src + (size_t)(rb + row) * HID_ + kb * 32 + c * 8,
                    lds + ti * 4096 + it * 2048 + wave * 512);
      }
    }
    __syncthreads();
    s16x8 a0[4], a1[4], a2[4], bfr[4];
#pragma unroll
    for (int f = 0; f < 4; ++f) {
      int ra = wm * 64 + f * 16 + lc;
      int ca = ((lg + (ra >> 1)) & 3) * 8;
      a0[f] = *(const s16x8*)(lds + 0 * 4096 + ra * 32 + ca);
      a1[f] = *(const s16x8*)(lds + 1 * 4096 + ra * 32 + ca);
      a2[f] = *(const s16x8*)(lds + 2 * 4096 + ra * 32 + ca);
    }
#pragma unroll
    for (int f = 0; f < 4; ++f) {
      int rb2 = wn * 64 + f * 16 + lc;
      bfr[f] = *(const s16x8*)(lds + 3 * 4096 + rb2 * 32 + (((lg + (rb2 >> 1)) & 3) * 8));
    }
#pragma unroll
    for (int fi = 0; fi < 4; ++fi)
#pragma unroll
      for (int fj = 0; fj < 4; ++fj) {
        acc[fi][fj] = __builtin_amdgcn_mfma_f32_16x16x32_bf16(a0[fi], bfr[fj], acc[fi][fj], 0, 0, 0);
        acc[fi][fj] = __builtin_amdgcn_mfma_f32_16x16x32_bf16(a1[fi], bfr[fj], acc[fi][fj], 0, 0, 0);
        acc[fi][fj] = __builtin_amdgcn_mfma_f32_16x16x32_bf16(a2[fi], bfr[fj], acc[fi][fj], 0, 0, 0);
      }
#pragma unroll
    for (int f = 0; f < 4; ++f) {
      int rb2 = wn * 64 + f * 16 + lc;
      bfr[f] = *(const s16x8*)(lds + 4 * 4096 + rb2 * 32 + (((lg + (rb2 >> 1)) & 3) * 8));
    }
#pragma unroll
    for (int fi = 0; fi < 4; ++fi)
#pragma unroll
      for (int fj = 0; fj < 4; ++fj) {
        acc[fi][fj] = __builtin_amdgcn_mfma_f32_16x16x32_bf16(a0[fi], bfr[fj], acc[fi][fj], 0, 0, 0);
        acc[fi][fj] = __builtin_amdgcn_mfma_f32_16x16x32_bf16(a1[fi], bfr[fj], acc[fi][fj], 0, 0, 0);
      }
#pragma unroll
    for (int f = 0; f < 4; ++f) {
      int rb2 = wn * 64 + f * 16 + lc;
      bfr[f] = *(const s16x8*)(lds + 5 * 4096 + rb2 * 32 + (((lg + (rb2 >> 1)) & 3) * 8));
    }
#pragma unroll
    for (int fi = 0; fi < 4; ++fi)
#pragma unroll
      for (int fj = 0; fj < 4; ++fj)
        acc[fi][fj] = __builtin_amdgcn_mfma_f32_16x16x32_bf16(a0[fi], bfr[fj], acc[fi][fj], 0, 0, 0);
  }
#pragma unroll
  for (int fi = 0; fi < 4; ++fi)
#pragma unroll
    for (int fj = 0; fj < 4; ++fj)
#pragma unroll
      for (int r = 0; r < 4; ++r)
        C[(size_t)(crow0 + wm * 64 + fi * 16 + lg * 4 + r) * N +
          ccol0 + wn * 64 + fj * 16 + lc] = acc[fi][fj][r];
}

// ---------------- single-term GEMM body (BK=64, full/partial K) ----------------
__device__ __forceinline__ void gemm1_body(const ushort_t* __restrict__ A,
                                           const ushort_t* __restrict__ B,
                                           float* __restrict__ C,
                                           int N, int K, int KSTEPS, ushort_t* lds) {
  const int t = threadIdx.x;
  const int wave = t >> 6, lane = t & 63;
  const int lc = lane & 15, lg = lane >> 4;
  int bm, bn;
  xcd_bmbn(bm, bn);
  const int wm = wave >> 1, wn = wave & 1;
  const int srow = t >> 3, schunk = t & 7;

  f32x4 acc[4][4];
#pragma unroll
  for (int fi = 0; fi < 4; ++fi)
#pragma unroll
    for (int fj = 0; fj < 4; ++fj) acc[fi][fj] = 0.f;

  for (int kb = 0; kb < KSTEPS; ++kb) {
    __syncthreads();
#pragma unroll
    for (int g = 0; g < 4; ++g) {
      int row = g * 32 + srow;
      int sw = schunk ^ (row & 7);
      size_t co = kb * 64 + sw * 8;
      gload_lds16(A + (size_t)(bm * 128 + row) * K + co, lds + g * 2048 + wave * 512);
      gload_lds16(B + (size_t)(bn * 128 + row) * K + co, lds + 8192 + g * 2048 + wave * 512);
    }
    __syncthreads();
#pragma unroll
    for (int ks = 0; ks < 2; ++ks) {
      s16x8 af[4], bf[4];
#pragma unroll
      for (int f = 0; f < 4; ++f) {
        int ra = wm * 64 + f * 16 + lc;
        af[f] = *(const s16x8*)(lds + ra * 64 + (((ks * 4 + lg) ^ (ra & 7)) * 8));
        int rb = wn * 64 + f * 16 + lc;
        bf[f] = *(const s16x8*)(lds + 8192 + rb * 64 + (((ks * 4 + lg) ^ (rb & 7)) * 8));
      }
#pragma unroll
      for (int fi = 0; fi < 4; ++fi)
#pragma unroll
        for (int fj = 0; fj < 4; ++fj)
          acc[fi][fj] = __builtin_amdgcn_mfma_f32_16x16x32_bf16(af[fi], bf[fj], acc[fi][fj], 0, 0, 0);
    }
  }
#pragma unroll
  for (int fi = 0; fi < 4; ++fi)
#pragma unroll
    for (int fj = 0; fj < 4; ++fj)
#pragma unroll
      for (int r = 0; r < 4; ++r)
        C[(size_t)(bm * 128 + wm * 64 + fi * 16 + lg * 4 + r) * N +
          bn * 128 + wn * 64 + fj * 16 + lc] = acc[fi][fj][r];
}

__global__ __launch_bounds__(256) void gemm1(const ushort_t* __restrict__ A,
                                             const ushort_t* __restrict__ B,
                                             float* __restrict__ C,
                                             int N, int K, int KSTEPS) {
  __shared__ ushort_t lds[2 * 128 * 64];
  gemm1_body(A, B, C, N, K, KSTEPS, lds);
}

// ---------------- M2: z0 = Q GEMM; z1 = kv_finish + qobs_fuse + wo transpose ----------
__global__ __launch_bounds__(256) void m2_kernel(const ushort_t* __restrict__ h0,
                                                 const ushort_t* __restrict__ wq0T,
                                                 float* __restrict__ qf,
                                                 const float* __restrict__ kvp,
                                                 const float* __restrict__ invf,
                                                 float* __restrict__ kvf,
                                                 ushort_t* __restrict__ k0,
                                                 ushort_t* __restrict__ k1,
                                                 ushort_t* __restrict__ k2,
                                                 const float* __restrict__ qpart,
                                                 ushort_t* __restrict__ q0,
                                                 ushort_t* __restrict__ q1,
                                                 ushort_t* __restrict__ q2,
                                                 const float* __restrict__ wo,
                                                 ushort_t* __restrict__ woT) {
  __shared__ ushort_t lds[2 * 128 * 64];
  if (blockIdx.z == 0) {
    gemm1_body(h0, wq0T, qf, NQ_, HID_, 64, lds);
    return;
  }
  const int l = blockIdx.y * gridDim.x + blockIdx.x;   // 0..511
  const int t = threadIdx.x;
  const size_t n = (size_t)S_ * KLD_;
  // kv_finish: sum2 partials, RoPE K-half, 3-split K
  for (int vb = l; vb < 6144; vb += 512) {
    if (vb < 4096) {
      int idx = vb * 256 + t;
      int j = idx & 63;
      int h = (idx >> 6) & 7;
      int s = idx >> 9;
      size_t base = (size_t)s * KLD_ + h * 128 + j;
      float x1 = kvp[base] + kvp[base + n];
      float x2 = kvp[base + 64] + kvp[base + 64 + n];
      float ang = (float)s * invf[j];
      float sn, cs; sincosf(ang, &sn, &cs);
      float o1 = x1 * cs - x2 * sn;
      float o2 = x2 * cs + x1 * sn;
      kvf[base] = o1; kvf[base + 64] = o2;
      size_t o = (size_t)h * 262144 + (size_t)s * 128 + j;
      float ys[2] = {o1, o2};
#pragma unroll
      for (int e = 0; e < 2; ++e) {
        float x = ys[e];
        unsigned short b0 = f2bf(x);
        float r = x - bf2f(b0);
        unsigned short b1 = f2bf(r);
        k0[o + e * 64] = b0; k1[o + e * 64] = b1; k2[o + e * 64] = f2bf(r - bf2f(b1));
      }
    } else {
      int idx = (vb - 4096) * 256 + t;
      int s = idx >> 8, c4 = idx & 255;
      size_t base = (size_t)s * KLD_ + 1024 + c4 * 4;
      float4 a = *(const float4*)(kvp + base);
      float4 bb = *(const float4*)(kvp + base + n);
      float4 o;
      o.x = a.x + bb.x; o.y = a.y + bb.y; o.z = a.z + bb.z; o.w = a.w + bb.w;
      *(float4*)(kvf + base) = o;
    }
  }
  // qobs_fuse: sum8 partials + RoPE + 3-split
  for (int vb = l; vb < 1024; vb += 512) {
    int idx = vb * 256 + t;
    int j = idx & 63;
    int hq = (idx >> 6) & 31;
    int i = idx >> 11;
    size_t base = (size_t)i * NQ_ + hq * 128 + j;
    float x1 = 0.f, x2 = 0.f;
#pragma unroll
    for (int z = 0; z < 8; ++z) {
      x1 += qpart[(size_t)z * OBS_ * NQ_ + base];
      x2 += qpart[(size_t)z * OBS_ * NQ_ + base + 64];
    }
    float ang = (float)(S_ - OBS_ + i) * invf[j];
    float sn, cs; sincosf(ang, &sn, &cs);
    float o1 = x1 * cs - x2 * sn;
    float o2 = x2 * cs + x1 * sn;
    int hk = hq >> 2, g = hq & 3;
    size_t o = (size_t)hk * 65536 + (size_t)(g * 128 + i) * 128 + j;
    float ys[2] = {o1, o2};
#pragma unroll
    for (int e = 0; e < 2; ++e) {
      float x = ys[e];
      unsigned short b0 = f2bf(x);
      float r = x - bf2f(b0);
      unsigned short b1 = f2bf(r);
      q0[o + e * 64] = b0; q1[o + e * 64] = b1; q2[o + e * 64] = f2bf(r - bf2f(b1));
    }
  }
  // wo transpose+cast (single-term)
  float (*tile)[65] = (float(*)[65])lds;
  for (int vb = l; vb < 4096; vb += 512) {
    __syncthreads();
    splitT_body(wo, HID_, woT, nullptr, nullptr, vb, tile);
  }
}

// ---------------- s_obs: all 6 terms, z = kv-head, K=128 ----------------
__global__ __launch_bounds__(256) void gemm6z(TermPtrs P, float* __restrict__ Cg) {
  __shared__ ushort_t lds[2 * 128 * 64];
  const int t = threadIdx.x;
  const int wave = t >> 6, lane = t & 63;
  const int lc = lane & 15, lg = lane >> 4;
  const int bm = blockIdx.y, bn = blockIdx.x, z = blockIdx.z;
  const int wm = wave >> 1, wn = wave & 1;
  const int srow = t >> 3, schunk = t & 7;
  const size_t Aoff = (size_t)z * 512 * 128;
  const size_t Boff = (size_t)z * 2048 * 128;
  float* C = Cg + (size_t)z * 512 * 2048;

  f32x4 acc[4][4];
#pragma unroll
  for (int fi = 0; fi < 4; ++fi)
#pragma unroll
    for (int fj = 0; fj < 4; ++fj) acc[fi][fj] = 0.f;

  for (int tt = 0; tt < 6; ++tt) {
    const ushort_t *As, *Bs;
    term_sel(P, tt, As, Bs);
    As += Aoff; Bs += Boff;
    for (int kb = 0; kb < 2; ++kb) {
      __syncthreads();
#pragma unroll
      for (int g = 0; g < 4; ++g) {
        int row = g * 32 + srow;
        int sw = schunk ^ (row & 7);
        gload_lds16(As + (size_t)(bm * 128 + row) * 128 + kb * 64 + sw * 8,
                    lds + g * 2048 + wave * 512);
        gload_lds16(Bs + (size_t)(bn * 128 + row) * 128 + kb * 64 + sw * 8,
                    lds + 8192 + g * 2048 + wave * 512);
      }
      __syncthreads();
#pragma unroll
      for (int ks = 0; ks < 2; ++ks) {
        s16x8 af[4], bf[4];
#pragma unroll
        for (int f = 0; f < 4; ++f) {
          int ra = wm * 64 + f * 16 + lc;
          af[f] = *(const s16x8*)(lds + ra * 64 + (((ks * 4 + lg) ^ (ra & 7)) * 8));
          int rb = wn * 64 + f * 16 + lc;
          bf[f] = *(const s16x8*)(lds + 8192 + rb * 64 + (((ks * 4 + lg) ^ (rb & 7)) * 8));
        }
#pragma unroll
        for (int fi = 0; fi < 4; ++fi)
#pragma unroll
          for (int fj = 0; fj < 4; ++fj)
            acc[fi][fj] = __builtin_amdgcn_mfma_f32_16x16x32_bf16(af[fi], bf[fj], acc[fi][fj], 0, 0, 0);
      }
    }
  }
#pragma unroll
  for (int fi = 0; fi < 4; ++fi)
#pragma unroll
    for (int fj = 0; fj < 4; ++fj)
#pragma unroll
      for (int r = 0; r < 4; ++r)
        C[(size_t)(bm * 128 + wm * 64 + fi * 16 + lg * 4 + r) * 2048 +
          bn * 128 + wn * 64 + fj * 16 + lc] = acc[fi][fj][r];
}

// ---------------- RoPE Q from fp32 qf -> qb16 ----------------
__global__ __launch_bounds__(256) void rope_q_fuse(const float* __restrict__ qf,
                                                   const float* __restrict__ invf,
                                                   ushort_t* __restrict__ qb16) {
  int idx = blockIdx.x * 256 + threadIdx.x;
  int j = idx & 63;
  int h = (idx >> 6) & 31;
  int s = idx >> 11;
  size_t base = (size_t)s * NQ_ + h * 128 + j;
  float x1 = qf[base];
  float x2 = qf[base + 64];
  float ang = (float)s * invf[j];
  float sn, cs; sincosf(ang, &sn, &cs);
  qb16[base] = f2bf(x1 * cs - x2 * sn);
  qb16[base + 64] = f2bf(x2 * cs + x1 * sn);
}

// ---------------- per-row max + inv-denominator (causal) ----------------
__global__ __launch_bounds__(256) void rowstat_kernel(const float* __restrict__ s,
                                                      float* __restrict__ mx,
                                                      float* __restrict__ dinv) {
  const int row = blockIdx.x * 4 + (threadIdx.x >> 6);
  const int lane = threadIdx.x & 63;
  const int i = row & 127;
  const int jmax = S_ - OBS_ + i;
  const float* sp = s + (size_t)row * S_;
  float vals[32];
  float m = -INFINITY;
#pragma unroll
  for (int c = 0; c < 8; ++c) {
    int j0 = c * 256 + lane * 4;
    float4 v = *(const float4*)(sp + j0);
    float e0 = (j0 + 0 <= jmax) ? v.x * SCALE_ : -INFINITY;
    float e1 = (j0 + 1 <= jmax) ? v.y * SCALE_ : -INFINITY;
    float e2 = (j0 + 2 <= jmax) ? v.z * SCALE_ : -INFINITY;
    float e3 = (j0 + 3 <= jmax) ? v.w * SCALE_ : -INFINITY;
    vals[c * 4 + 0] = e0; vals[c * 4 + 1] = e1; vals[c * 4 + 2] = e2; vals[c * 4 + 3] = e3;
    m = fmaxf(m, fmaxf(fmaxf(e0, e1), fmaxf(e2, e3)));
  }
#pragma unroll
  for (int off = 1; off < 64; off <<= 1) m = fmaxf(m, __shfl_xor(m, off, 64));
  float ssum = 0.f;
#pragma unroll
  for (int c = 0; c < 32; ++c) ssum += expf(vals[c] - m);
#pragma unroll
  for (int off = 1; off < 64; off <<= 1) ssum += __shfl_xor(ssum, off, 64);
  if (lane == 0) { mx[row] = m; dinv[row] = 1.0f / ssum; }
}

// ---------------- column-sum stage 1 ----------------
__global__ __launch_bounds__(256) void colsum_part(const float* __restrict__ s,
                                                   const float* __restrict__ mx,
                                                   const float* __restrict__ dinv,
                                                   float* __restrict__ part) {
  __shared__ float mxl[64], dvl[64];
  const int jt = blockIdx.x, hk = blockIdx.y, rc = blockIdx.z;
  const int t = threadIdx.x;
  if (t < 64) {
    mxl[t] = mx[hk * 512 + rc * 64 + t];
    dvl[t] = dinv[hk * 512 + rc * 64 + t];
  }
  __syncthreads();
  const int j = jt * 256 + t;
  const float* sp = s + ((size_t)hk * 512 + rc * 64) * S_ + j;
  float acc = 0.f;
  for (int rr = 0; rr < 64; ++rr) {
    int i = (rc * 64 + rr) & 127;
    if (j <= S_ - OBS_ + i)
      acc += expf(sp[(size_t)rr * S_] * SCALE_ - mxl[rr]) * dvl[rr];
  }
  part[((size_t)rc * 8 + hk) * S_ + j] = acc;
}

// ---------------- column-sum stage 2 -> imp ----------------
__global__ void colsum_fin(const float* __restrict__ part, float* __restrict__ imp) {
  int idx = blockIdx.x * 256 + threadIdx.x;
  int hk = idx >> 11, j = idx & 2047;
  float acc = 0.f;
#pragma unroll
  for (int rc = 0; rc < 8; ++rc) acc += part[((size_t)rc * 8 + hk) * S_ + j];
  float cnt = (float)min(OBS_, S_ - j);
  imp[idx] = acc * 0.25f / cnt;
}

// ---------------- single-block radix select ----------------
__global__ __launch_bounds__(1024) void radix_all(const float* __restrict__ imp,
                                                  float* __restrict__ thr) {
  __shared__ unsigned hist[4][256];
  __shared__ unsigned pfx_s[4], need_s[4];
  const int t = threadIdx.x;
  if (t < 4) {
    pfx_s[t] = 0u;
    need_s[t] = (t == 0) ? 3225u : (t == 1) ? 3226u : (t == 2) ? 15320u : 15321u;
  }
  __syncthreads();
  for (int pass = 0; pass < 4; ++pass) {
    ((unsigned*)hist)[t] = 0u;
    __syncthreads();
    int shift = 24 - pass * 8;
    for (int idx = t; idx < NC_; idx += 1024) {
      int h = idx / (S_ - W_), j = idx - h * (S_ - W_);
      union { float f; unsigned u; } cv; cv.f = imp[h * S_ + j];
      unsigned u = cv.u;
#pragma unroll
      for (int q = 0; q < 4; ++q) {
        bool m = (pass == 0) || ((u >> (shift + 8)) == (pfx_s[q] >> (shift + 8)));
        if (m) atomicAdd(&hist[q][(u >> shift) & 255u], 1u);
      }
    }
    __syncthreads();
    if (t < 4) {
      unsigned need = need_s[t], cum = 0, pfx = pfx_s[t];
      for (int d = 0; d < 256; ++d) {
        unsigned c = hist[t][d];
        if (cum + c > need) { pfx |= ((unsigned)d) << shift; need_s[t] = need - cum; break; }
        cum += c;
      }
      pfx_s[t] = pfx;
    }
    __syncthreads();
  }
  if (t == 0) {
    union { unsigned u; float f; } c0, c1, c2, c3;
    c0.u = pfx_s[0]; c1.u = pfx_s[1]; c2.u = pfx_s[2]; c3.u = pfx_s[3];
    double fl = 0.2 * (double)(NC_ - 1) - 3225.0;
    double fh = 0.95 * (double)(NC_ - 1) - 15320.0;
    thr[0] = (float)((double)c2.f + ((double)c3.f - (double)c2.f) * fh);
    thr[1] = (float)((double)c0.f + ((double)c1.f - (double)c0.f) * fl);
  }
}

// ---------------- sparsify ----------------
__global__ __launch_bounds__(128) void sparsify_kernel(const float* __restrict__ kv,
                                                       const float* __restrict__ imp,
                                                       const float* __restrict__ thr,
                                                       ushort_t* __restrict__ ksp,
                                                       ushort_t* __restrict__ vsp,
                                                       float* __restrict__ ebias) {
  const int b = blockIdx.x;
  const int j = b >> 3;
  const int h = b & 7;
  const int t = threadIdx.x;
  float ipv = imp[h * S_ + j];
  bool dense = (j >= S_ - W_) || (j < 2);
  int lvl = dense ? 0 : ((ipv >= thr[0]) ? 0 : ((ipv < thr[1]) ? 2 : 1));
  if (t == 0) ebias[h * S_ + j] = (lvl == 2) ? -INFINITY : 0.0f;
  __shared__ float av[128];
  __shared__ float thv;
  size_t base_in = (size_t)j * KLD_ + h * D_;
  size_t base_out = (size_t)j * NKV_ + h * D_;
  float kvv = kv[base_in + t];
  av[t] = fabsf(kvv);
  __syncthreads();
  {
    float at = av[t]; int cnt = 0;
    for (int m = 0; m < 128; ++m) { float am = av[m]; cnt += (am < at) || (am == at && m < t); }
    if (cnt == THR_IDX_) thv = at;
  }
  __syncthreads();
  {
    bool keep = (lvl == 0) || (lvl == 1 && fabsf(kvv) >= thv);
    ksp[base_out + t] = f2bf(keep ? kvv : 0.0f);
  }
  __syncthreads();
  float vvv = kv[base_in + 1024 + t];
  av[t] = fabsf(vvv);
  __syncthreads();
  {
    float at = av[t]; int cnt = 0;
    for (int m = 0; m < 128; ++m) { float am = av[m]; cnt += (am < at) || (am == at && m < t); }
    if (cnt == THR_IDX_) thv = at;
  }
  __syncthreads();
  {
    bool keep = (lvl == 0) || (lvl == 1 && fabsf(vvv) >= thv);
    vsp[base_out + t] = f2bf(keep ? vvv : 0.0f);
  }
}

// ---------------- V transpose ----------------
__global__ __launch_bounds__(256) void vtrans_kernel(const ushort_t* __restrict__ vsp,
                                                     ushort_t* __restrict__ vspT) {
  __shared__ ushort_t tl[64][136];
  const int jt = blockIdx.x;
  const int hk = blockIdx.y;
  const int t = threadIdx.x;
#pragma unroll
  for (int i = 0; i < 4; ++i) {
    int idx = i * 256 + t;
    int j = idx >> 4, c = idx & 15;
    *(u16x8*)&tl[j][c * 8] = *(const u16x8*)(vsp + (size_t)(jt * 64 + j) * NKV_ + hk * 128 + c * 8);
  }
  __syncthreads();
  int d = t >> 1, j0 = (t & 1) * 32;
#pragma unroll
  for (int jj = 0; jj < 4; ++jj) {
    u16x8 v;
#pragma unroll
    for (int e = 0; e < 8; ++e) v[e] = tl[j0 + jj * 8 + e][d];
    *(u16x8*)(vspT + ((size_t)hk * 128 + d) * S_ + jt * 64 + j0 + jj * 8) = v;
  }
}

// ---------------- main attention ----------------
#define SPAD_ 66
__global__ __launch_bounds__(256) void attn_kernel(const ushort_t* __restrict__ qbp,
                                                   const ushort_t* __restrict__ ksp,
                                                   const ushort_t* __restrict__ vspT,
                                                   const float* __restrict__ ebias,
                                                   ushort_t* __restrict__ ob16) {
  __shared__ ushort_t k_lds[64 * 128];
  __shared__ ushort_t vT_lds[128 * 64];
  __shared__ float s_lds[4][16][SPAD_];
  const int b = blockIdx.x;
  const int xcd = b & 7;
  const int idx = b >> 3;
  const int h = xcd * 4 + (idx >> 4);
  const int p = idx & 15;
  const int hk = h >> 2;
  const int t = threadIdx.x;
  const int w = t >> 6, lane = t & 63;
  const int lc = lane & 15, lg = lane >> 4;

  const ushort_t* kbase = ksp + hk * D_;
  const ushort_t* vbase = vspT + (size_t)hk * D_ * S_;

  for (int strip = 0; strip < 2; ++strip) {
    const int qb = (strip == 0) ? p : 31 - p;
    const int q0 = qb * 64 + w * 16;
    s16x8 qfrag[4];
#pragma unroll
    for (int db = 0; db < 4; ++db)
      qfrag[db] = *(const s16x8*)(qbp + (size_t)(q0 + lc) * NQ_ + h * D_ + db * 32 + lg * 8);

    f32x4 o[8];
#pragma unroll
    for (int n = 0; n < 8; ++n) o[n] = 0.f;
    float mr[4] = {-INFINITY, -INFINITY, -INFINITY, -INFINITY};
    float lr[4] = {0.f, 0.f, 0.f, 0.f};

    const int ntj = qb + 1;
    for (int tj = 0; tj < ntj; ++tj) {
      const int j0 = tj * 64;
      __syncthreads();
#pragma unroll
      for (int i = 0; i < 4; ++i) {
        int slot = i * 256 + w * 64 + lane;
        int row = slot >> 4, c = slot & 15;
        const ushort_t* gp = kbase + (size_t)(j0 + row) * NKV_ + ((c ^ (row & 7)) * 8);
        gload_lds16(gp, &k_lds[(i * 256 + w * 64) * 8]);
      }
#pragma unroll
      for (int i = 0; i < 4; ++i) {
        int slot = i * 256 + w * 64 + lane;
        int d = slot >> 3, c = slot & 7;
        const ushort_t* gp = vbase + (size_t)d * S_ + j0 + ((c ^ (d & 7)) * 8);
        gload_lds16(gp, &vT_lds[(i * 256 + w * 64) * 8]);
      }
      __syncthreads();

      f32x4 sfr[4];
#pragma unroll
      for (int js = 0; js < 4; ++js) sfr[js] = 0.f;
#pragma unroll
      for (int js = 0; js < 4; ++js) {
        int row = js * 16 + lc;
#pragma unroll
        for (int db = 0; db < 4; ++db) {
          s16x8 kf = *(const s16x8*)&k_lds[row * 128 + (((db * 4 + lg) ^ (lc & 7)) * 8)];
          sfr[js] = __builtin_amdgcn_mfma_f32_16x16x32_bf16(qfrag[db], kf, sfr[js], 0, 0, 0);
        }
      }
      float eb[4];
#pragma unroll
      for (int js = 0; js < 4; ++js) eb[js] = ebias[hk * S_ + j0 + js * 16 + lc];

      const bool diag = (tj == qb);
      float sclv[4];
#pragma unroll
      for (int r = 0; r < 4; ++r) {
        float sv[4];
#pragma unroll
        for (int js = 0; js < 4; ++js) sv[js] = sfr[js][r] * SCALE_ + eb[js];
        if (diag) {
          int qrow = w * 16 + lg * 4 + r;
#pragma unroll
          for (int js = 0; js < 4; ++js)
            if (js * 16 + lc > qrow) sv[js] = -INFINITY;
        }
        float tm = fmaxf(fmaxf(sv[0], sv[1]), fmaxf(sv[2], sv[3]));
#pragma unroll
        for (int off = 1; off < 16; off <<= 1) tm = fmaxf(tm, __shfl_xor(tm, off, 64));
        float mnew = fmaxf(mr[r], tm);
        float scl = __expf(mr[r] - mnew);
        float ps = 0.f;
#pragma unroll
        for (int js = 0; js < 4; ++js) {
          float e = __expf(sv[js] - mnew);
          s_lds[w][lg * 4 + r][js * 16 + lc] = e;
          ps += e;
        }
#pragma unroll
        for (int off = 1; off < 16; off <<= 1) ps += __shfl_xor(ps, off, 64);
        lr[r] = lr[r] * scl + ps;
        mr[r] = mnew;
        sclv[r] = scl;
      }
#pragma unroll
      for (int n = 0; n < 8; ++n) {
        f32x4 ov = o[n];
#pragma unroll
        for (int r = 0; r < 4; ++r) ov[r] *= sclv[r];
        o[n] = ov;
      }
      asm volatile("s_waitcnt lgkmcnt(0)" ::: "memory");
      s16x8 pa[2];
#pragma unroll
      for (int ks = 0; ks < 2; ++ks) {
        float pv[8];
        *(f32x4*)&pv[0] = *(const f32x4*)&s_lds[w][lc][ks * 32 + lg * 8];
        *(f32x4*)&pv[4] = *(const f32x4*)&s_lds[w][lc][ks * 32 + lg * 8 + 4];
        s16x8 pk;
#pragma unroll
        for (int e = 0; e < 8; ++e) pk[e] = (short)f2bf(pv[e]);
        pa[ks] = pk;
      }
#pragma unroll
      for (int n = 0; n < 8; ++n) {
        int d = n * 16 + lc;
#pragma unroll
        for (int ks = 0; ks < 2; ++ks) {
          s16x8 vf = *(const s16x8*)&vT_lds[d * 64 + (((ks * 4 + lg) ^ (lc & 7)) * 8)];
          o[n] = __builtin_amdgcn_mfma_f32_16x16x32_bf16(pa[ks], vf, o[n], 0, 0, 0);
        }
      }
    }
#pragma unroll
    for (int r = 0; r < 4; ++r) {
      float rinv = 1.0f / lr[r];
      int row = q0 + lg * 4 + r;
#pragma unroll
      for (int n = 0; n < 8; ++n)
        ob16[(size_t)row * NQ_ + h * D_ + n * 16 + lc] = f2bf(o[n][r] * rinv);
    }
  }
}

// ---------------- launcher ----------------
extern "C" void kernel_launch(void* const* d_in, const int* in_sizes, int n_in,
                              void* d_out, int out_size, void* d_ws, size_t ws_size,
                              hipStream_t stream) {
  (void)in_sizes; (void)n_in; (void)out_size; (void)ws_size;
  const float* hid = (const float*)d_in[0];
  const float* wq  = (const float*)d_in[1];
  const float* wk  = (const float*)d_in[2];
  const float* wv  = (const float*)d_in[3];
  const float* wo  = (const float*)d_in[4];
  float* out = (float*)d_out;
  char* ws = (char*)d_ws;
  const size_t MB = 1ull << 20;

  // Overlay map (liveness audited against the 13-launch order):
  ushort_t* h0     = (ushort_t*)(ws + 0 * MB);     // L1 -> L3z0
  ushort_t* h1     = (ushort_t*)(ws + 16 * MB);    // L1 -> L2
  ushort_t* h2     = (ushort_t*)(ws + 32 * MB);    // L1 -> L2
  ushort_t* wq0T   = (ushort_t*)(ws + 48 * MB);    // L1 -> L3z0
  ushort_t* wq1T   = (ushort_t*)(ws + 80 * MB);    // L1 -> L2
  ushort_t* wq2T   = (ushort_t*)(ws + 112 * MB);   // L1 -> L2
  ushort_t* wkv0T  = (ushort_t*)(ws + 144 * MB);   // L1 -> L2
  ushort_t* wkv1T  = (ushort_t*)(ws + 160 * MB);   // L1 -> L2
  ushort_t* wkv2T  = (ushort_t*)(ws + 176 * MB);   // L1 -> L2
  float*    kvp    = (float*)d_out;                // L2 KV partials (2x16.78MB = exact d_out fit), read L3z1
  float*    qpart  = (float*)(ws + 192 * MB);      // L2 obsQ -> L3z1 (16 MB)
  float*    qf     = (float*)(ws + 80 * MB);       // L3z0 -> L4 (32 MB over dead wq1T)
  float*    kvf    = (float*)(ws + 112 * MB);      // L3z1 -> L10 (16 MB over dead wq2T)
  ushort_t* qb16   = (ushort_t*)(ws + 16 * MB);    // L4 -> L12 (over dead h1)
  ushort_t* kb0    = (ushort_t*)(ws + 32 * MB);    // L3z1 -> L5 (over dead h2)
  ushort_t* kb1    = (ushort_t*)(ws + 36 * MB);
  ushort_t* kb2    = (ushort_t*)(ws + 40 * MB);
  float*    s_obs  = (float*)(ws + 48 * MB);       // L5 -> L7 (32 MB over dead wq0T)
  ushort_t* woT    = (ushort_t*)(ws + 144 * MB);   // L3z1 -> L13 (over dead wkv0T/1T)
  ushort_t* ksp    = (ushort_t*)(ws + 176 * MB);   // L10 -> L12 (over dead wkv2T)
  ushort_t* vsp    = (ushort_t*)(ws + 180 * MB);
  ushort_t* vspT   = (ushort_t*)(ws + 184 * MB);
  ushort_t* ob16   = (ushort_t*)(ws + 188 * MB + 512 * 1024);  // L12 -> L13 (over dead qpart head)
  ushort_t* qo0    = (ushort_t*)(ws + 208 * MB);   // L3z1 -> L5
  ushort_t* qo1    = (ushort_t*)(ws + 209 * MB);
  ushort_t* qo2    = (ushort_t*)(ws + 210 * MB);
  char*     misc   = ws + 212 * MB;
  float*    impv   = (float*)(misc + 0);
  float*    eb     = (float*)(misc + 64 * 1024);
  float*    invf   = (float*)(misc + 128 * 1024);
  float*    thr    = (float*)(misc + 132 * 1024);
  float*    mxbuf  = (float*)(misc + 160 * 1024);
  float*    dinvb  = (float*)(misc + 192 * 1024);
  float*    part   = (float*)(misc + 256 * 1024);  // 512 KB

  // L1) prep: freq + split3 + splitT(wq,wk,wv)
  prep_kernel<<<14337, 256, 0, stream>>>(hid, wq, wk, wv, h0, h1, h2,
                                         wq0T, wq1T, wq2T, wkv0T, wkv1T, wkv2T, invf);

  // L2) merged GEMM: KV (split-K z=2 -> kvp@d_out) + obsQ (z=2 plane -> qpart)
  const size_t obs_off = (size_t)(S_ - OBS_) * HID_;
  {
    M1A P;
    P.A[0] = h0; P.A[1] = h1; P.A[2] = h2;
    P.B[0] = wkv0T; P.B[1] = wkv1T; P.B[2] = wkv2T;
    P.QA[0] = h0 + obs_off; P.QA[1] = h1 + obs_off; P.QA[2] = h2 + obs_off;
    P.QB[0] = wq0T; P.QB[1] = wq1T; P.QB[2] = wq2T;
    gemm6m<<<dim3(16, 16, 3), 256, 0, stream>>>(P, kvp, qpart);
  }

  // L3) m2: z0 = Q GEMM (full-K -> qf); z1 = kv_finish + qobs_fuse + wo transpose
  m2_kernel<<<dim3(32, 16, 2), 256, 0, stream>>>(h0, wq0T, qf, kvp, invf, kvf,
                                                 kb0, kb1, kb2, qpart, qo0, qo1, qo2,
                                                 wo, woT);

  // L4) RoPE Q
  rope_q_fuse<<<(S_ * HQ_ * 64) / 256, 256, 0, stream>>>(qf, invf, qb16);

  // L5) obs importance GEMM
  {
    TermPtrs P;
    P.a[0] = qo0; P.b[0] = kb0;
    P.a[1] = qo0; P.b[1] = kb1;
    P.a[2] = qo1; P.b[2] = kb0;
    P.a[3] = qo1; P.b[3] = kb1;
    P.a[4] = qo0; P.b[4] = kb2;
    P.a[5] = qo2; P.b[5] = kb0;
    gemm6z<<<dim3(16, 4, 8), 256, 0, stream>>>(P, s_obs);
  }

  // L6-L9) reductions + thresholds
  rowstat_kernel<<<1024, 256, 0, stream>>>(s_obs, mxbuf, dinvb);
  colsum_part<<<dim3(8, 8, 8), 256, 0, stream>>>(s_obs, mxbuf, dinvb, part);
  colsum_fin<<<64, 256, 0, stream>>>(part, impv);
  radix_all<<<1, 1024, 0, stream>>>(impv, thr);

  // L10-L12) sparsify + V-transpose + attention
  sparsify_kernel<<<S_ * HKV_, 128, 0, stream>>>(kvf, impv, thr, ksp, vsp, eb);
  vtrans_kernel<<<dim3(S_ / 64, HKV_), 256, 0, stream>>>(vsp, vspT);
  attn_kernel<<<512, 256, 0, stream>>>(qb16, ksp, vspT, eb, ob16);

  // L13) out projection (full-K, direct write to out)
  gemm1<<<dim3(32, 16, 1), 256, 0, stream>>>(ob16, woT, out, HID_, HID_, 64);
}